// Round 2
// baseline (1658.215 us; speedup 1.0000x reference)
//
#include <hip/hip_runtime.h>
#include <math.h>

#define GG 64
#define NPGc 512
#define NN (GG*NPGc)      // 32768 nodes
#define EE (NN*8)         // 262144 edges
#define HH 64
#define NL 3

// ---------------- threefry2x32 (JAX-compatible) ----------------
__device__ __forceinline__ unsigned rotl32(unsigned x, int r){ return (x<<r)|(x>>(32-r)); }
__device__ __forceinline__ void threefry(unsigned k0, unsigned k1, unsigned x0, unsigned x1,
                                         unsigned &o0, unsigned &o1){
  unsigned ks2 = k0 ^ k1 ^ 0x1BD11BDAu;
  unsigned v0 = x0 + k0, v1 = x1 + k1;
#define R4(a,b,c,d) v0+=v1; v1=rotl32(v1,a); v1^=v0; v0+=v1; v1=rotl32(v1,b); v1^=v0; \
                    v0+=v1; v1=rotl32(v1,c); v1^=v0; v0+=v1; v1=rotl32(v1,d); v1^=v0;
  R4(13,15,26,6)  v0+=k1;  v1+=ks2+1u;
  R4(17,29,16,24) v0+=ks2; v1+=k0+2u;
  R4(13,15,26,6)  v0+=k0;  v1+=k1+3u;
  R4(17,29,16,24) v0+=k1;  v1+=ks2+4u;
  R4(13,15,26,6)  v0+=ks2; v1+=k0+5u;
#undef R4
  o0=v0; o1=v1;
}

// ---------------- encoders: out = relu(in @ w + b), w is [K][64] ----------------
template<int K>
__global__ __launch_bounds__(256) void encode_kernel(const float* __restrict__ in,
    const float* __restrict__ w, const float* __restrict__ b,
    float* __restrict__ out, int rows)
{
  int wid = blockIdx.x*4 + (threadIdx.x>>6);
  int lane = threadIdx.x & 63;
  if (wid >= rows) return;
  const float* xr = in + (size_t)wid*K;
  float acc = b[lane];
#pragma unroll
  for (int i=0;i<K;i++) acc = fmaf(xr[i], w[i*64+lane], acc);
  out[(size_t)wid*64+lane] = fmaxf(acc, 0.f);
}

__global__ __launch_bounds__(256) void initu_kernel(const float* __restrict__ iu, float* __restrict__ u){
  int i = blockIdx.x*256 + threadIdx.x;
  if (i < GG*64) u[i] = iu[i & 63];
}

// ---------------- CSR build (deterministic aggregation) ----------------
__global__ __launch_bounds__(256) void count_kernel(const int* __restrict__ dst, int* __restrict__ cnt){
  int e = blockIdx.x*256 + threadIdx.x;
  if (e < EE) atomicAdd(&cnt[dst[e]], 1);
}
__global__ __launch_bounds__(1024) void scan_kernel(const int* __restrict__ cnt, int* __restrict__ indptr){
  __shared__ int part[1024];
  const int t = threadIdx.x;
  const int base = t*32;
  int s = 0;
  for (int i=0;i<32;i++) s += cnt[base+i];
  part[t] = s;
  __syncthreads();
  for (int off=1; off<1024; off<<=1){
    int v = part[t];
    int add = (t >= off) ? part[t-off] : 0;
    __syncthreads();
    part[t] = v + add;
    __syncthreads();
  }
  int run = (t==0) ? 0 : part[t-1];
  for (int i=0;i<32;i++){ indptr[base+i] = run; run += cnt[base+i]; }
  if (t==1023) indptr[NN] = run;
}
__global__ __launch_bounds__(256) void fill_kernel(const int* __restrict__ dst, const int* __restrict__ indptr,
                                                   int* __restrict__ fillc, int* __restrict__ eord){
  int e = blockIdx.x*256 + threadIdx.x;
  if (e < EE){ int dn = dst[e]; int p = atomicAdd(&fillc[dn], 1); eord[indptr[dn]+p] = e; }
}
__global__ __launch_bounds__(256) void sort_kernel(const int* __restrict__ indptr, int* __restrict__ eord){
  int n = blockIdx.x*256 + threadIdx.x;
  if (n >= NN) return;
  int lo = indptr[n], hi = indptr[n+1];
  for (int i=lo+1;i<hi;i++){
    int v = eord[i]; int j = i-1;
    while (j >= lo && eord[j] > v){ eord[j+1]=eord[j]; j--; }
    eord[j+1] = v;
  }
}

// ---------------- agg[n] = sum_{e: dst[e]==n} he[e] (sorted order = deterministic) ----------------
__global__ __launch_bounds__(256) void agg_kernel(const float* __restrict__ he, const int* __restrict__ indptr,
                                                  const int* __restrict__ eord, float* __restrict__ agg){
  int tid = blockIdx.x*256 + threadIdx.x;
  int n = tid >> 4, cq = tid & 15;
  if (n >= NN) return;
  float4 s = {0.f,0.f,0.f,0.f};
  int lo = indptr[n], hi = indptr[n+1];
  for (int p=lo;p<hi;++p){
    int e = eord[p];
    float4 v = ((const float4*)(he + (size_t)e*64))[cq];
    s.x+=v.x; s.y+=v.y; s.z+=v.z; s.w+=v.w;
  }
  ((float4*)(agg + (size_t)n*64))[cq] = s;
}

// ---------------- per-graph means of hn (512 rows) and he (4096 rows) ----------------
__global__ __launch_bounds__(256) void means_kernel(const float* __restrict__ hn, const float* __restrict__ he,
                                                    float* __restrict__ nmean, float* __restrict__ emean){
  int g = blockIdx.x, t = threadIdx.x;
  int c = t & 63, part = t >> 6;
  float ns = 0.f, es = 0.f;
  for (int r = part; r < 512; r += 4)  ns += hn[((size_t)g*512 + r)*64 + c];
  for (int r = part; r < 4096; r += 4) es += he[((size_t)g*4096 + r)*64 + c];
  __shared__ float nb[4][64], ebf[4][64];
  nb[part][c] = ns; ebf[part][c] = es;
  __syncthreads();
  if (part==0){
    float n4 = nb[0][c]+nb[1][c]+nb[2][c]+nb[3][c];
    float e4 = ebf[0][c]+ebf[1][c]+ebf[2][c]+ebf[3][c];
    nmean[g*64+c] = n4 * (1.f/512.f);
    emean[g*64+c] = e4 * (1.f/4096.f);
  }
}

// ---------------- fused  LN(relu(x@w1+b1)@w2+b2)  for edge/node/global ----------------
// MODE 0: edge rows (DIN=256): [hn[src], hn[dst], he[e], u[e>>12]]
// MODE 1: node rows (DIN=192): [hn[n], agg[n], u[n>>9]]
// MODE 2: graph rows (DIN=192): [u[g], nmean[g], emean[g]]
template<int MODE>
__global__ __launch_bounds__(256) void mlp_ln(
    const float* __restrict__ s0, const float* __restrict__ s1,
    const float* __restrict__ s2, const float* __restrict__ s3,
    const int* __restrict__ srcp, const int* __restrict__ dstp,
    const float* __restrict__ w1, const float* __restrict__ b1,
    const float* __restrict__ w2, const float* __restrict__ b2,
    const float* __restrict__ lng, const float* __restrict__ lnb,
    float* __restrict__ outp)
{
  constexpr int DIN  = (MODE==0) ? 256 : 192;
  constexpr int NSEG = (MODE==0) ? 4 : 3;
  constexpr int DP4  = DIN/4 + 1;         // +1 float4 pad -> conflict-free a-reads

  __shared__ float4 xs4[32*DP4];          // 32 gathered input rows (then reused for h1)
  __shared__ float4 ws4[1024];            // 64x64 weight chunk
  __shared__ float  bsm[4][64];           // b1, b2, ln_g, ln_b

  const int t = threadIdx.x;
  const int rowbase = blockIdx.x*32;

  if (t < 64)       bsm[0][t]     = b1[t];
  else if (t < 128) bsm[1][t-64]  = b2[t-64];
  else if (t < 192) bsm[2][t-128] = lng[t-128];
  else              bsm[3][t-192] = lnb[t-192];

  // ---- gather/stage the 32 input rows ----
  {
    const int gi16 = t >> 4, lg = t & 15;
#pragma unroll
    for (int it = 0; it < 2*NSEG; ++it){
      int pair = gi16 + (it << 4);        // seg = it/2 (constant after unroll)
      int er = pair & 31, seg = pair >> 5;
      int row = rowbase + er;
      const float* bp;
      if constexpr (MODE==0){
        int e = row;
        bp = (seg==0) ? s0 + (size_t)64*srcp[e]
           : (seg==1) ? s1 + (size_t)64*dstp[e]
           : (seg==2) ? s2 + (size_t)64*e
           :            s3 + (size_t)64*(e>>12);
      } else if constexpr (MODE==1){
        bp = (seg==0) ? s0 + (size_t)64*row
           : (seg==1) ? s1 + (size_t)64*row
           :            s2 + (size_t)64*(row>>9);
      } else {
        bp = ((seg==0)? s0 : (seg==1)? s1 : s2) + (size_t)64*row;
      }
      xs4[er*DP4 + seg*16 + lg] = ((const float4*)bp)[lg];
    }
  }
  __syncthreads();

  const int r0 = (t >> 4) * 2, cq = t & 15;
  float acc[2][4] = {{0.f,0.f,0.f,0.f},{0.f,0.f,0.f,0.f}};
  const float4* w1g4 = (const float4*)w1;

  // ---- GEMM1: K chunked by 64 through ws4 ----
  for (int kc = 0; kc < DIN; kc += 64){
    __syncthreads();
    ws4[t]     = w1g4[kc*16 + t];
    ws4[t+256] = w1g4[kc*16 + t + 256];
    ws4[t+512] = w1g4[kc*16 + t + 512];
    ws4[t+768] = w1g4[kc*16 + t + 768];
    __syncthreads();
#pragma unroll
    for (int k4=0;k4<16;k4++){
      float4 a0 = xs4[(r0  )*DP4 + (kc>>2) + k4];
      float4 a1 = xs4[(r0+1)*DP4 + (kc>>2) + k4];
      float4 bb[4];
#pragma unroll
      for (int kk=0;kk<4;kk++) bb[kk] = ws4[(k4*4+kk)*16 + cq];
      const float* a0p = (const float*)&a0;
      const float* a1p = (const float*)&a1;
#pragma unroll
      for (int kk=0;kk<4;kk++){
        acc[0][0]=fmaf(a0p[kk],bb[kk].x,acc[0][0]);
        acc[0][1]=fmaf(a0p[kk],bb[kk].y,acc[0][1]);
        acc[0][2]=fmaf(a0p[kk],bb[kk].z,acc[0][2]);
        acc[0][3]=fmaf(a0p[kk],bb[kk].w,acc[0][3]);
        acc[1][0]=fmaf(a1p[kk],bb[kk].x,acc[1][0]);
        acc[1][1]=fmaf(a1p[kk],bb[kk].y,acc[1][1]);
        acc[1][2]=fmaf(a1p[kk],bb[kk].z,acc[1][2]);
        acc[1][3]=fmaf(a1p[kk],bb[kk].w,acc[1][3]);
      }
    }
  }

  // ---- h1 = relu(acc+b1) -> xs ; stage w2 ----
  __syncthreads();
  {
    float4 h0, h1v;
    h0.x  = fmaxf(acc[0][0]+bsm[0][cq*4+0], 0.f);
    h0.y  = fmaxf(acc[0][1]+bsm[0][cq*4+1], 0.f);
    h0.z  = fmaxf(acc[0][2]+bsm[0][cq*4+2], 0.f);
    h0.w  = fmaxf(acc[0][3]+bsm[0][cq*4+3], 0.f);
    h1v.x = fmaxf(acc[1][0]+bsm[0][cq*4+0], 0.f);
    h1v.y = fmaxf(acc[1][1]+bsm[0][cq*4+1], 0.f);
    h1v.z = fmaxf(acc[1][2]+bsm[0][cq*4+2], 0.f);
    h1v.w = fmaxf(acc[1][3]+bsm[0][cq*4+3], 0.f);
    xs4[(r0  )*DP4 + cq] = h0;
    xs4[(r0+1)*DP4 + cq] = h1v;
    const float4* w2g4 = (const float4*)w2;
    ws4[t]     = w2g4[t];
    ws4[t+256] = w2g4[t+256];
    ws4[t+512] = w2g4[t+512];
    ws4[t+768] = w2g4[t+768];
  }
  __syncthreads();

  // ---- GEMM2 (K=64) ----
  float acc2[2][4] = {{0.f,0.f,0.f,0.f},{0.f,0.f,0.f,0.f}};
#pragma unroll
  for (int k4=0;k4<16;k4++){
    float4 a0 = xs4[(r0  )*DP4 + k4];
    float4 a1 = xs4[(r0+1)*DP4 + k4];
    float4 bb[4];
#pragma unroll
    for (int kk=0;kk<4;kk++) bb[kk] = ws4[(k4*4+kk)*16 + cq];
    const float* a0p = (const float*)&a0;
    const float* a1p = (const float*)&a1;
#pragma unroll
    for (int kk=0;kk<4;kk++){
      acc2[0][0]=fmaf(a0p[kk],bb[kk].x,acc2[0][0]);
      acc2[0][1]=fmaf(a0p[kk],bb[kk].y,acc2[0][1]);
      acc2[0][2]=fmaf(a0p[kk],bb[kk].z,acc2[0][2]);
      acc2[0][3]=fmaf(a0p[kk],bb[kk].w,acc2[0][3]);
      acc2[1][0]=fmaf(a1p[kk],bb[kk].x,acc2[1][0]);
      acc2[1][1]=fmaf(a1p[kk],bb[kk].y,acc2[1][1]);
      acc2[1][2]=fmaf(a1p[kk],bb[kk].z,acc2[1][2]);
      acc2[1][3]=fmaf(a1p[kk],bb[kk].w,acc2[1][3]);
    }
  }

  // ---- LayerNorm over 64 (16-lane-group shfl reduce) + store ----
#pragma unroll
  for (int rr=0; rr<2; rr++){
    float v0 = acc2[rr][0] + bsm[1][cq*4+0];
    float v1 = acc2[rr][1] + bsm[1][cq*4+1];
    float v2 = acc2[rr][2] + bsm[1][cq*4+2];
    float v3 = acc2[rr][3] + bsm[1][cq*4+3];
    float sA = v0+v1+v2+v3;
    float sB = v0*v0+v1*v1+v2*v2+v3*v3;
#pragma unroll
    for (int m=1;m<16;m<<=1){ sA += __shfl_xor(sA,m); sB += __shfl_xor(sB,m); }
    float mean = sA * 0.015625f;
    float var  = sB * 0.015625f - mean*mean;
    float inv  = 1.0f / sqrtf(var + 1e-5f);
    float4 o;
    o.x = (v0-mean)*inv*bsm[2][cq*4+0] + bsm[3][cq*4+0];
    o.y = (v1-mean)*inv*bsm[2][cq*4+1] + bsm[3][cq*4+1];
    o.z = (v2-mean)*inv*bsm[2][cq*4+2] + bsm[3][cq*4+2];
    o.w = (v3-mean)*inv*bsm[2][cq*4+3] + bsm[3][cq*4+3];
    ((float4*)(outp + (size_t)(rowbase + r0 + rr)*64))[cq] = o;
  }
}

// ---------------- heads: sigmoid-logits, log_softmax, gumbel argmax, entropy, value ----------------
__global__ __launch_bounds__(512) void heads_kernel(
    const float* __restrict__ hn, const float* __restrict__ uvec,
    const float* __restrict__ aw, const float* __restrict__ ab,
    const float* __restrict__ cw, const float* __restrict__ cb,
    float* __restrict__ out)
{
  const int g = blockIdx.x, t = threadIdx.x;
  const int n = (g<<9) + t;
  const float4* hp = (const float4*)(hn + (size_t)n*64);
  const float4* ap = (const float4*)aw;
  float d = 0.f;
#pragma unroll
  for (int i=0;i<16;i++){
    float4 h = hp[i], a = ap[i];
    d += h.x*a.x + h.y*a.y + h.z*a.z + h.w*a.w;
  }
  d += ab[0];
  float z = 1.0f/(1.0f + expf(-d));

  // JAX gumbel(key=42), PARTITIONABLE threefry:
  // bits[i] = o0 ^ o1 where (o0,o1) = threefry2x32(key, hi32(i), lo32(i)), hi=0 here
  unsigned o0,o1;
  threefry(0u, 42u, 0u, (unsigned)n, o0, o1);
  unsigned bits = o0 ^ o1;
  float f = __uint_as_float((bits>>9) | 0x3f800000u) - 1.0f;
  float gum = -logf(-logf(fmaxf(1.17549435e-38f, f)));

  const int lane = t & 63, wid = t >> 6;
  __shared__ float smax[8], ssum[8], sent[8], skey[8];
  __shared__ int   sidx[8];
  __shared__ float sM, sS;
  __shared__ int   sA;

  float m = z;
#pragma unroll
  for (int sh=1; sh<64; sh<<=1) m = fmaxf(m, __shfl_xor(m, sh));
  if (lane==0) smax[wid] = m;
  __syncthreads();
  if (t==0){ float mm=smax[0]; for(int i=1;i<8;i++) mm=fmaxf(mm,smax[i]); sM=mm; }
  __syncthreads();
  float M = sM;
  float ex = expf(z - M);
  float ssl = ex;
#pragma unroll
  for (int sh=1; sh<64; sh<<=1) ssl += __shfl_xor(ssl, sh);
  if (lane==0) ssum[wid] = ssl;
  __syncthreads();
  if (t==0){ float ss=0.f; for(int i=0;i<8;i++) ss+=ssum[i]; sS=ss; }
  __syncthreads();
  float logp = z - M - logf(sS);
  float p = expf(logp);
  float entl = p * logp;
#pragma unroll
  for (int sh=1; sh<64; sh<<=1) entl += __shfl_xor(entl, sh);
  if (lane==0) sent[wid] = entl;

  float kv = z + gum; int ki = t;
#pragma unroll
  for (int sh=1; sh<64; sh<<=1){
    float ov = __shfl_xor(kv, sh);
    int   oi = __shfl_xor(ki, sh);
    if (ov > kv || (ov == kv && oi < ki)){ kv = ov; ki = oi; }
  }
  if (lane==0){ skey[wid] = kv; sidx[wid] = ki; }
  __syncthreads();
  if (t==0){
    float bv = skey[0]; int bi = sidx[0];
    for (int i=1;i<8;i++) if (skey[i] > bv || (skey[i]==bv && sidx[i] < bi)){ bv=skey[i]; bi=sidx[i]; }
    sA = bi;
    float ent = 0.f; for (int i=0;i<8;i++) ent += sent[i];
    out[g]      = (float)bi;   // actions
    out[128+g]  = -ent;        // entropy
  }
  __syncthreads();
  if (t == sA) out[64+g] = logp;   // logprobs

  if (t < 64){
    float pv = uvec[(g<<6)+t] * cw[t];
#pragma unroll
    for (int sh=1; sh<64; sh<<=1) pv += __shfl_xor(pv, sh);
    if (t==0) out[192+g] = pv + cb[0];   // value
  }
}

// ---------------- launch ----------------
extern "C" void kernel_launch(void* const* d_in, const int* in_sizes, int n_in,
                              void* d_out, int out_size, void* d_ws, size_t ws_size,
                              hipStream_t stream)
{
  (void)in_sizes; (void)n_in; (void)out_size; (void)ws_size;
  const float* x      = (const float*)d_in[0];
  const float* eattr  = (const float*)d_in[1];
  const int*   eidx   = (const int*)d_in[2];
  const float* node_w = (const float*)d_in[5];
  const float* node_b = (const float*)d_in[6];
  const float* edge_w = (const float*)d_in[7];
  const float* edge_b = (const float*)d_in[8];
  const float* init_u = (const float*)d_in[9];
  const float* ew1 = (const float*)d_in[10]; const float* eb1 = (const float*)d_in[11];
  const float* ew2 = (const float*)d_in[12]; const float* eb2 = (const float*)d_in[13];
  const float* elg = (const float*)d_in[14]; const float* elb = (const float*)d_in[15];
  const float* nw1 = (const float*)d_in[16]; const float* nb1 = (const float*)d_in[17];
  const float* nw2 = (const float*)d_in[18]; const float* nb2 = (const float*)d_in[19];
  const float* nlg = (const float*)d_in[20]; const float* nlb = (const float*)d_in[21];
  const float* gw1 = (const float*)d_in[22]; const float* gb1 = (const float*)d_in[23];
  const float* gw2 = (const float*)d_in[24]; const float* gb2 = (const float*)d_in[25];
  const float* glg = (const float*)d_in[26]; const float* glb = (const float*)d_in[27];
  const float* aw  = (const float*)d_in[28]; const float* ab  = (const float*)d_in[29];
  const float* cw  = (const float*)d_in[30]; const float* cb  = (const float*)d_in[31];
  const int* src = eidx;
  const int* dst = eidx + EE;

  float* ws    = (float*)d_ws;
  float* hn    = ws;                         // N*64
  float* he    = hn + (size_t)NN*64;         // E*64
  float* agg   = he + (size_t)EE*64;         // N*64
  float* u     = agg + (size_t)NN*64;        // G*64
  float* nmean = u + GG*64;
  float* emean = nmean + GG*64;
  int* cnt     = (int*)(emean + GG*64);      // N
  int* indptr  = cnt + NN;                   // N+1
  int* fillc   = indptr + NN + 1;            // N
  int* eord    = fillc + NN;                 // E

  float* out = (float*)d_out;

  hipMemsetAsync(cnt,   0, NN*sizeof(int), stream);
  hipMemsetAsync(fillc, 0, NN*sizeof(int), stream);

  encode_kernel<32><<<NN/4, 256, 0, stream>>>(x, node_w, node_b, hn, NN);
  encode_kernel<16><<<EE/4, 256, 0, stream>>>(eattr, edge_w, edge_b, he, EE);
  initu_kernel<<<16, 256, 0, stream>>>(init_u, u);

  count_kernel<<<EE/256, 256, 0, stream>>>(dst, cnt);
  scan_kernel<<<1, 1024, 0, stream>>>(cnt, indptr);
  fill_kernel<<<EE/256, 256, 0, stream>>>(dst, indptr, fillc, eord);
  sort_kernel<<<NN/256, 256, 0, stream>>>(indptr, eord);

  for (int l=0; l<NL; ++l){
    mlp_ln<0><<<EE/32, 256, 0, stream>>>(hn, hn, he, u, src, dst,
        ew1 + (size_t)l*256*64, eb1 + l*64, ew2 + (size_t)l*64*64, eb2 + l*64,
        elg + l*64, elb + l*64, he);
    agg_kernel<<<NN*16/256, 256, 0, stream>>>(he, indptr, eord, agg);
    mlp_ln<1><<<NN/32, 256, 0, stream>>>(hn, agg, u, nullptr, nullptr, nullptr,
        nw1 + (size_t)l*192*64, nb1 + l*64, nw2 + (size_t)l*64*64, nb2 + l*64,
        nlg + l*64, nlb + l*64, hn);
    means_kernel<<<GG, 256, 0, stream>>>(hn, he, nmean, emean);
    mlp_ln<2><<<GG/32, 256, 0, stream>>>(u, nmean, emean, nullptr, nullptr, nullptr,
        gw1 + (size_t)l*192*64, gb1 + l*64, gw2 + (size_t)l*64*64, gb2 + l*64,
        glg + l*64, glb + l*64, u);
  }

  heads_kernel<<<GG, 512, 0, stream>>>(hn, u, aw, ab, cw, cb, out);
}

// Round 3
// 941.616 us; speedup vs baseline: 1.7610x; 1.7610x over previous
//
#include <hip/hip_runtime.h>
#include <math.h>

#define GG 64
#define NPGc 512
#define NN (GG*NPGc)      // 32768 nodes
#define EE (NN*8)         // 262144 edges
#define HH 64
#define NL 3

// ---------------- threefry2x32 (JAX-compatible, partitionable mode) ----------------
__device__ __forceinline__ unsigned rotl32(unsigned x, int r){ return (x<<r)|(x>>(32-r)); }
__device__ __forceinline__ void threefry(unsigned k0, unsigned k1, unsigned x0, unsigned x1,
                                         unsigned &o0, unsigned &o1){
  unsigned ks2 = k0 ^ k1 ^ 0x1BD11BDAu;
  unsigned v0 = x0 + k0, v1 = x1 + k1;
#define R4(a,b,c,d) v0+=v1; v1=rotl32(v1,a); v1^=v0; v0+=v1; v1=rotl32(v1,b); v1^=v0; \
                    v0+=v1; v1=rotl32(v1,c); v1^=v0; v0+=v1; v1=rotl32(v1,d); v1^=v0;
  R4(13,15,26,6)  v0+=k1;  v1+=ks2+1u;
  R4(17,29,16,24) v0+=ks2; v1+=k0+2u;
  R4(13,15,26,6)  v0+=k0;  v1+=k1+3u;
  R4(17,29,16,24) v0+=k1;  v1+=ks2+4u;
  R4(13,15,26,6)  v0+=ks2; v1+=k0+5u;
#undef R4
  o0=v0; o1=v1;
}

// ---------------- encoders: out = relu(in @ w + b), w is [K][64] ----------------
template<int K>
__global__ __launch_bounds__(256) void encode_kernel(const float* __restrict__ in,
    const float* __restrict__ w, const float* __restrict__ b,
    float* __restrict__ out, int rows)
{
  int wid = blockIdx.x*4 + (threadIdx.x>>6);
  int lane = threadIdx.x & 63;
  if (wid >= rows) return;
  const float* xr = in + (size_t)wid*K;
  float acc = b[lane];
#pragma unroll
  for (int i=0;i<K;i++) acc = fmaf(xr[i], w[i*64+lane], acc);
  out[(size_t)wid*64+lane] = fmaxf(acc, 0.f);
}

__global__ __launch_bounds__(256) void initu_kernel(const float* __restrict__ iu, float* __restrict__ u){
  int i = blockIdx.x*256 + threadIdx.x;
  if (i < GG*64) u[i] = iu[i & 63];
}

// ---------------- CSR build (deterministic aggregation) ----------------
__global__ __launch_bounds__(256) void count_kernel(const int* __restrict__ dst, int* __restrict__ cnt){
  int e = blockIdx.x*256 + threadIdx.x;
  if (e < EE) atomicAdd(&cnt[dst[e]], 1);
}
__global__ __launch_bounds__(1024) void scan_kernel(const int* __restrict__ cnt, int* __restrict__ indptr){
  __shared__ int part[1024];
  const int t = threadIdx.x;
  const int base = t*32;
  int s = 0;
  for (int i=0;i<32;i++) s += cnt[base+i];
  part[t] = s;
  __syncthreads();
  for (int off=1; off<1024; off<<=1){
    int v = part[t];
    int add = (t >= off) ? part[t-off] : 0;
    __syncthreads();
    part[t] = v + add;
    __syncthreads();
  }
  int run = (t==0) ? 0 : part[t-1];
  for (int i=0;i<32;i++){ indptr[base+i] = run; run += cnt[base+i]; }
  if (t==1023) indptr[NN] = run;
}
__global__ __launch_bounds__(256) void fill_kernel(const int* __restrict__ dst, const int* __restrict__ indptr,
                                                   int* __restrict__ fillc, int* __restrict__ eord){
  int e = blockIdx.x*256 + threadIdx.x;
  if (e < EE){ int dn = dst[e]; int p = atomicAdd(&fillc[dn], 1); eord[indptr[dn]+p] = e; }
}
__global__ __launch_bounds__(256) void sort_kernel(const int* __restrict__ indptr, int* __restrict__ eord){
  int n = blockIdx.x*256 + threadIdx.x;
  if (n >= NN) return;
  int lo = indptr[n], hi = indptr[n+1];
  for (int i=lo+1;i<hi;i++){
    int v = eord[i]; int j = i-1;
    while (j >= lo && eord[j] > v){ eord[j+1]=eord[j]; j--; }
    eord[j+1] = v;
  }
}

// ---------------- agg[n] = sum_{e: dst[e]==n} he[e] (sorted order = deterministic) ----------------
__global__ __launch_bounds__(256) void agg_kernel(const float* __restrict__ he, const int* __restrict__ indptr,
                                                  const int* __restrict__ eord, float* __restrict__ agg){
  int tid = blockIdx.x*256 + threadIdx.x;
  int n = tid >> 4, cq = tid & 15;
  if (n >= NN) return;
  float4 s = {0.f,0.f,0.f,0.f};
  int lo = indptr[n], hi = indptr[n+1];
  for (int p=lo;p<hi;++p){
    int e = eord[p];
    float4 v = ((const float4*)(he + (size_t)e*64))[cq];
    s.x+=v.x; s.y+=v.y; s.z+=v.z; s.w+=v.w;
  }
  ((float4*)(agg + (size_t)n*64))[cq] = s;
}

// ---------------- per-graph means, stage 1: partial sums (64 graphs x 32 chunks) ----------------
// block b: graph g=b>>5, chunk c=b&31. he rows [c*128,(c+1)*128), hn rows [c*16,(c+1)*16).
// Fixed-order sums -> deterministic across replays.
__global__ __launch_bounds__(256) void pmeans_kernel(const float* __restrict__ hn, const float* __restrict__ he,
                                                     float* __restrict__ pn, float* __restrict__ pe){
  const int b = blockIdx.x, g = b >> 5, c = b & 31;
  const int t = threadIdx.x, cq = t & 15, part = t >> 4;   // 16 col-quads x 16 parts
  const float4* heb = (const float4*)(he + ((size_t)g*4096 + (size_t)c*128)*64);
  const float4* hnb = (const float4*)(hn + ((size_t)g*512  + (size_t)c*16 )*64);
  float4 es = {0,0,0,0};
  for (int r = part; r < 128; r += 16){
    float4 v = heb[r*16 + cq];
    es.x+=v.x; es.y+=v.y; es.z+=v.z; es.w+=v.w;
  }
  float4 ns = hnb[part*16 + cq];   // exactly one row per part (16 rows, 16 parts)
  __shared__ float4 sbe[16][16], sbn[16][16];
  sbe[part][cq] = es; sbn[part][cq] = ns;
  __syncthreads();
  if (part == 0){
    float4 se = sbe[0][cq], sn = sbn[0][cq];
    for (int p=1;p<16;p++){
      float4 ve = sbe[p][cq], vn = sbn[p][cq];
      se.x+=ve.x; se.y+=ve.y; se.z+=ve.z; se.w+=ve.w;
      sn.x+=vn.x; sn.y+=vn.y; sn.z+=vn.z; sn.w+=vn.w;
    }
    ((float4*)pe)[(g*32+c)*16 + cq] = se;
    ((float4*)pn)[(g*32+c)*16 + cq] = sn;
  }
}

// ---------------- per-graph means, stage 2: reduce 32 partials ----------------
__global__ __launch_bounds__(64) void fmeans_kernel(const float* __restrict__ pn, const float* __restrict__ pe,
                                                    float* __restrict__ nmean, float* __restrict__ emean){
  const int g = blockIdx.x, col = threadIdx.x;
  float ns = 0.f, es = 0.f;
  for (int c=0;c<32;c++){
    ns += pn[(g*32+c)*64 + col];
    es += pe[(g*32+c)*64 + col];
  }
  nmean[g*64+col] = ns * (1.f/512.f);
  emean[g*64+col] = es * (1.f/4096.f);
}

// ---------------- fused  LN(relu(x@w1+b1)@w2+b2)  for edge/node/global ----------------
// MODE 0: edge rows (DIN=256): [hn[src], hn[dst], he[e], u[e>>12]]
// MODE 1: node rows (DIN=192): [hn[n], agg[n], u[n>>9]]
// MODE 2: graph rows (DIN=192): [u[g], nmean[g], emean[g]]
template<int MODE>
__global__ __launch_bounds__(256) void mlp_ln(
    const float* __restrict__ s0, const float* __restrict__ s1,
    const float* __restrict__ s2, const float* __restrict__ s3,
    const int* __restrict__ srcp, const int* __restrict__ dstp,
    const float* __restrict__ w1, const float* __restrict__ b1,
    const float* __restrict__ w2, const float* __restrict__ b2,
    const float* __restrict__ lng, const float* __restrict__ lnb,
    float* __restrict__ outp)
{
  constexpr int DIN  = (MODE==0) ? 256 : 192;
  constexpr int NSEG = (MODE==0) ? 4 : 3;
  constexpr int DP4  = DIN/4 + 1;         // +1 float4 pad -> conflict-free a-reads

  __shared__ float4 xs4[32*DP4];          // 32 gathered input rows (then reused for h1)
  __shared__ float4 ws4[1024];            // 64x64 weight chunk
  __shared__ float  bsm[4][64];           // b1, b2, ln_g, ln_b

  const int t = threadIdx.x;
  const int rowbase = blockIdx.x*32;

  if (t < 64)       bsm[0][t]     = b1[t];
  else if (t < 128) bsm[1][t-64]  = b2[t-64];
  else if (t < 192) bsm[2][t-128] = lng[t-128];
  else              bsm[3][t-192] = lnb[t-192];

  // ---- gather/stage the 32 input rows ----
  {
    const int gi16 = t >> 4, lg = t & 15;
#pragma unroll
    for (int it = 0; it < 2*NSEG; ++it){
      int pair = gi16 + (it << 4);        // seg = it/2 (constant after unroll)
      int er = pair & 31, seg = pair >> 5;
      int row = rowbase + er;
      const float* bp;
      if constexpr (MODE==0){
        int e = row;
        bp = (seg==0) ? s0 + (size_t)64*srcp[e]
           : (seg==1) ? s1 + (size_t)64*dstp[e]
           : (seg==2) ? s2 + (size_t)64*e
           :            s3 + (size_t)64*(e>>12);
      } else if constexpr (MODE==1){
        bp = (seg==0) ? s0 + (size_t)64*row
           : (seg==1) ? s1 + (size_t)64*row
           :            s2 + (size_t)64*(row>>9);
      } else {
        bp = ((seg==0)? s0 : (seg==1)? s1 : s2) + (size_t)64*row;
      }
      xs4[er*DP4 + seg*16 + lg] = ((const float4*)bp)[lg];
    }
  }
  __syncthreads();

  const int r0 = (t >> 4) * 2, cq = t & 15;
  float acc[2][4] = {{0.f,0.f,0.f,0.f},{0.f,0.f,0.f,0.f}};
  const float4* w1g4 = (const float4*)w1;

  // ---- GEMM1: K chunked by 64 through ws4 ----
  for (int kc = 0; kc < DIN; kc += 64){
    __syncthreads();
    ws4[t]     = w1g4[kc*16 + t];
    ws4[t+256] = w1g4[kc*16 + t + 256];
    ws4[t+512] = w1g4[kc*16 + t + 512];
    ws4[t+768] = w1g4[kc*16 + t + 768];
    __syncthreads();
#pragma unroll
    for (int k4=0;k4<16;k4++){
      float4 a0 = xs4[(r0  )*DP4 + (kc>>2) + k4];
      float4 a1 = xs4[(r0+1)*DP4 + (kc>>2) + k4];
      float4 bb[4];
#pragma unroll
      for (int kk=0;kk<4;kk++) bb[kk] = ws4[(k4*4+kk)*16 + cq];
      const float* a0p = (const float*)&a0;
      const float* a1p = (const float*)&a1;
#pragma unroll
      for (int kk=0;kk<4;kk++){
        acc[0][0]=fmaf(a0p[kk],bb[kk].x,acc[0][0]);
        acc[0][1]=fmaf(a0p[kk],bb[kk].y,acc[0][1]);
        acc[0][2]=fmaf(a0p[kk],bb[kk].z,acc[0][2]);
        acc[0][3]=fmaf(a0p[kk],bb[kk].w,acc[0][3]);
        acc[1][0]=fmaf(a1p[kk],bb[kk].x,acc[1][0]);
        acc[1][1]=fmaf(a1p[kk],bb[kk].y,acc[1][1]);
        acc[1][2]=fmaf(a1p[kk],bb[kk].z,acc[1][2]);
        acc[1][3]=fmaf(a1p[kk],bb[kk].w,acc[1][3]);
      }
    }
  }

  // ---- h1 = relu(acc+b1) -> xs ; stage w2 ----
  __syncthreads();
  {
    float4 h0, h1v;
    h0.x  = fmaxf(acc[0][0]+bsm[0][cq*4+0], 0.f);
    h0.y  = fmaxf(acc[0][1]+bsm[0][cq*4+1], 0.f);
    h0.z  = fmaxf(acc[0][2]+bsm[0][cq*4+2], 0.f);
    h0.w  = fmaxf(acc[0][3]+bsm[0][cq*4+3], 0.f);
    h1v.x = fmaxf(acc[1][0]+bsm[0][cq*4+0], 0.f);
    h1v.y = fmaxf(acc[1][1]+bsm[0][cq*4+1], 0.f);
    h1v.z = fmaxf(acc[1][2]+bsm[0][cq*4+2], 0.f);
    h1v.w = fmaxf(acc[1][3]+bsm[0][cq*4+3], 0.f);
    xs4[(r0  )*DP4 + cq] = h0;
    xs4[(r0+1)*DP4 + cq] = h1v;
    const float4* w2g4 = (const float4*)w2;
    ws4[t]     = w2g4[t];
    ws4[t+256] = w2g4[t+256];
    ws4[t+512] = w2g4[t+512];
    ws4[t+768] = w2g4[t+768];
  }
  __syncthreads();

  // ---- GEMM2 (K=64) ----
  float acc2[2][4] = {{0.f,0.f,0.f,0.f},{0.f,0.f,0.f,0.f}};
#pragma unroll
  for (int k4=0;k4<16;k4++){
    float4 a0 = xs4[(r0  )*DP4 + k4];
    float4 a1 = xs4[(r0+1)*DP4 + k4];
    float4 bb[4];
#pragma unroll
    for (int kk=0;kk<4;kk++) bb[kk] = ws4[(k4*4+kk)*16 + cq];
    const float* a0p = (const float*)&a0;
    const float* a1p = (const float*)&a1;
#pragma unroll
    for (int kk=0;kk<4;kk++){
      acc2[0][0]=fmaf(a0p[kk],bb[kk].x,acc2[0][0]);
      acc2[0][1]=fmaf(a0p[kk],bb[kk].y,acc2[0][1]);
      acc2[0][2]=fmaf(a0p[kk],bb[kk].z,acc2[0][2]);
      acc2[0][3]=fmaf(a0p[kk],bb[kk].w,acc2[0][3]);
      acc2[1][0]=fmaf(a1p[kk],bb[kk].x,acc2[1][0]);
      acc2[1][1]=fmaf(a1p[kk],bb[kk].y,acc2[1][1]);
      acc2[1][2]=fmaf(a1p[kk],bb[kk].z,acc2[1][2]);
      acc2[1][3]=fmaf(a1p[kk],bb[kk].w,acc2[1][3]);
    }
  }

  // ---- LayerNorm over 64 (16-lane-group shfl reduce) + store ----
#pragma unroll
  for (int rr=0; rr<2; rr++){
    float v0 = acc2[rr][0] + bsm[1][cq*4+0];
    float v1 = acc2[rr][1] + bsm[1][cq*4+1];
    float v2 = acc2[rr][2] + bsm[1][cq*4+2];
    float v3 = acc2[rr][3] + bsm[1][cq*4+3];
    float sA = v0+v1+v2+v3;
    float sB = v0*v0+v1*v1+v2*v2+v3*v3;
#pragma unroll
    for (int m=1;m<16;m<<=1){ sA += __shfl_xor(sA,m); sB += __shfl_xor(sB,m); }
    float mean = sA * 0.015625f;
    float var  = sB * 0.015625f - mean*mean;
    float inv  = 1.0f / sqrtf(var + 1e-5f);
    float4 o;
    o.x = (v0-mean)*inv*bsm[2][cq*4+0] + bsm[3][cq*4+0];
    o.y = (v1-mean)*inv*bsm[2][cq*4+1] + bsm[3][cq*4+1];
    o.z = (v2-mean)*inv*bsm[2][cq*4+2] + bsm[3][cq*4+2];
    o.w = (v3-mean)*inv*bsm[2][cq*4+3] + bsm[3][cq*4+3];
    ((float4*)(outp + (size_t)(rowbase + r0 + rr)*64))[cq] = o;
  }
}

// ---------------- heads: sigmoid-logits, log_softmax, gumbel argmax, entropy, value ----------------
__global__ __launch_bounds__(512) void heads_kernel(
    const float* __restrict__ hn, const float* __restrict__ uvec,
    const float* __restrict__ aw, const float* __restrict__ ab,
    const float* __restrict__ cw, const float* __restrict__ cb,
    float* __restrict__ out)
{
  const int g = blockIdx.x, t = threadIdx.x;
  const int n = (g<<9) + t;
  const float4* hp = (const float4*)(hn + (size_t)n*64);
  const float4* ap = (const float4*)aw;
  float d = 0.f;
#pragma unroll
  for (int i=0;i<16;i++){
    float4 h = hp[i], a = ap[i];
    d += h.x*a.x + h.y*a.y + h.z*a.z + h.w*a.w;
  }
  d += ab[0];
  float z = 1.0f/(1.0f + expf(-d));

  // JAX gumbel(key=42), partitionable threefry: bits = o0 ^ o1, counts = (0, n)
  unsigned o0,o1;
  threefry(0u, 42u, 0u, (unsigned)n, o0, o1);
  unsigned bits = o0 ^ o1;
  float f = __uint_as_float((bits>>9) | 0x3f800000u) - 1.0f;
  float gum = -logf(-logf(fmaxf(1.17549435e-38f, f)));

  const int lane = t & 63, wid = t >> 6;
  __shared__ float smax[8], ssum[8], sent[8], skey[8];
  __shared__ int   sidx[8];
  __shared__ float sM, sS;
  __shared__ int   sA;

  float m = z;
#pragma unroll
  for (int sh=1; sh<64; sh<<=1) m = fmaxf(m, __shfl_xor(m, sh));
  if (lane==0) smax[wid] = m;
  __syncthreads();
  if (t==0){ float mm=smax[0]; for(int i=1;i<8;i++) mm=fmaxf(mm,smax[i]); sM=mm; }
  __syncthreads();
  float M = sM;
  float ex = expf(z - M);
  float ssl = ex;
#pragma unroll
  for (int sh=1; sh<64; sh<<=1) ssl += __shfl_xor(ssl, sh);
  if (lane==0) ssum[wid] = ssl;
  __syncthreads();
  if (t==0){ float ss=0.f; for(int i=0;i<8;i++) ss+=ssum[i]; sS=ss; }
  __syncthreads();
  float logp = z - M - logf(sS);
  float p = expf(logp);
  float entl = p * logp;
#pragma unroll
  for (int sh=1; sh<64; sh<<=1) entl += __shfl_xor(entl, sh);
  if (lane==0) sent[wid] = entl;

  float kv = z + gum; int ki = t;
#pragma unroll
  for (int sh=1; sh<64; sh<<=1){
    float ov = __shfl_xor(kv, sh);
    int   oi = __shfl_xor(ki, sh);
    if (ov > kv || (ov == kv && oi < ki)){ kv = ov; ki = oi; }
  }
  if (lane==0){ skey[wid] = kv; sidx[wid] = ki; }
  __syncthreads();
  if (t==0){
    float bv = skey[0]; int bi = sidx[0];
    for (int i=1;i<8;i++) if (skey[i] > bv || (skey[i]==bv && sidx[i] < bi)){ bv=skey[i]; bi=sidx[i]; }
    sA = bi;
    float ent = 0.f; for (int i=0;i<8;i++) ent += sent[i];
    out[g]      = (float)bi;   // actions
    out[128+g]  = -ent;        // entropy
  }
  __syncthreads();
  if (t == sA) out[64+g] = logp;   // logprobs

  if (t < 64){
    float pv = uvec[(g<<6)+t] * cw[t];
#pragma unroll
    for (int sh=1; sh<64; sh<<=1) pv += __shfl_xor(pv, sh);
    if (t==0) out[192+g] = pv + cb[0];   // value
  }
}

// ---------------- launch ----------------
extern "C" void kernel_launch(void* const* d_in, const int* in_sizes, int n_in,
                              void* d_out, int out_size, void* d_ws, size_t ws_size,
                              hipStream_t stream)
{
  (void)in_sizes; (void)n_in; (void)out_size; (void)ws_size;
  const float* x      = (const float*)d_in[0];
  const float* eattr  = (const float*)d_in[1];
  const int*   eidx   = (const int*)d_in[2];
  const float* node_w = (const float*)d_in[5];
  const float* node_b = (const float*)d_in[6];
  const float* edge_w = (const float*)d_in[7];
  const float* edge_b = (const float*)d_in[8];
  const float* init_u = (const float*)d_in[9];
  const float* ew1 = (const float*)d_in[10]; const float* eb1 = (const float*)d_in[11];
  const float* ew2 = (const float*)d_in[12]; const float* eb2 = (const float*)d_in[13];
  const float* elg = (const float*)d_in[14]; const float* elb = (const float*)d_in[15];
  const float* nw1 = (const float*)d_in[16]; const float* nb1 = (const float*)d_in[17];
  const float* nw2 = (const float*)d_in[18]; const float* nb2 = (const float*)d_in[19];
  const float* nlg = (const float*)d_in[20]; const float* nlb = (const float*)d_in[21];
  const float* gw1 = (const float*)d_in[22]; const float* gb1 = (const float*)d_in[23];
  const float* gw2 = (const float*)d_in[24]; const float* gb2 = (const float*)d_in[25];
  const float* glg = (const float*)d_in[26]; const float* glb = (const float*)d_in[27];
  const float* aw  = (const float*)d_in[28]; const float* ab  = (const float*)d_in[29];
  const float* cw  = (const float*)d_in[30]; const float* cb  = (const float*)d_in[31];
  const int* src = eidx;
  const int* dst = eidx + EE;

  float* ws    = (float*)d_ws;
  float* hn    = ws;                         // N*64
  float* he    = hn + (size_t)NN*64;         // E*64
  float* agg   = he + (size_t)EE*64;         // N*64
  float* u     = agg + (size_t)NN*64;        // G*64
  float* nmean = u + GG*64;
  float* emean = nmean + GG*64;
  int* cnt     = (int*)(emean + GG*64);      // N
  int* indptr  = cnt + NN;                   // N+1
  int* fillc   = indptr + NN + 1;            // N
  int* eord    = fillc + NN;                 // E

  // partial-mean buffers reuse agg (dead between mlp_ln<1> and next agg_kernel)
  float* pn = agg;                           // 64*32*64
  float* pe = agg + GG*32*64;                // 64*32*64

  float* out = (float*)d_out;

  hipMemsetAsync(cnt,   0, NN*sizeof(int), stream);
  hipMemsetAsync(fillc, 0, NN*sizeof(int), stream);

  encode_kernel<32><<<NN/4, 256, 0, stream>>>(x, node_w, node_b, hn, NN);
  encode_kernel<16><<<EE/4, 256, 0, stream>>>(eattr, edge_w, edge_b, he, EE);
  initu_kernel<<<16, 256, 0, stream>>>(init_u, u);

  count_kernel<<<EE/256, 256, 0, stream>>>(dst, cnt);
  scan_kernel<<<1, 1024, 0, stream>>>(cnt, indptr);
  fill_kernel<<<EE/256, 256, 0, stream>>>(dst, indptr, fillc, eord);
  sort_kernel<<<NN/256, 256, 0, stream>>>(indptr, eord);

  for (int l=0; l<NL; ++l){
    mlp_ln<0><<<EE/32, 256, 0, stream>>>(hn, hn, he, u, src, dst,
        ew1 + (size_t)l*256*64, eb1 + l*64, ew2 + (size_t)l*64*64, eb2 + l*64,
        elg + l*64, elb + l*64, he);
    agg_kernel<<<NN*16/256, 256, 0, stream>>>(he, indptr, eord, agg);
    mlp_ln<1><<<NN/32, 256, 0, stream>>>(hn, agg, u, nullptr, nullptr, nullptr,
        nw1 + (size_t)l*192*64, nb1 + l*64, nw2 + (size_t)l*64*64, nb2 + l*64,
        nlg + l*64, nlb + l*64, hn);
    pmeans_kernel<<<GG*32, 256, 0, stream>>>(hn, he, pn, pe);
    fmeans_kernel<<<GG, 64, 0, stream>>>(pn, pe, nmean, emean);
    mlp_ln<2><<<GG/32, 256, 0, stream>>>(u, nmean, emean, nullptr, nullptr, nullptr,
        gw1 + (size_t)l*192*64, gb1 + l*64, gw2 + (size_t)l*64*64, gb2 + l*64,
        glg + l*64, glb + l*64, u);
  }

  heads_kernel<<<GG, 512, 0, stream>>>(hn, u, aw, ab, cw, cb, out);
}

// Round 4
// 687.639 us; speedup vs baseline: 2.4115x; 1.3693x over previous
//
#include <hip/hip_runtime.h>
#include <math.h>

#define GG 64
#define NPGc 512
#define NN (GG*NPGc)      // 32768 nodes
#define EE (NN*8)         // 262144 edges
#define HH 64
#define NL 3

// ---------------- threefry2x32 (JAX-compatible, partitionable mode) ----------------
__device__ __forceinline__ unsigned rotl32(unsigned x, int r){ return (x<<r)|(x>>(32-r)); }
__device__ __forceinline__ void threefry(unsigned k0, unsigned k1, unsigned x0, unsigned x1,
                                         unsigned &o0, unsigned &o1){
  unsigned ks2 = k0 ^ k1 ^ 0x1BD11BDAu;
  unsigned v0 = x0 + k0, v1 = x1 + k1;
#define R4(a,b,c,d) v0+=v1; v1=rotl32(v1,a); v1^=v0; v0+=v1; v1=rotl32(v1,b); v1^=v0; \
                    v0+=v1; v1=rotl32(v1,c); v1^=v0; v0+=v1; v1=rotl32(v1,d); v1^=v0;
  R4(13,15,26,6)  v0+=k1;  v1+=ks2+1u;
  R4(17,29,16,24) v0+=ks2; v1+=k0+2u;
  R4(13,15,26,6)  v0+=k0;  v1+=k1+3u;
  R4(17,29,16,24) v0+=k1;  v1+=ks2+4u;
  R4(13,15,26,6)  v0+=ks2; v1+=k0+5u;
#undef R4
  o0=v0; o1=v1;
}

// ---------------- encoders: out = relu(in @ w + b), w is [K][64] ----------------
template<int K>
__global__ __launch_bounds__(256) void encode_kernel(const float* __restrict__ in,
    const float* __restrict__ w, const float* __restrict__ b,
    float* __restrict__ out, int rows)
{
  int wid = blockIdx.x*4 + (threadIdx.x>>6);
  int lane = threadIdx.x & 63;
  if (wid >= rows) return;
  const float* xr = in + (size_t)wid*K;
  float acc = b[lane];
#pragma unroll
  for (int i=0;i<K;i++) acc = fmaf(xr[i], w[i*64+lane], acc);
  out[(size_t)wid*64+lane] = fmaxf(acc, 0.f);
}

__global__ __launch_bounds__(256) void initu_kernel(const float* __restrict__ iu, float* __restrict__ u){
  int i = blockIdx.x*256 + threadIdx.x;
  if (i < GG*64) u[i] = iu[i & 63];
}

// ---------------- CSR build (deterministic aggregation) ----------------
__global__ __launch_bounds__(256) void count_kernel(const int* __restrict__ dst, int* __restrict__ cnt){
  int e = blockIdx.x*256 + threadIdx.x;
  if (e < EE) atomicAdd(&cnt[dst[e]], 1);
}
__global__ __launch_bounds__(1024) void scan_kernel(const int* __restrict__ cnt, int* __restrict__ indptr){
  __shared__ int part[1024];
  const int t = threadIdx.x;
  const int base = t*32;
  int s = 0;
  for (int i=0;i<32;i++) s += cnt[base+i];
  part[t] = s;
  __syncthreads();
  for (int off=1; off<1024; off<<=1){
    int v = part[t];
    int add = (t >= off) ? part[t-off] : 0;
    __syncthreads();
    part[t] = v + add;
    __syncthreads();
  }
  int run = (t==0) ? 0 : part[t-1];
  for (int i=0;i<32;i++){ indptr[base+i] = run; run += cnt[base+i]; }
  if (t==1023) indptr[NN] = run;
}
__global__ __launch_bounds__(256) void fill_kernel(const int* __restrict__ dst, const int* __restrict__ indptr,
                                                   int* __restrict__ fillc, int* __restrict__ eord){
  int e = blockIdx.x*256 + threadIdx.x;
  if (e < EE){ int dn = dst[e]; int p = atomicAdd(&fillc[dn], 1); eord[indptr[dn]+p] = e; }
}
__global__ __launch_bounds__(256) void sort_kernel(const int* __restrict__ indptr, int* __restrict__ eord){
  int n = blockIdx.x*256 + threadIdx.x;
  if (n >= NN) return;
  int lo = indptr[n], hi = indptr[n+1];
  for (int i=lo+1;i<hi;i++){
    int v = eord[i]; int j = i-1;
    while (j >= lo && eord[j] > v){ eord[j+1]=eord[j]; j--; }
    eord[j+1] = v;
  }
}

// ---------------- agg[n] = sum_{e: dst[e]==n} he[e] (sorted order = deterministic) ----------------
__global__ __launch_bounds__(256) void agg_kernel(const float* __restrict__ he, const int* __restrict__ indptr,
                                                  const int* __restrict__ eord, float* __restrict__ agg){
  int tid = blockIdx.x*256 + threadIdx.x;
  int n = tid >> 4, cq = tid & 15;
  if (n >= NN) return;
  float4 s = {0.f,0.f,0.f,0.f};
  int lo = indptr[n], hi = indptr[n+1];
  for (int p=lo;p<hi;++p){
    int e = eord[p];
    float4 v = ((const float4*)(he + (size_t)e*64))[cq];
    s.x+=v.x; s.y+=v.y; s.z+=v.z; s.w+=v.w;
  }
  ((float4*)(agg + (size_t)n*64))[cq] = s;
}

// ---------------- per-graph means, stage 1: partial sums (64 graphs x 32 chunks) ----------------
__global__ __launch_bounds__(256) void pmeans_kernel(const float* __restrict__ hn, const float* __restrict__ he,
                                                     float* __restrict__ pn, float* __restrict__ pe){
  const int b = blockIdx.x, g = b >> 5, c = b & 31;
  const int t = threadIdx.x, cq = t & 15, part = t >> 4;
  const float4* heb = (const float4*)(he + ((size_t)g*4096 + (size_t)c*128)*64);
  const float4* hnb = (const float4*)(hn + ((size_t)g*512  + (size_t)c*16 )*64);
  float4 es = {0,0,0,0};
  for (int r = part; r < 128; r += 16){
    float4 v = heb[r*16 + cq];
    es.x+=v.x; es.y+=v.y; es.z+=v.z; es.w+=v.w;
  }
  float4 ns = hnb[part*16 + cq];
  __shared__ float4 sbe[16][16], sbn[16][16];
  sbe[part][cq] = es; sbn[part][cq] = ns;
  __syncthreads();
  if (part == 0){
    float4 se = sbe[0][cq], sn = sbn[0][cq];
    for (int p=1;p<16;p++){
      float4 ve = sbe[p][cq], vn = sbn[p][cq];
      se.x+=ve.x; se.y+=ve.y; se.z+=ve.z; se.w+=ve.w;
      sn.x+=vn.x; sn.y+=vn.y; sn.z+=vn.z; sn.w+=vn.w;
    }
    ((float4*)pe)[(g*32+c)*16 + cq] = se;
    ((float4*)pn)[(g*32+c)*16 + cq] = sn;
  }
}

// ---------------- per-graph means, stage 2 ----------------
__global__ __launch_bounds__(64) void fmeans_kernel(const float* __restrict__ pn, const float* __restrict__ pe,
                                                    float* __restrict__ nmean, float* __restrict__ emean){
  const int g = blockIdx.x, col = threadIdx.x;
  float ns = 0.f, es = 0.f;
  for (int c=0;c<32;c++){
    ns += pn[(g*32+c)*64 + col];
    es += pe[(g*32+c)*64 + col];
  }
  nmean[g*64+col] = ns * (1.f/512.f);
  emean[g*64+col] = es * (1.f/4096.f);
}

// ---------------- pre_kernel: oa = x@wa, ob = x@wb  (x: rows x 64, w: 64x64) ----------------
__global__ __launch_bounds__(256) void pre_kernel(const float* __restrict__ x,
    const float* __restrict__ wa, const float* __restrict__ wb,
    float* __restrict__ oa, float* __restrict__ ob, int rows)
{
  __shared__ float4 xs4[32*17];
  __shared__ float4 wsa[1024], wsb[1024];
  const int t = threadIdx.x;
  const int rowbase = blockIdx.x*32;
  {
    const int gi16 = t>>4, lg = t&15;
#pragma unroll
    for (int it=0; it<2; ++it){
      int er = gi16 + (it<<4);
      xs4[er*17+lg] = ((const float4*)(x + (size_t)64*(rowbase+er)))[lg];
    }
  }
  const float4* wa4 = (const float4*)wa;
  const float4* wb4 = (const float4*)wb;
#pragma unroll
  for (int i=0;i<4;i++){ wsa[t+i*256] = wa4[t+i*256]; wsb[t+i*256] = wb4[t+i*256]; }
  __syncthreads();

  const int r0 = (t>>4)*2, cq = t&15;
  float accA[2][4] = {{0,0,0,0},{0,0,0,0}};
  float accB[2][4] = {{0,0,0,0},{0,0,0,0}};
#pragma unroll
  for (int k4=0;k4<16;k4++){
    float4 a0 = xs4[(r0  )*17 + k4];
    float4 a1 = xs4[(r0+1)*17 + k4];
    const float* a0p = (const float*)&a0;
    const float* a1p = (const float*)&a1;
#pragma unroll
    for (int kk=0;kk<4;kk++){
      float4 ba = wsa[(k4*4+kk)*16 + cq];
      float4 bb = wsb[(k4*4+kk)*16 + cq];
      accA[0][0]=fmaf(a0p[kk],ba.x,accA[0][0]); accA[0][1]=fmaf(a0p[kk],ba.y,accA[0][1]);
      accA[0][2]=fmaf(a0p[kk],ba.z,accA[0][2]); accA[0][3]=fmaf(a0p[kk],ba.w,accA[0][3]);
      accA[1][0]=fmaf(a1p[kk],ba.x,accA[1][0]); accA[1][1]=fmaf(a1p[kk],ba.y,accA[1][1]);
      accA[1][2]=fmaf(a1p[kk],ba.z,accA[1][2]); accA[1][3]=fmaf(a1p[kk],ba.w,accA[1][3]);
      accB[0][0]=fmaf(a0p[kk],bb.x,accB[0][0]); accB[0][1]=fmaf(a0p[kk],bb.y,accB[0][1]);
      accB[0][2]=fmaf(a0p[kk],bb.z,accB[0][2]); accB[0][3]=fmaf(a0p[kk],bb.w,accB[0][3]);
      accB[1][0]=fmaf(a1p[kk],bb.x,accB[1][0]); accB[1][1]=fmaf(a1p[kk],bb.y,accB[1][1]);
      accB[1][2]=fmaf(a1p[kk],bb.z,accB[1][2]); accB[1][3]=fmaf(a1p[kk],bb.w,accB[1][3]);
    }
  }
#pragma unroll
  for (int rr=0; rr<2; rr++){
    size_t row = rowbase + r0 + rr;
    float4 va = {accA[rr][0],accA[rr][1],accA[rr][2],accA[rr][3]};
    float4 vb = {accB[rr][0],accB[rr][1],accB[rr][2],accB[rr][3]};
    ((float4*)(oa + row*64))[cq] = va;
    ((float4*)(ob + row*64))[cq] = vb;
  }
}

// ---------------- fused  LN(relu(x@w1+b1)@w2+b2) ----------------
// MODE 0: edge rows (DIN=64: he), epilogue add pa[src]+pb[dst]+ue[g], g=row>>12
// MODE 1: node rows (DIN=128: [hn,agg]), epilogue add un[g], g=row>>9
// MODE 2: graph rows (DIN=192: [u,nmean,emean])
template<int MODE>
__global__ __launch_bounds__(256) void mlp_ln(
    const float* __restrict__ s0, const float* __restrict__ s1,
    const float* __restrict__ s2, const float* __restrict__ s3,
    const int* __restrict__ srcp, const int* __restrict__ dstp,
    const float* __restrict__ w1, const float* __restrict__ b1,
    const float* __restrict__ w2, const float* __restrict__ b2,
    const float* __restrict__ lng, const float* __restrict__ lnb,
    float* __restrict__ outp)
{
  constexpr int DIN  = (MODE==0) ? 64 : (MODE==1) ? 128 : 192;
  constexpr int DP4  = DIN/4 + 1;
  constexpr int PASZ = (MODE==0) ? 32*17 : 1;

  __shared__ float4 xs4[32*DP4];
  __shared__ float4 pas[PASZ], pbs[PASZ];
  __shared__ float4 ws4[1024];
  __shared__ float  bsm[5][64];

  const int t = threadIdx.x;
  const int rowbase = blockIdx.x*32;

  if (t < 64)       bsm[0][t]     = b1[t];
  else if (t < 128) bsm[1][t-64]  = b2[t-64];
  else if (t < 192) bsm[2][t-128] = lng[t-128];
  else              bsm[3][t-192] = lnb[t-192];

  if constexpr (MODE==0){
    const int g = rowbase >> 12;
    if (t < 64) bsm[4][t] = s3[(g<<6)+t];
  } else if constexpr (MODE==1){
    const int g = rowbase >> 9;
    if (t < 64) bsm[4][t] = s2[(g<<6)+t];
  }

  // ---- stage inputs ----
  if constexpr (MODE==0){
    const int gi16 = t >> 4, lg = t & 15;
#pragma unroll
    for (int it = 0; it < 6; ++it){
      int pair = gi16 + (it << 4);
      int er = pair & 31, seg = pair >> 5;
      int row = rowbase + er;
      if (seg==0)      xs4[er*DP4 + lg] = ((const float4*)(s0 + (size_t)64*row))[lg];
      else if (seg==1) pas[er*17 + lg] = ((const float4*)(s1 + (size_t)64*srcp[row]))[lg];
      else             pbs[er*17 + lg] = ((const float4*)(s2 + (size_t)64*dstp[row]))[lg];
    }
  } else {
    constexpr int NSEG = DIN/64;
    const int gi16 = t >> 4, lg = t & 15;
#pragma unroll
    for (int it = 0; it < 2*NSEG; ++it){
      int pair = gi16 + (it << 4);
      int er = pair & 31, seg = pair >> 5;
      int row = rowbase + er;
      const float* bp = ((seg==0)? s0 : (seg==1)? s1 : s2) + (size_t)64*row;
      xs4[er*DP4 + seg*16 + lg] = ((const float4*)bp)[lg];
    }
  }
  __syncthreads();

  const int r0 = (t >> 4) * 2, cq = t & 15;
  float acc[2][4] = {{0.f,0.f,0.f,0.f},{0.f,0.f,0.f,0.f}};
  const float4* w1g4 = (const float4*)w1;

  // ---- GEMM1: K chunked by 64 ----
  for (int kc = 0; kc < DIN; kc += 64){
    __syncthreads();
    ws4[t]     = w1g4[kc*16 + t];
    ws4[t+256] = w1g4[kc*16 + t + 256];
    ws4[t+512] = w1g4[kc*16 + t + 512];
    ws4[t+768] = w1g4[kc*16 + t + 768];
    __syncthreads();
#pragma unroll
    for (int k4=0;k4<16;k4++){
      float4 a0 = xs4[(r0  )*DP4 + (kc>>2) + k4];
      float4 a1 = xs4[(r0+1)*DP4 + (kc>>2) + k4];
      float4 bb[4];
#pragma unroll
      for (int kk=0;kk<4;kk++) bb[kk] = ws4[(k4*4+kk)*16 + cq];
      const float* a0p = (const float*)&a0;
      const float* a1p = (const float*)&a1;
#pragma unroll
      for (int kk=0;kk<4;kk++){
        acc[0][0]=fmaf(a0p[kk],bb[kk].x,acc[0][0]);
        acc[0][1]=fmaf(a0p[kk],bb[kk].y,acc[0][1]);
        acc[0][2]=fmaf(a0p[kk],bb[kk].z,acc[0][2]);
        acc[0][3]=fmaf(a0p[kk],bb[kk].w,acc[0][3]);
        acc[1][0]=fmaf(a1p[kk],bb[kk].x,acc[1][0]);
        acc[1][1]=fmaf(a1p[kk],bb[kk].y,acc[1][1]);
        acc[1][2]=fmaf(a1p[kk],bb[kk].z,acc[1][2]);
        acc[1][3]=fmaf(a1p[kk],bb[kk].w,acc[1][3]);
      }
    }
  }

  // ---- epilogue adds (pa[src]+pb[dst]+ue[g] or un[g]) ----
  float4 ex0 = {0.f,0.f,0.f,0.f}, ex1 = {0.f,0.f,0.f,0.f};
  if constexpr (MODE==0){
    float4 qa0 = pas[(r0  )*17+cq], qb0 = pbs[(r0  )*17+cq];
    float4 qa1 = pas[(r0+1)*17+cq], qb1 = pbs[(r0+1)*17+cq];
    ex0.x = qa0.x+qb0.x+bsm[4][cq*4+0]; ex0.y = qa0.y+qb0.y+bsm[4][cq*4+1];
    ex0.z = qa0.z+qb0.z+bsm[4][cq*4+2]; ex0.w = qa0.w+qb0.w+bsm[4][cq*4+3];
    ex1.x = qa1.x+qb1.x+bsm[4][cq*4+0]; ex1.y = qa1.y+qb1.y+bsm[4][cq*4+1];
    ex1.z = qa1.z+qb1.z+bsm[4][cq*4+2]; ex1.w = qa1.w+qb1.w+bsm[4][cq*4+3];
  } else if constexpr (MODE==1){
    ex0.x = ex1.x = bsm[4][cq*4+0]; ex0.y = ex1.y = bsm[4][cq*4+1];
    ex0.z = ex1.z = bsm[4][cq*4+2]; ex0.w = ex1.w = bsm[4][cq*4+3];
  }

  // ---- h1 = relu(acc+b1+ex) -> xs ; stage w2 ----
  __syncthreads();
  {
    float4 h0, h1v;
    h0.x  = fmaxf(acc[0][0]+bsm[0][cq*4+0]+ex0.x, 0.f);
    h0.y  = fmaxf(acc[0][1]+bsm[0][cq*4+1]+ex0.y, 0.f);
    h0.z  = fmaxf(acc[0][2]+bsm[0][cq*4+2]+ex0.z, 0.f);
    h0.w  = fmaxf(acc[0][3]+bsm[0][cq*4+3]+ex0.w, 0.f);
    h1v.x = fmaxf(acc[1][0]+bsm[0][cq*4+0]+ex1.x, 0.f);
    h1v.y = fmaxf(acc[1][1]+bsm[0][cq*4+1]+ex1.y, 0.f);
    h1v.z = fmaxf(acc[1][2]+bsm[0][cq*4+2]+ex1.z, 0.f);
    h1v.w = fmaxf(acc[1][3]+bsm[0][cq*4+3]+ex1.w, 0.f);
    xs4[(r0  )*DP4 + cq] = h0;
    xs4[(r0+1)*DP4 + cq] = h1v;
    const float4* w2g4 = (const float4*)w2;
    ws4[t]     = w2g4[t];
    ws4[t+256] = w2g4[t+256];
    ws4[t+512] = w2g4[t+512];
    ws4[t+768] = w2g4[t+768];
  }
  __syncthreads();

  // ---- GEMM2 (K=64) ----
  float acc2[2][4] = {{0.f,0.f,0.f,0.f},{0.f,0.f,0.f,0.f}};
#pragma unroll
  for (int k4=0;k4<16;k4++){
    float4 a0 = xs4[(r0  )*DP4 + k4];
    float4 a1 = xs4[(r0+1)*DP4 + k4];
    float4 bb[4];
#pragma unroll
    for (int kk=0;kk<4;kk++) bb[kk] = ws4[(k4*4+kk)*16 + cq];
    const float* a0p = (const float*)&a0;
    const float* a1p = (const float*)&a1;
#pragma unroll
    for (int kk=0;kk<4;kk++){
      acc2[0][0]=fmaf(a0p[kk],bb[kk].x,acc2[0][0]);
      acc2[0][1]=fmaf(a0p[kk],bb[kk].y,acc2[0][1]);
      acc2[0][2]=fmaf(a0p[kk],bb[kk].z,acc2[0][2]);
      acc2[0][3]=fmaf(a0p[kk],bb[kk].w,acc2[0][3]);
      acc2[1][0]=fmaf(a1p[kk],bb[kk].x,acc2[1][0]);
      acc2[1][1]=fmaf(a1p[kk],bb[kk].y,acc2[1][1]);
      acc2[1][2]=fmaf(a1p[kk],bb[kk].z,acc2[1][2]);
      acc2[1][3]=fmaf(a1p[kk],bb[kk].w,acc2[1][3]);
    }
  }

  // ---- LayerNorm over 64 + store ----
#pragma unroll
  for (int rr=0; rr<2; rr++){
    float v0 = acc2[rr][0] + bsm[1][cq*4+0];
    float v1 = acc2[rr][1] + bsm[1][cq*4+1];
    float v2 = acc2[rr][2] + bsm[1][cq*4+2];
    float v3 = acc2[rr][3] + bsm[1][cq*4+3];
    float sA = v0+v1+v2+v3;
    float sB = v0*v0+v1*v1+v2*v2+v3*v3;
#pragma unroll
    for (int m=1;m<16;m<<=1){ sA += __shfl_xor(sA,m); sB += __shfl_xor(sB,m); }
    float mean = sA * 0.015625f;
    float var  = sB * 0.015625f - mean*mean;
    float inv  = 1.0f / sqrtf(var + 1e-5f);
    float4 o;
    o.x = (v0-mean)*inv*bsm[2][cq*4+0] + bsm[3][cq*4+0];
    o.y = (v1-mean)*inv*bsm[2][cq*4+1] + bsm[3][cq*4+1];
    o.z = (v2-mean)*inv*bsm[2][cq*4+2] + bsm[3][cq*4+2];
    o.w = (v3-mean)*inv*bsm[2][cq*4+3] + bsm[3][cq*4+3];
    ((float4*)(outp + (size_t)(rowbase + r0 + rr)*64))[cq] = o;
  }
}

// ---------------- heads ----------------
__global__ __launch_bounds__(512) void heads_kernel(
    const float* __restrict__ hn, const float* __restrict__ uvec,
    const float* __restrict__ aw, const float* __restrict__ ab,
    const float* __restrict__ cw, const float* __restrict__ cb,
    float* __restrict__ out)
{
  const int g = blockIdx.x, t = threadIdx.x;
  const int n = (g<<9) + t;
  const float4* hp = (const float4*)(hn + (size_t)n*64);
  const float4* ap = (const float4*)aw;
  float d = 0.f;
#pragma unroll
  for (int i=0;i<16;i++){
    float4 h = hp[i], a = ap[i];
    d += h.x*a.x + h.y*a.y + h.z*a.z + h.w*a.w;
  }
  d += ab[0];
  float z = 1.0f/(1.0f + expf(-d));

  unsigned o0,o1;
  threefry(0u, 42u, 0u, (unsigned)n, o0, o1);
  unsigned bits = o0 ^ o1;
  float f = __uint_as_float((bits>>9) | 0x3f800000u) - 1.0f;
  float gum = -logf(-logf(fmaxf(1.17549435e-38f, f)));

  const int lane = t & 63, wid = t >> 6;
  __shared__ float smax[8], ssum[8], sent[8], skey[8];
  __shared__ int   sidx[8];
  __shared__ float sM, sS;
  __shared__ int   sA;

  float m = z;
#pragma unroll
  for (int sh=1; sh<64; sh<<=1) m = fmaxf(m, __shfl_xor(m, sh));
  if (lane==0) smax[wid] = m;
  __syncthreads();
  if (t==0){ float mm=smax[0]; for(int i=1;i<8;i++) mm=fmaxf(mm,smax[i]); sM=mm; }
  __syncthreads();
  float M = sM;
  float ex = expf(z - M);
  float ssl = ex;
#pragma unroll
  for (int sh=1; sh<64; sh<<=1) ssl += __shfl_xor(ssl, sh);
  if (lane==0) ssum[wid] = ssl;
  __syncthreads();
  if (t==0){ float ss=0.f; for(int i=0;i<8;i++) ss+=ssum[i]; sS=ss; }
  __syncthreads();
  float logp = z - M - logf(sS);
  float p = expf(logp);
  float entl = p * logp;
#pragma unroll
  for (int sh=1; sh<64; sh<<=1) entl += __shfl_xor(entl, sh);
  if (lane==0) sent[wid] = entl;

  float kv = z + gum; int ki = t;
#pragma unroll
  for (int sh=1; sh<64; sh<<=1){
    float ov = __shfl_xor(kv, sh);
    int   oi = __shfl_xor(ki, sh);
    if (ov > kv || (ov == kv && oi < ki)){ kv = ov; ki = oi; }
  }
  if (lane==0){ skey[wid] = kv; sidx[wid] = ki; }
  __syncthreads();
  if (t==0){
    float bv = skey[0]; int bi = sidx[0];
    for (int i=1;i<8;i++) if (skey[i] > bv || (skey[i]==bv && sidx[i] < bi)){ bv=skey[i]; bi=sidx[i]; }
    sA = bi;
    float ent = 0.f; for (int i=0;i<8;i++) ent += sent[i];
    out[g]      = (float)bi;
    out[128+g]  = -ent;
  }
  __syncthreads();
  if (t == sA) out[64+g] = logp;

  if (t < 64){
    float pv = uvec[(g<<6)+t] * cw[t];
#pragma unroll
    for (int sh=1; sh<64; sh<<=1) pv += __shfl_xor(pv, sh);
    if (t==0) out[192+g] = pv + cb[0];
  }
}

// ---------------- launch ----------------
extern "C" void kernel_launch(void* const* d_in, const int* in_sizes, int n_in,
                              void* d_out, int out_size, void* d_ws, size_t ws_size,
                              hipStream_t stream)
{
  (void)in_sizes; (void)n_in; (void)out_size; (void)ws_size;
  const float* x      = (const float*)d_in[0];
  const float* eattr  = (const float*)d_in[1];
  const int*   eidx   = (const int*)d_in[2];
  const float* node_w = (const float*)d_in[5];
  const float* node_b = (const float*)d_in[6];
  const float* edge_w = (const float*)d_in[7];
  const float* edge_b = (const float*)d_in[8];
  const float* init_u = (const float*)d_in[9];
  const float* ew1 = (const float*)d_in[10]; const float* eb1 = (const float*)d_in[11];
  const float* ew2 = (const float*)d_in[12]; const float* eb2 = (const float*)d_in[13];
  const float* elg = (const float*)d_in[14]; const float* elb = (const float*)d_in[15];
  const float* nw1 = (const float*)d_in[16]; const float* nb1 = (const float*)d_in[17];
  const float* nw2 = (const float*)d_in[18]; const float* nb2 = (const float*)d_in[19];
  const float* nlg = (const float*)d_in[20]; const float* nlb = (const float*)d_in[21];
  const float* gw1 = (const float*)d_in[22]; const float* gb1 = (const float*)d_in[23];
  const float* gw2 = (const float*)d_in[24]; const float* gb2 = (const float*)d_in[25];
  const float* glg = (const float*)d_in[26]; const float* glb = (const float*)d_in[27];
  const float* aw  = (const float*)d_in[28]; const float* ab  = (const float*)d_in[29];
  const float* cw  = (const float*)d_in[30]; const float* cb  = (const float*)d_in[31];
  const int* src = eidx;
  const int* dst = eidx + EE;

  float* ws    = (float*)d_ws;
  float* hn    = ws;                         // N*64
  float* he    = hn + (size_t)NN*64;         // E*64
  float* agg   = he + (size_t)EE*64;         // N*64
  float* u     = agg + (size_t)NN*64;        // G*64
  float* nmean = u + GG*64;
  float* emean = nmean + GG*64;
  int* cnt     = (int*)(emean + GG*64);      // N
  int* indptr  = cnt + NN;                   // N+1
  int* fillc   = indptr + NN + 1;            // N
  int* eord    = fillc + NN;                 // E

  // pa aliases agg (dead during edge phase); pn/pe alias agg (dead after node MLP)
  float* pa = agg;
  float* pn = agg;
  float* pe = agg + GG*32*64;
  float* pb = (float*)(eord + EE);           // N*64 (new, +8 MB)
  float* ue = pb + (size_t)NN*64;            // G*64
  float* un = ue + GG*64;                    // G*64

  float* out = (float*)d_out;

  hipMemsetAsync(cnt,   0, NN*sizeof(int), stream);
  hipMemsetAsync(fillc, 0, NN*sizeof(int), stream);

  encode_kernel<32><<<NN/4, 256, 0, stream>>>(x, node_w, node_b, hn, NN);
  encode_kernel<16><<<EE/4, 256, 0, stream>>>(eattr, edge_w, edge_b, he, EE);
  initu_kernel<<<16, 256, 0, stream>>>(init_u, u);

  count_kernel<<<EE/256, 256, 0, stream>>>(dst, cnt);
  scan_kernel<<<1, 1024, 0, stream>>>(cnt, indptr);
  fill_kernel<<<EE/256, 256, 0, stream>>>(dst, indptr, fillc, eord);
  sort_kernel<<<NN/256, 256, 0, stream>>>(indptr, eord);

  for (int l=0; l<NL; ++l){
    const float* ew1l = ew1 + (size_t)l*256*64;
    const float* nw1l = nw1 + (size_t)l*192*64;
    // per-node endpoint precomputes: pa = hn@W1[0:64], pb = hn@W1[64:128]
    pre_kernel<<<NN/32, 256, 0, stream>>>(hn, ew1l, ew1l + 64*64, pa, pb, NN);
    // per-graph u precomputes: ue = u@W1e[192:256], un = u@W1n[128:192]
    pre_kernel<<<2, 256, 0, stream>>>(u, ew1l + 192*64, nw1l + 128*64, ue, un, GG);

    mlp_ln<0><<<EE/32, 256, 0, stream>>>(he, pa, pb, ue, src, dst,
        ew1l + 128*64, eb1 + l*64, ew2 + (size_t)l*64*64, eb2 + l*64,
        elg + l*64, elb + l*64, he);
    agg_kernel<<<NN*16/256, 256, 0, stream>>>(he, indptr, eord, agg);
    mlp_ln<1><<<NN/32, 256, 0, stream>>>(hn, agg, un, nullptr, nullptr, nullptr,
        nw1l, nb1 + l*64, nw2 + (size_t)l*64*64, nb2 + l*64,
        nlg + l*64, nlb + l*64, hn);
    pmeans_kernel<<<GG*32, 256, 0, stream>>>(hn, he, pn, pe);
    fmeans_kernel<<<GG, 64, 0, stream>>>(pn, pe, nmean, emean);
    mlp_ln<2><<<GG/32, 256, 0, stream>>>(u, nmean, emean, nullptr, nullptr, nullptr,
        gw1 + (size_t)l*192*64, gb1 + l*64, gw2 + (size_t)l*64*64, gb2 + l*64,
        glg + l*64, glb + l*64, u);
  }

  heads_kernel<<<GG, 512, 0, stream>>>(hn, u, aw, ab, cw, cb, out);
}

// Round 5
// 571.288 us; speedup vs baseline: 2.9026x; 1.2037x over previous
//
#include <hip/hip_runtime.h>
#include <math.h>

#define GG 64
#define NPGc 512
#define NN (GG*NPGc)      // 32768 nodes
#define EE (NN*8)         // 262144 edges
#define HH 64
#define NL 3

// ---------------- threefry2x32 (JAX-compatible, partitionable mode) ----------------
__device__ __forceinline__ unsigned rotl32(unsigned x, int r){ return (x<<r)|(x>>(32-r)); }
__device__ __forceinline__ void threefry(unsigned k0, unsigned k1, unsigned x0, unsigned x1,
                                         unsigned &o0, unsigned &o1){
  unsigned ks2 = k0 ^ k1 ^ 0x1BD11BDAu;
  unsigned v0 = x0 + k0, v1 = x1 + k1;
#define R4(a,b,c,d) v0+=v1; v1=rotl32(v1,a); v1^=v0; v0+=v1; v1=rotl32(v1,b); v1^=v0; \
                    v0+=v1; v1=rotl32(v1,c); v1^=v0; v0+=v1; v1=rotl32(v1,d); v1^=v0;
  R4(13,15,26,6)  v0+=k1;  v1+=ks2+1u;
  R4(17,29,16,24) v0+=ks2; v1+=k0+2u;
  R4(13,15,26,6)  v0+=k0;  v1+=k1+3u;
  R4(17,29,16,24) v0+=k1;  v1+=ks2+4u;
  R4(13,15,26,6)  v0+=ks2; v1+=k0+5u;
#undef R4
  o0=v0; o1=v1;
}

// ---------------- node encoder: out = relu(in @ w + b), w is [K][64] ----------------
template<int K>
__global__ __launch_bounds__(256) void encode_kernel(const float* __restrict__ in,
    const float* __restrict__ w, const float* __restrict__ b,
    float* __restrict__ out, int rows)
{
  int wid = blockIdx.x*4 + (threadIdx.x>>6);
  int lane = threadIdx.x & 63;
  if (wid >= rows) return;
  const float* xr = in + (size_t)wid*K;
  float acc = b[lane];
#pragma unroll
  for (int i=0;i<K;i++) acc = fmaf(xr[i], w[i*64+lane], acc);
  out[(size_t)wid*64+lane] = fmaxf(acc, 0.f);
}

// ---------------- edge encoder, writes dst-sorted order: out[p] = relu(in[eord[p]]@w+b) ----
template<int K>
__global__ __launch_bounds__(256) void encode_gather_kernel(const float* __restrict__ in,
    const float* __restrict__ w, const float* __restrict__ b,
    const int* __restrict__ eord, float* __restrict__ out)
{
  int wid = blockIdx.x*4 + (threadIdx.x>>6);
  int lane = threadIdx.x & 63;
  const float* xr = in + (size_t)eord[wid]*K;
  float acc = b[lane];
#pragma unroll
  for (int i=0;i<K;i++) acc = fmaf(xr[i], w[i*64+lane], acc);
  out[(size_t)wid*64+lane] = fmaxf(acc, 0.f);
}

__global__ __launch_bounds__(256) void initu_kernel(const float* __restrict__ iu, float* __restrict__ u){
  int i = blockIdx.x*256 + threadIdx.x;
  if (i < GG*64) u[i] = iu[i & 63];
}

// ---------------- CSR build (deterministic aggregation) ----------------
__global__ __launch_bounds__(256) void count_kernel(const int* __restrict__ dst, int* __restrict__ cnt){
  int e = blockIdx.x*256 + threadIdx.x;
  if (e < EE) atomicAdd(&cnt[dst[e]], 1);
}
__global__ __launch_bounds__(1024) void scan_kernel(const int* __restrict__ cnt, int* __restrict__ indptr){
  __shared__ int part[1024];
  const int t = threadIdx.x;
  const int base = t*32;
  int s = 0;
  for (int i=0;i<32;i++) s += cnt[base+i];
  part[t] = s;
  __syncthreads();
  for (int off=1; off<1024; off<<=1){
    int v = part[t];
    int add = (t >= off) ? part[t-off] : 0;
    __syncthreads();
    part[t] = v + add;
    __syncthreads();
  }
  int run = (t==0) ? 0 : part[t-1];
  for (int i=0;i<32;i++){ indptr[base+i] = run; run += cnt[base+i]; }
  if (t==1023) indptr[NN] = run;
}
__global__ __launch_bounds__(256) void fill_kernel(const int* __restrict__ dst, const int* __restrict__ indptr,
                                                   int* __restrict__ fillc, int* __restrict__ eord){
  int e = blockIdx.x*256 + threadIdx.x;
  if (e < EE){ int dn = dst[e]; int p = atomicAdd(&fillc[dn], 1); eord[indptr[dn]+p] = e; }
}
__global__ __launch_bounds__(256) void sort_kernel(const int* __restrict__ indptr, int* __restrict__ eord){
  int n = blockIdx.x*256 + threadIdx.x;
  if (n >= NN) return;
  int lo = indptr[n], hi = indptr[n+1];
  for (int i=lo+1;i<hi;i++){
    int v = eord[i]; int j = i-1;
    while (j >= lo && eord[j] > v){ eord[j+1]=eord[j]; j--; }
    eord[j+1] = v;
  }
}
__global__ __launch_bounds__(256) void perm_kernel(const int* __restrict__ src, const int* __restrict__ dst,
                                                   const int* __restrict__ eord,
                                                   int* __restrict__ srcs, int* __restrict__ dsts){
  int p = blockIdx.x*256 + threadIdx.x;
  if (p < EE){ int e = eord[p]; srcs[p] = src[e]; dsts[p] = dst[e]; }
}

// ---------------- agg[n] = sum of he_sorted rows [indptr[n],indptr[n+1]) — contiguous ----------------
__global__ __launch_bounds__(256) void agg_kernel(const float* __restrict__ he, const int* __restrict__ indptr,
                                                  float* __restrict__ agg){
  int tid = blockIdx.x*256 + threadIdx.x;
  int n = tid >> 4, cq = tid & 15;
  if (n >= NN) return;
  float4 s = {0.f,0.f,0.f,0.f};
  int lo = indptr[n], hi = indptr[n+1];
  const float4* he4 = (const float4*)he;
  for (int p=lo;p<hi;++p){
    float4 v = he4[(size_t)p*16 + cq];
    s.x+=v.x; s.y+=v.y; s.z+=v.z; s.w+=v.w;
  }
  ((float4*)(agg + (size_t)n*64))[cq] = s;
}

// ---------------- per-graph means from hn + agg (16 MB total), 2-stage ----------------
// stage 1: 64 graphs x 4 chunks of 128 node-rows
__global__ __launch_bounds__(256) void pmeans_kernel(const float* __restrict__ hn, const float* __restrict__ agg,
                                                     float* __restrict__ pn, float* __restrict__ pe){
  const int b = blockIdx.x, g = b >> 2, c = b & 3;
  const int t = threadIdx.x, cq = t & 15, part = t >> 4;
  const float4* A = (const float4*)(hn  + ((size_t)g*512 + (size_t)c*128)*64);
  const float4* B = (const float4*)(agg + ((size_t)g*512 + (size_t)c*128)*64);
  float4 ns = {0,0,0,0}, es = {0,0,0,0};
  for (int r = part; r < 128; r += 16){
    float4 a = A[r*16 + cq], e = B[r*16 + cq];
    ns.x+=a.x; ns.y+=a.y; ns.z+=a.z; ns.w+=a.w;
    es.x+=e.x; es.y+=e.y; es.z+=e.z; es.w+=e.w;
  }
  __shared__ float4 sbn[16][16], sbe[16][16];
  sbn[part][cq] = ns; sbe[part][cq] = es;
  __syncthreads();
  if (part == 0){
    float4 sn = sbn[0][cq], se = sbe[0][cq];
    for (int p=1;p<16;p++){
      float4 vn = sbn[p][cq], ve = sbe[p][cq];
      sn.x+=vn.x; sn.y+=vn.y; sn.z+=vn.z; sn.w+=vn.w;
      se.x+=ve.x; se.y+=ve.y; se.z+=ve.z; se.w+=ve.w;
    }
    ((float4*)pn)[(g*4+c)*16 + cq] = sn;
    ((float4*)pe)[(g*4+c)*16 + cq] = se;
  }
}
__global__ __launch_bounds__(64) void fmeans_kernel(const float* __restrict__ pn, const float* __restrict__ pe,
                                                    float* __restrict__ nmean, float* __restrict__ emean){
  const int g = blockIdx.x, col = threadIdx.x;
  float ns = 0.f, es = 0.f;
  for (int c=0;c<4;c++){
    ns += pn[(g*4+c)*64 + col];
    es += pe[(g*4+c)*64 + col];
  }
  nmean[g*64+col] = ns * (1.f/512.f);
  emean[g*64+col] = es * (1.f/4096.f);   // sum(agg) over graph == sum(he) over graph edges
}

// ---------------- pre_kernel: oa = x@wa, ob = x@wb  (x: rows x 64, w: 64x64) ----------------
__global__ __launch_bounds__(256) void pre_kernel(const float* __restrict__ x,
    const float* __restrict__ wa, const float* __restrict__ wb,
    float* __restrict__ oa, float* __restrict__ ob, int rows)
{
  __shared__ float4 xs4[32*17];
  __shared__ float4 wsa[1024], wsb[1024];
  const int t = threadIdx.x;
  const int rowbase = blockIdx.x*32;
  {
    const int gi16 = t>>4, lg = t&15;
#pragma unroll
    for (int it=0; it<2; ++it){
      int er = gi16 + (it<<4);
      xs4[er*17+lg] = ((const float4*)(x + (size_t)64*(rowbase+er)))[lg];
    }
  }
  const float4* wa4 = (const float4*)wa;
  const float4* wb4 = (const float4*)wb;
#pragma unroll
  for (int i=0;i<4;i++){ wsa[t+i*256] = wa4[t+i*256]; wsb[t+i*256] = wb4[t+i*256]; }
  __syncthreads();

  const int r0 = (t>>4)*2, cq = t&15;
  float accA[2][4] = {{0,0,0,0},{0,0,0,0}};
  float accB[2][4] = {{0,0,0,0},{0,0,0,0}};
#pragma unroll
  for (int k4=0;k4<16;k4++){
    float4 a0 = xs4[(r0  )*17 + k4];
    float4 a1 = xs4[(r0+1)*17 + k4];
    const float* a0p = (const float*)&a0;
    const float* a1p = (const float*)&a1;
#pragma unroll
    for (int kk=0;kk<4;kk++){
      float4 ba = wsa[(k4*4+kk)*16 + cq];
      float4 bb = wsb[(k4*4+kk)*16 + cq];
      accA[0][0]=fmaf(a0p[kk],ba.x,accA[0][0]); accA[0][1]=fmaf(a0p[kk],ba.y,accA[0][1]);
      accA[0][2]=fmaf(a0p[kk],ba.z,accA[0][2]); accA[0][3]=fmaf(a0p[kk],ba.w,accA[0][3]);
      accA[1][0]=fmaf(a1p[kk],ba.x,accA[1][0]); accA[1][1]=fmaf(a1p[kk],ba.y,accA[1][1]);
      accA[1][2]=fmaf(a1p[kk],ba.z,accA[1][2]); accA[1][3]=fmaf(a1p[kk],ba.w,accA[1][3]);
      accB[0][0]=fmaf(a0p[kk],bb.x,accB[0][0]); accB[0][1]=fmaf(a0p[kk],bb.y,accB[0][1]);
      accB[0][2]=fmaf(a0p[kk],bb.z,accB[0][2]); accB[0][3]=fmaf(a0p[kk],bb.w,accB[0][3]);
      accB[1][0]=fmaf(a1p[kk],bb.x,accB[1][0]); accB[1][1]=fmaf(a1p[kk],bb.y,accB[1][1]);
      accB[1][2]=fmaf(a1p[kk],bb.z,accB[1][2]); accB[1][3]=fmaf(a1p[kk],bb.w,accB[1][3]);
    }
  }
#pragma unroll
  for (int rr=0; rr<2; rr++){
    size_t row = rowbase + r0 + rr;
    float4 va = {accA[rr][0],accA[rr][1],accA[rr][2],accA[rr][3]};
    float4 vb = {accB[rr][0],accB[rr][1],accB[rr][2],accB[rr][3]};
    ((float4*)(oa + row*64))[cq] = va;
    ((float4*)(ob + row*64))[cq] = vb;
  }
}

// ---------------- edge MLP: rows = dst-sorted edges, 64 rows/block, 4x4 thread tile ----------------
// out = LN(relu(he@w1 + pa[src]+pb[dst]+ue[g] + b1) @ w2 + b2)
__global__ __launch_bounds__(256) void edge_mlp(
    const float* __restrict__ he, const float* __restrict__ pa,
    const float* __restrict__ pb, const float* __restrict__ ue,
    const int* __restrict__ srcs, const int* __restrict__ dsts,
    const float* __restrict__ w1, const float* __restrict__ b1,
    const float* __restrict__ w2, const float* __restrict__ b2,
    const float* __restrict__ lng, const float* __restrict__ lnb,
    float* __restrict__ outp)
{
  __shared__ float4 xs4[64*17];   // 64 input rows (reused for h1)
  __shared__ float4 ws4[1024];    // weight chunk
  __shared__ float  bsm[5][64];

  const int t = threadIdx.x;
  const int rowbase = blockIdx.x*64;
  const int g = rowbase >> 12;
  const int r0 = (t >> 4) * 4, cq = t & 15;

  if (t < 64){ bsm[0][t] = b1[t]; bsm[4][t] = ue[(g<<6)+t]; }
  else if (t < 128) bsm[1][t-64]  = b2[t-64];
  else if (t < 192) bsm[2][t-128] = lng[t-128];
  else              bsm[3][t-192] = lnb[t-192];

  // issue epilogue gathers early (coalesced 256B rows, hidden under GEMM1)
  int si[4], di[4];
#pragma unroll
  for (int r=0;r<4;r++){ si[r] = srcs[rowbase+r0+r]; di[r] = dsts[rowbase+r0+r]; }
  float4 exa[4], exb[4];
#pragma unroll
  for (int r=0;r<4;r++){
    exa[r] = ((const float4*)(pa + (size_t)64*si[r]))[cq];
    exb[r] = ((const float4*)(pb + (size_t)64*di[r]))[cq];
  }

  // stage he rows (coalesced) + w1
  {
    const float4* heb = (const float4*)(he + (size_t)rowbase*64);
#pragma unroll
    for (int i=0;i<4;i++){
      int idx = t + i*256;
      xs4[(idx>>4)*17 + (idx&15)] = heb[idx];
    }
    const float4* w1g4 = (const float4*)w1;
#pragma unroll
    for (int i=0;i<4;i++) ws4[t+i*256] = w1g4[t+i*256];
  }
  __syncthreads();

  // GEMM1 (K=64)
  float acc[4][4] = {{0,0,0,0},{0,0,0,0},{0,0,0,0},{0,0,0,0}};
#pragma unroll
  for (int k4=0;k4<16;k4++){
    float4 a[4];
#pragma unroll
    for (int r=0;r<4;r++) a[r] = xs4[(r0+r)*17 + k4];
    float4 bb[4];
#pragma unroll
    for (int kk=0;kk<4;kk++) bb[kk] = ws4[(k4*4+kk)*16 + cq];
#pragma unroll
    for (int kk=0;kk<4;kk++){
      const float4 b = bb[kk];
#pragma unroll
      for (int r=0;r<4;r++){
        const float av = ((const float*)&a[r])[kk];
        acc[r][0]=fmaf(av,b.x,acc[r][0]);
        acc[r][1]=fmaf(av,b.y,acc[r][1]);
        acc[r][2]=fmaf(av,b.z,acc[r][2]);
        acc[r][3]=fmaf(av,b.w,acc[r][3]);
      }
    }
  }

  // h1 = relu(acc + b1 + pa[src]+pb[dst]+ue[g]) -> xs4 ; stage w2
  __syncthreads();
#pragma unroll
  for (int r=0;r<4;r++){
    float4 h;
    h.x = fmaxf(acc[r][0]+bsm[0][cq*4+0]+exa[r].x+exb[r].x+bsm[4][cq*4+0], 0.f);
    h.y = fmaxf(acc[r][1]+bsm[0][cq*4+1]+exa[r].y+exb[r].y+bsm[4][cq*4+1], 0.f);
    h.z = fmaxf(acc[r][2]+bsm[0][cq*4+2]+exa[r].z+exb[r].z+bsm[4][cq*4+2], 0.f);
    h.w = fmaxf(acc[r][3]+bsm[0][cq*4+3]+exa[r].w+exb[r].w+bsm[4][cq*4+3], 0.f);
    xs4[(r0+r)*17 + cq] = h;
  }
  {
    const float4* w2g4 = (const float4*)w2;
#pragma unroll
    for (int i=0;i<4;i++) ws4[t+i*256] = w2g4[t+i*256];
  }
  __syncthreads();

  // GEMM2 (K=64)
  float acc2[4][4] = {{0,0,0,0},{0,0,0,0},{0,0,0,0},{0,0,0,0}};
#pragma unroll
  for (int k4=0;k4<16;k4++){
    float4 a[4];
#pragma unroll
    for (int r=0;r<4;r++) a[r] = xs4[(r0+r)*17 + k4];
    float4 bb[4];
#pragma unroll
    for (int kk=0;kk<4;kk++) bb[kk] = ws4[(k4*4+kk)*16 + cq];
#pragma unroll
    for (int kk=0;kk<4;kk++){
      const float4 b = bb[kk];
#pragma unroll
      for (int r=0;r<4;r++){
        const float av = ((const float*)&a[r])[kk];
        acc2[r][0]=fmaf(av,b.x,acc2[r][0]);
        acc2[r][1]=fmaf(av,b.y,acc2[r][1]);
        acc2[r][2]=fmaf(av,b.z,acc2[r][2]);
        acc2[r][3]=fmaf(av,b.w,acc2[r][3]);
      }
    }
  }

  // LayerNorm over 64 (16-lane-group shfl reduce) + store
#pragma unroll
  for (int r=0;r<4;r++){
    float v0 = acc2[r][0] + bsm[1][cq*4+0];
    float v1 = acc2[r][1] + bsm[1][cq*4+1];
    float v2 = acc2[r][2] + bsm[1][cq*4+2];
    float v3 = acc2[r][3] + bsm[1][cq*4+3];
    float sA = v0+v1+v2+v3;
    float sB = v0*v0+v1*v1+v2*v2+v3*v3;
#pragma unroll
    for (int m=1;m<16;m<<=1){ sA += __shfl_xor(sA,m); sB += __shfl_xor(sB,m); }
    float mean = sA * 0.015625f;
    float var  = sB * 0.015625f - mean*mean;
    float inv  = 1.0f / sqrtf(var + 1e-5f);
    float4 o;
    o.x = (v0-mean)*inv*bsm[2][cq*4+0] + bsm[3][cq*4+0];
    o.y = (v1-mean)*inv*bsm[2][cq*4+1] + bsm[3][cq*4+1];
    o.z = (v2-mean)*inv*bsm[2][cq*4+2] + bsm[3][cq*4+2];
    o.w = (v3-mean)*inv*bsm[2][cq*4+3] + bsm[3][cq*4+3];
    ((float4*)(outp + (size_t)(rowbase + r0 + r)*64))[cq] = o;
  }
}

// ---------------- fused  LN(relu(x@w1+b1)@w2+b2)  for node/global ----------------
// MODE 1: node rows (DIN=128: [hn,agg]), epilogue add un[g], g=row>>9
// MODE 2: graph rows (DIN=192: [u,nmean,emean])
template<int MODE>
__global__ __launch_bounds__(256) void mlp_ln(
    const float* __restrict__ s0, const float* __restrict__ s1,
    const float* __restrict__ s2,
    const float* __restrict__ w1, const float* __restrict__ b1,
    const float* __restrict__ w2, const float* __restrict__ b2,
    const float* __restrict__ lng, const float* __restrict__ lnb,
    float* __restrict__ outp)
{
  constexpr int DIN  = (MODE==1) ? 128 : 192;
  constexpr int NSEG = DIN/64;
  constexpr int DP4  = DIN/4 + 1;

  __shared__ float4 xs4[32*DP4];
  __shared__ float4 ws4[1024];
  __shared__ float  bsm[5][64];

  const int t = threadIdx.x;
  const int rowbase = blockIdx.x*32;

  if (t < 64)       bsm[0][t]     = b1[t];
  else if (t < 128) bsm[1][t-64]  = b2[t-64];
  else if (t < 192) bsm[2][t-128] = lng[t-128];
  else              bsm[3][t-192] = lnb[t-192];

  if constexpr (MODE==1){
    const int g = rowbase >> 9;
    if (t < 64) bsm[4][t] = s2[(g<<6)+t];
  }

  {
    const int gi16 = t >> 4, lg = t & 15;
#pragma unroll
    for (int it = 0; it < 2*NSEG; ++it){
      int pair = gi16 + (it << 4);
      int er = pair & 31, seg = pair >> 5;
      int row = rowbase + er;
      const float* bp = ((seg==0)? s0 : (seg==1)? s1 : s2) + (size_t)64*row;
      xs4[er*DP4 + seg*16 + lg] = ((const float4*)bp)[lg];
    }
  }
  __syncthreads();

  const int r0 = (t >> 4) * 2, cq = t & 15;
  float acc[2][4] = {{0.f,0.f,0.f,0.f},{0.f,0.f,0.f,0.f}};
  const float4* w1g4 = (const float4*)w1;

  for (int kc = 0; kc < DIN; kc += 64){
    __syncthreads();
    ws4[t]     = w1g4[kc*16 + t];
    ws4[t+256] = w1g4[kc*16 + t + 256];
    ws4[t+512] = w1g4[kc*16 + t + 512];
    ws4[t+768] = w1g4[kc*16 + t + 768];
    __syncthreads();
#pragma unroll
    for (int k4=0;k4<16;k4++){
      float4 a0 = xs4[(r0  )*DP4 + (kc>>2) + k4];
      float4 a1 = xs4[(r0+1)*DP4 + (kc>>2) + k4];
      float4 bb[4];
#pragma unroll
      for (int kk=0;kk<4;kk++) bb[kk] = ws4[(k4*4+kk)*16 + cq];
      const float* a0p = (const float*)&a0;
      const float* a1p = (const float*)&a1;
#pragma unroll
      for (int kk=0;kk<4;kk++){
        acc[0][0]=fmaf(a0p[kk],bb[kk].x,acc[0][0]);
        acc[0][1]=fmaf(a0p[kk],bb[kk].y,acc[0][1]);
        acc[0][2]=fmaf(a0p[kk],bb[kk].z,acc[0][2]);
        acc[0][3]=fmaf(a0p[kk],bb[kk].w,acc[0][3]);
        acc[1][0]=fmaf(a1p[kk],bb[kk].x,acc[1][0]);
        acc[1][1]=fmaf(a1p[kk],bb[kk].y,acc[1][1]);
        acc[1][2]=fmaf(a1p[kk],bb[kk].z,acc[1][2]);
        acc[1][3]=fmaf(a1p[kk],bb[kk].w,acc[1][3]);
      }
    }
  }

  float4 ex;
  if constexpr (MODE==1){
    ex.x = bsm[4][cq*4+0]; ex.y = bsm[4][cq*4+1];
    ex.z = bsm[4][cq*4+2]; ex.w = bsm[4][cq*4+3];
  } else {
    ex.x = ex.y = ex.z = ex.w = 0.f;
  }

  __syncthreads();
  {
    float4 h0, h1v;
    h0.x  = fmaxf(acc[0][0]+bsm[0][cq*4+0]+ex.x, 0.f);
    h0.y  = fmaxf(acc[0][1]+bsm[0][cq*4+1]+ex.y, 0.f);
    h0.z  = fmaxf(acc[0][2]+bsm[0][cq*4+2]+ex.z, 0.f);
    h0.w  = fmaxf(acc[0][3]+bsm[0][cq*4+3]+ex.w, 0.f);
    h1v.x = fmaxf(acc[1][0]+bsm[0][cq*4+0]+ex.x, 0.f);
    h1v.y = fmaxf(acc[1][1]+bsm[0][cq*4+1]+ex.y, 0.f);
    h1v.z = fmaxf(acc[1][2]+bsm[0][cq*4+2]+ex.z, 0.f);
    h1v.w = fmaxf(acc[1][3]+bsm[0][cq*4+3]+ex.w, 0.f);
    xs4[(r0  )*DP4 + cq] = h0;
    xs4[(r0+1)*DP4 + cq] = h1v;
    const float4* w2g4 = (const float4*)w2;
    ws4[t]     = w2g4[t];
    ws4[t+256] = w2g4[t+256];
    ws4[t+512] = w2g4[t+512];
    ws4[t+768] = w2g4[t+768];
  }
  __syncthreads();

  float acc2[2][4] = {{0.f,0.f,0.f,0.f},{0.f,0.f,0.f,0.f}};
#pragma unroll
  for (int k4=0;k4<16;k4++){
    float4 a0 = xs4[(r0  )*DP4 + k4];
    float4 a1 = xs4[(r0+1)*DP4 + k4];
    float4 bb[4];
#pragma unroll
    for (int kk=0;kk<4;kk++) bb[kk] = ws4[(k4*4+kk)*16 + cq];
    const float* a0p = (const float*)&a0;
    const float* a1p = (const float*)&a1;
#pragma unroll
    for (int kk=0;kk<4;kk++){
      acc2[0][0]=fmaf(a0p[kk],bb[kk].x,acc2[0][0]);
      acc2[0][1]=fmaf(a0p[kk],bb[kk].y,acc2[0][1]);
      acc2[0][2]=fmaf(a0p[kk],bb[kk].z,acc2[0][2]);
      acc2[0][3]=fmaf(a0p[kk],bb[kk].w,acc2[0][3]);
      acc2[1][0]=fmaf(a1p[kk],bb[kk].x,acc2[1][0]);
      acc2[1][1]=fmaf(a1p[kk],bb[kk].y,acc2[1][1]);
      acc2[1][2]=fmaf(a1p[kk],bb[kk].z,acc2[1][2]);
      acc2[1][3]=fmaf(a1p[kk],bb[kk].w,acc2[1][3]);
    }
  }

#pragma unroll
  for (int rr=0; rr<2; rr++){
    float v0 = acc2[rr][0] + bsm[1][cq*4+0];
    float v1 = acc2[rr][1] + bsm[1][cq*4+1];
    float v2 = acc2[rr][2] + bsm[1][cq*4+2];
    float v3 = acc2[rr][3] + bsm[1][cq*4+3];
    float sA = v0+v1+v2+v3;
    float sB = v0*v0+v1*v1+v2*v2+v3*v3;
#pragma unroll
    for (int m=1;m<16;m<<=1){ sA += __shfl_xor(sA,m); sB += __shfl_xor(sB,m); }
    float mean = sA * 0.015625f;
    float var  = sB * 0.015625f - mean*mean;
    float inv  = 1.0f / sqrtf(var + 1e-5f);
    float4 o;
    o.x = (v0-mean)*inv*bsm[2][cq*4+0] + bsm[3][cq*4+0];
    o.y = (v1-mean)*inv*bsm[2][cq*4+1] + bsm[3][cq*4+1];
    o.z = (v2-mean)*inv*bsm[2][cq*4+2] + bsm[3][cq*4+2];
    o.w = (v3-mean)*inv*bsm[2][cq*4+3] + bsm[3][cq*4+3];
    ((float4*)(outp + (size_t)(rowbase + r0 + rr)*64))[cq] = o;
  }
}

// ---------------- heads ----------------
__global__ __launch_bounds__(512) void heads_kernel(
    const float* __restrict__ hn, const float* __restrict__ uvec,
    const float* __restrict__ aw, const float* __restrict__ ab,
    const float* __restrict__ cw, const float* __restrict__ cb,
    float* __restrict__ out)
{
  const int g = blockIdx.x, t = threadIdx.x;
  const int n = (g<<9) + t;
  const float4* hp = (const float4*)(hn + (size_t)n*64);
  const float4* ap = (const float4*)aw;
  float d = 0.f;
#pragma unroll
  for (int i=0;i<16;i++){
    float4 h = hp[i], a = ap[i];
    d += h.x*a.x + h.y*a.y + h.z*a.z + h.w*a.w;
  }
  d += ab[0];
  float z = 1.0f/(1.0f + expf(-d));

  unsigned o0,o1;
  threefry(0u, 42u, 0u, (unsigned)n, o0, o1);
  unsigned bits = o0 ^ o1;
  float f = __uint_as_float((bits>>9) | 0x3f800000u) - 1.0f;
  float gum = -logf(-logf(fmaxf(1.17549435e-38f, f)));

  const int lane = t & 63, wid = t >> 6;
  __shared__ float smax[8], ssum[8], sent[8], skey[8];
  __shared__ int   sidx[8];
  __shared__ float sM, sS;
  __shared__ int   sA;

  float m = z;
#pragma unroll
  for (int sh=1; sh<64; sh<<=1) m = fmaxf(m, __shfl_xor(m, sh));
  if (lane==0) smax[wid] = m;
  __syncthreads();
  if (t==0){ float mm=smax[0]; for(int i=1;i<8;i++) mm=fmaxf(mm,smax[i]); sM=mm; }
  __syncthreads();
  float M = sM;
  float ex = expf(z - M);
  float ssl = ex;
#pragma unroll
  for (int sh=1; sh<64; sh<<=1) ssl += __shfl_xor(ssl, sh);
  if (lane==0) ssum[wid] = ssl;
  __syncthreads();
  if (t==0){ float ss=0.f; for(int i=0;i<8;i++) ss+=ssum[i]; sS=ss; }
  __syncthreads();
  float logp = z - M - logf(sS);
  float p = expf(logp);
  float entl = p * logp;
#pragma unroll
  for (int sh=1; sh<64; sh<<=1) entl += __shfl_xor(entl, sh);
  if (lane==0) sent[wid] = entl;

  float kv = z + gum; int ki = t;
#pragma unroll
  for (int sh=1; sh<64; sh<<=1){
    float ov = __shfl_xor(kv, sh);
    int   oi = __shfl_xor(ki, sh);
    if (ov > kv || (ov == kv && oi < ki)){ kv = ov; ki = oi; }
  }
  if (lane==0){ skey[wid] = kv; sidx[wid] = ki; }
  __syncthreads();
  if (t==0){
    float bv = skey[0]; int bi = sidx[0];
    for (int i=1;i<8;i++) if (skey[i] > bv || (skey[i]==bv && sidx[i] < bi)){ bv=skey[i]; bi=sidx[i]; }
    sA = bi;
    float ent = 0.f; for (int i=0;i<8;i++) ent += sent[i];
    out[g]      = (float)bi;
    out[128+g]  = -ent;
  }
  __syncthreads();
  if (t == sA) out[64+g] = logp;

  if (t < 64){
    float pv = uvec[(g<<6)+t] * cw[t];
#pragma unroll
    for (int sh=1; sh<64; sh<<=1) pv += __shfl_xor(pv, sh);
    if (t==0) out[192+g] = pv + cb[0];
  }
}

// ---------------- launch ----------------
extern "C" void kernel_launch(void* const* d_in, const int* in_sizes, int n_in,
                              void* d_out, int out_size, void* d_ws, size_t ws_size,
                              hipStream_t stream)
{
  (void)in_sizes; (void)n_in; (void)out_size; (void)ws_size;
  const float* x      = (const float*)d_in[0];
  const float* eattr  = (const float*)d_in[1];
  const int*   eidx   = (const int*)d_in[2];
  const float* node_w = (const float*)d_in[5];
  const float* node_b = (const float*)d_in[6];
  const float* edge_w = (const float*)d_in[7];
  const float* edge_b = (const float*)d_in[8];
  const float* init_u = (const float*)d_in[9];
  const float* ew1 = (const float*)d_in[10]; const float* eb1 = (const float*)d_in[11];
  const float* ew2 = (const float*)d_in[12]; const float* eb2 = (const float*)d_in[13];
  const float* elg = (const float*)d_in[14]; const float* elb = (const float*)d_in[15];
  const float* nw1 = (const float*)d_in[16]; const float* nb1 = (const float*)d_in[17];
  const float* nw2 = (const float*)d_in[18]; const float* nb2 = (const float*)d_in[19];
  const float* nlg = (const float*)d_in[20]; const float* nlb = (const float*)d_in[21];
  const float* gw1 = (const float*)d_in[22]; const float* gb1 = (const float*)d_in[23];
  const float* gw2 = (const float*)d_in[24]; const float* gb2 = (const float*)d_in[25];
  const float* glg = (const float*)d_in[26]; const float* glb = (const float*)d_in[27];
  const float* aw  = (const float*)d_in[28]; const float* ab  = (const float*)d_in[29];
  const float* cw  = (const float*)d_in[30]; const float* cb  = (const float*)d_in[31];
  const int* src = eidx;
  const int* dst = eidx + EE;

  float* ws    = (float*)d_ws;
  float* hn    = ws;                         // N*64
  float* he    = hn + (size_t)NN*64;         // E*64  (dst-sorted order)
  float* agg   = he + (size_t)EE*64;         // N*64
  float* u     = agg + (size_t)NN*64;        // G*64
  float* nmean = u + GG*64;
  float* emean = nmean + GG*64;
  int* cnt     = (int*)(emean + GG*64);      // N
  int* indptr  = cnt + NN;                   // N+1
  int* fillc   = indptr + NN + 1;            // N
  int* eord    = fillc + NN;                 // E
  int* srcs    = eord + EE;                  // E (sorted-order src)
  int* dsts    = srcs + EE;                  // E (sorted-order dst)
  float* pb    = (float*)(dsts + EE);        // N*64
  float* ue    = pb + (size_t)NN*64;         // G*64
  float* un    = ue + GG*64;                 // G*64
  float* pn    = un + GG*64;                 // G*4*64
  float* pe    = pn + GG*4*64;               // G*4*64

  float* pa = agg;   // pa aliases agg: written by pre, consumed by edge_mlp, then agg overwrites

  float* out = (float*)d_out;

  hipMemsetAsync(cnt,   0, NN*sizeof(int), stream);
  hipMemsetAsync(fillc, 0, NN*sizeof(int), stream);

  // CSR + permutation (needed before edge encode now)
  count_kernel<<<EE/256, 256, 0, stream>>>(dst, cnt);
  scan_kernel<<<1, 1024, 0, stream>>>(cnt, indptr);
  fill_kernel<<<EE/256, 256, 0, stream>>>(dst, indptr, fillc, eord);
  sort_kernel<<<NN/256, 256, 0, stream>>>(indptr, eord);
  perm_kernel<<<EE/256, 256, 0, stream>>>(src, dst, eord, srcs, dsts);

  encode_kernel<32><<<NN/4, 256, 0, stream>>>(x, node_w, node_b, hn, NN);
  encode_gather_kernel<16><<<EE/4, 256, 0, stream>>>(eattr, edge_w, edge_b, eord, he);
  initu_kernel<<<16, 256, 0, stream>>>(init_u, u);

  for (int l=0; l<NL; ++l){
    const float* ew1l = ew1 + (size_t)l*256*64;
    const float* nw1l = nw1 + (size_t)l*192*64;
    pre_kernel<<<NN/32, 256, 0, stream>>>(hn, ew1l, ew1l + 64*64, pa, pb, NN);
    pre_kernel<<<2, 256, 0, stream>>>(u, ew1l + 192*64, nw1l + 128*64, ue, un, GG);

    edge_mlp<<<EE/64, 256, 0, stream>>>(he, pa, pb, ue, srcs, dsts,
        ew1l + 128*64, eb1 + l*64, ew2 + (size_t)l*64*64, eb2 + l*64,
        elg + l*64, elb + l*64, he);
    agg_kernel<<<NN*16/256, 256, 0, stream>>>(he, indptr, agg);
    mlp_ln<1><<<NN/32, 256, 0, stream>>>(hn, agg, un,
        nw1l, nb1 + l*64, nw2 + (size_t)l*64*64, nb2 + l*64,
        nlg + l*64, nlb + l*64, hn);
    pmeans_kernel<<<GG*4, 256, 0, stream>>>(hn, agg, pn, pe);
    fmeans_kernel<<<GG, 64, 0, stream>>>(pn, pe, nmean, emean);
    mlp_ln<2><<<GG/32, 256, 0, stream>>>(u, nmean, emean,
        gw1 + (size_t)l*192*64, gb1 + l*64, gw2 + (size_t)l*64*64, gb2 + l*64,
        glg + l*64, glb + l*64, u);
  }

  heads_kernel<<<GG, 512, 0, stream>>>(hn, u, aw, ab, cw, cb, out);
}

// Round 6
// 499.224 us; speedup vs baseline: 3.3216x; 1.1444x over previous
//
#include <hip/hip_runtime.h>
#include <math.h>

#define GG 64
#define NPGc 512
#define NN (GG*NPGc)      // 32768 nodes
#define EE (NN*8)         // 262144 edges
#define HH 64
#define NL 3

typedef __attribute__((ext_vector_type(8))) short short8b;
typedef __attribute__((ext_vector_type(4))) float f32x4;

// ---------------- bf16 split helpers ----------------
__device__ __forceinline__ unsigned short f2bf_rne(float f){
  unsigned u = __float_as_uint(f);
  unsigned r = u + 0x7fffu + ((u>>16)&1u);
  return (unsigned short)(r>>16);
}
__device__ __forceinline__ float bf2f(unsigned short h){
  return __uint_as_float(((unsigned)h)<<16);
}
__device__ __forceinline__ void mk_frag(const float4 &u, const float4 &v, short8b &hi, short8b &lo){
  float av[8] = {u.x,u.y,u.z,u.w,v.x,v.y,v.z,v.w};
#pragma unroll
  for (int j=0;j<8;j++){
    unsigned short h = f2bf_rne(av[j]);
    hi[j] = (short)h;
    lo[j] = (short)f2bf_rne(av[j] - bf2f(h));
  }
}

// ---------------- threefry2x32 (JAX-compatible, partitionable mode) ----------------
__device__ __forceinline__ unsigned rotl32(unsigned x, int r){ return (x<<r)|(x>>(32-r)); }
__device__ __forceinline__ void threefry(unsigned k0, unsigned k1, unsigned x0, unsigned x1,
                                         unsigned &o0, unsigned &o1){
  unsigned ks2 = k0 ^ k1 ^ 0x1BD11BDAu;
  unsigned v0 = x0 + k0, v1 = x1 + k1;
#define R4(a,b,c,d) v0+=v1; v1=rotl32(v1,a); v1^=v0; v0+=v1; v1=rotl32(v1,b); v1^=v0; \
                    v0+=v1; v1=rotl32(v1,c); v1^=v0; v0+=v1; v1=rotl32(v1,d); v1^=v0;
  R4(13,15,26,6)  v0+=k1;  v1+=ks2+1u;
  R4(17,29,16,24) v0+=ks2; v1+=k0+2u;
  R4(13,15,26,6)  v0+=k0;  v1+=k1+3u;
  R4(17,29,16,24) v0+=k1;  v1+=ks2+4u;
  R4(13,15,26,6)  v0+=ks2; v1+=k0+5u;
#undef R4
  o0=v0; o1=v1;
}

// ---------------- node encoder ----------------
template<int K>
__global__ __launch_bounds__(256) void encode_kernel(const float* __restrict__ in,
    const float* __restrict__ w, const float* __restrict__ b,
    float* __restrict__ out, int rows)
{
  int wid = blockIdx.x*4 + (threadIdx.x>>6);
  int lane = threadIdx.x & 63;
  if (wid >= rows) return;
  const float* xr = in + (size_t)wid*K;
  float acc = b[lane];
#pragma unroll
  for (int i=0;i<K;i++) acc = fmaf(xr[i], w[i*64+lane], acc);
  out[(size_t)wid*64+lane] = fmaxf(acc, 0.f);
}

// ---------------- edge encoder, dst-sorted output ----------------
template<int K>
__global__ __launch_bounds__(256) void encode_gather_kernel(const float* __restrict__ in,
    const float* __restrict__ w, const float* __restrict__ b,
    const int* __restrict__ eord, float* __restrict__ out)
{
  int wid = blockIdx.x*4 + (threadIdx.x>>6);
  int lane = threadIdx.x & 63;
  const float* xr = in + (size_t)eord[wid]*K;
  float acc = b[lane];
#pragma unroll
  for (int i=0;i<K;i++) acc = fmaf(xr[i], w[i*64+lane], acc);
  out[(size_t)wid*64+lane] = fmaxf(acc, 0.f);
}

__global__ __launch_bounds__(256) void initu_kernel(const float* __restrict__ iu, float* __restrict__ u){
  int i = blockIdx.x*256 + threadIdx.x;
  if (i < GG*64) u[i] = iu[i & 63];
}

// ---------------- CSR build ----------------
__global__ __launch_bounds__(256) void count_kernel(const int* __restrict__ dst, int* __restrict__ cnt){
  int e = blockIdx.x*256 + threadIdx.x;
  if (e < EE) atomicAdd(&cnt[dst[e]], 1);
}
__global__ __launch_bounds__(1024) void scan_kernel(const int* __restrict__ cnt, int* __restrict__ indptr){
  __shared__ int part[1024];
  const int t = threadIdx.x;
  const int base = t*32;
  int s = 0;
  for (int i=0;i<32;i++) s += cnt[base+i];
  part[t] = s;
  __syncthreads();
  for (int off=1; off<1024; off<<=1){
    int v = part[t];
    int add = (t >= off) ? part[t-off] : 0;
    __syncthreads();
    part[t] = v + add;
    __syncthreads();
  }
  int run = (t==0) ? 0 : part[t-1];
  for (int i=0;i<32;i++){ indptr[base+i] = run; run += cnt[base+i]; }
  if (t==1023) indptr[NN] = run;
}
__global__ __launch_bounds__(256) void fill_kernel(const int* __restrict__ dst, const int* __restrict__ indptr,
                                                   int* __restrict__ fillc, int* __restrict__ eord){
  int e = blockIdx.x*256 + threadIdx.x;
  if (e < EE){ int dn = dst[e]; int p = atomicAdd(&fillc[dn], 1); eord[indptr[dn]+p] = e; }
}
__global__ __launch_bounds__(256) void sort_kernel(const int* __restrict__ indptr, int* __restrict__ eord){
  int n = blockIdx.x*256 + threadIdx.x;
  if (n >= NN) return;
  int lo = indptr[n], hi = indptr[n+1];
  for (int i=lo+1;i<hi;i++){
    int v = eord[i]; int j = i-1;
    while (j >= lo && eord[j] > v){ eord[j+1]=eord[j]; j--; }
    eord[j+1] = v;
  }
}
__global__ __launch_bounds__(256) void perm_kernel(const int* __restrict__ src, const int* __restrict__ dst,
                                                   const int* __restrict__ eord,
                                                   int* __restrict__ srcs, int* __restrict__ dsts){
  int p = blockIdx.x*256 + threadIdx.x;
  if (p < EE){ int e = eord[p]; srcs[p] = src[e]; dsts[p] = dst[e]; }
}

// ---------------- agg (contiguous, deterministic) ----------------
__global__ __launch_bounds__(256) void agg_kernel(const float* __restrict__ he, const int* __restrict__ indptr,
                                                  float* __restrict__ agg){
  int tid = blockIdx.x*256 + threadIdx.x;
  int n = tid >> 4, cq = tid & 15;
  if (n >= NN) return;
  float4 s = {0.f,0.f,0.f,0.f};
  int lo = indptr[n], hi = indptr[n+1];
  const float4* he4 = (const float4*)he;
  for (int p=lo;p<hi;++p){
    float4 v = he4[(size_t)p*16 + cq];
    s.x+=v.x; s.y+=v.y; s.z+=v.z; s.w+=v.w;
  }
  ((float4*)(agg + (size_t)n*64))[cq] = s;
}

// ---------------- per-graph means from hn + agg, 2-stage ----------------
__global__ __launch_bounds__(256) void pmeans_kernel(const float* __restrict__ hn, const float* __restrict__ agg,
                                                     float* __restrict__ pn, float* __restrict__ pe){
  const int b = blockIdx.x, g = b >> 2, c = b & 3;
  const int t = threadIdx.x, cq = t & 15, part = t >> 4;
  const float4* A = (const float4*)(hn  + ((size_t)g*512 + (size_t)c*128)*64);
  const float4* B = (const float4*)(agg + ((size_t)g*512 + (size_t)c*128)*64);
  float4 ns = {0,0,0,0}, es = {0,0,0,0};
  for (int r = part; r < 128; r += 16){
    float4 a = A[r*16 + cq], e = B[r*16 + cq];
    ns.x+=a.x; ns.y+=a.y; ns.z+=a.z; ns.w+=a.w;
    es.x+=e.x; es.y+=e.y; es.z+=e.z; es.w+=e.w;
  }
  __shared__ float4 sbn[16][16], sbe[16][16];
  sbn[part][cq] = ns; sbe[part][cq] = es;
  __syncthreads();
  if (part == 0){
    float4 sn = sbn[0][cq], se = sbe[0][cq];
    for (int p=1;p<16;p++){
      float4 vn = sbn[p][cq], ve = sbe[p][cq];
      sn.x+=vn.x; sn.y+=vn.y; sn.z+=vn.z; sn.w+=vn.w;
      se.x+=ve.x; se.y+=ve.y; se.z+=ve.z; se.w+=ve.w;
    }
    ((float4*)pn)[(g*4+c)*16 + cq] = sn;
    ((float4*)pe)[(g*4+c)*16 + cq] = se;
  }
}
__global__ __launch_bounds__(64) void fmeans_kernel(const float* __restrict__ pn, const float* __restrict__ pe,
                                                    float* __restrict__ nmean, float* __restrict__ emean){
  const int g = blockIdx.x, col = threadIdx.x;
  float ns = 0.f, es = 0.f;
  for (int c=0;c<4;c++){
    ns += pn[(g*4+c)*64 + col];
    es += pe[(g*4+c)*64 + col];
  }
  nmean[g*64+col] = ns * (1.f/512.f);
  emean[g*64+col] = es * (1.f/4096.f);
}

// ---------------- pre_kernel: oa = x@wa, ob = x@wb ----------------
__global__ __launch_bounds__(256) void pre_kernel(const float* __restrict__ x,
    const float* __restrict__ wa, const float* __restrict__ wb,
    float* __restrict__ oa, float* __restrict__ ob, int rows)
{
  __shared__ float4 xs4[32*17];
  __shared__ float4 wsa[1024], wsb[1024];
  const int t = threadIdx.x;
  const int rowbase = blockIdx.x*32;
  {
    const int gi16 = t>>4, lg = t&15;
#pragma unroll
    for (int it=0; it<2; ++it){
      int er = gi16 + (it<<4);
      xs4[er*17+lg] = ((const float4*)(x + (size_t)64*(rowbase+er)))[lg];
    }
  }
  const float4* wa4 = (const float4*)wa;
  const float4* wb4 = (const float4*)wb;
#pragma unroll
  for (int i=0;i<4;i++){ wsa[t+i*256] = wa4[t+i*256]; wsb[t+i*256] = wb4[t+i*256]; }
  __syncthreads();

  const int r0 = (t>>4)*2, cq = t&15;
  float accA[2][4] = {{0,0,0,0},{0,0,0,0}};
  float accB[2][4] = {{0,0,0,0},{0,0,0,0}};
#pragma unroll
  for (int k4=0;k4<16;k4++){
    float4 a0 = xs4[(r0  )*17 + k4];
    float4 a1 = xs4[(r0+1)*17 + k4];
    const float* a0p = (const float*)&a0;
    const float* a1p = (const float*)&a1;
#pragma unroll
    for (int kk=0;kk<4;kk++){
      float4 ba = wsa[(k4*4+kk)*16 + cq];
      float4 bb = wsb[(k4*4+kk)*16 + cq];
      accA[0][0]=fmaf(a0p[kk],ba.x,accA[0][0]); accA[0][1]=fmaf(a0p[kk],ba.y,accA[0][1]);
      accA[0][2]=fmaf(a0p[kk],ba.z,accA[0][2]); accA[0][3]=fmaf(a0p[kk],ba.w,accA[0][3]);
      accA[1][0]=fmaf(a1p[kk],ba.x,accA[1][0]); accA[1][1]=fmaf(a1p[kk],ba.y,accA[1][1]);
      accA[1][2]=fmaf(a1p[kk],ba.z,accA[1][2]); accA[1][3]=fmaf(a1p[kk],ba.w,accA[1][3]);
      accB[0][0]=fmaf(a0p[kk],bb.x,accB[0][0]); accB[0][1]=fmaf(a0p[kk],bb.y,accB[0][1]);
      accB[0][2]=fmaf(a0p[kk],bb.z,accB[0][2]); accB[0][3]=fmaf(a0p[kk],bb.w,accB[0][3]);
      accB[1][0]=fmaf(a1p[kk],bb.x,accB[1][0]); accB[1][1]=fmaf(a1p[kk],bb.y,accB[1][1]);
      accB[1][2]=fmaf(a1p[kk],bb.z,accB[1][2]); accB[1][3]=fmaf(a1p[kk],bb.w,accB[1][3]);
    }
  }
#pragma unroll
  for (int rr=0; rr<2; rr++){
    size_t row = rowbase + r0 + rr;
    float4 va = {accA[rr][0],accA[rr][1],accA[rr][2],accA[rr][3]};
    float4 vb = {accB[rr][0],accB[rr][1],accB[rr][2],accB[rr][3]};
    ((float4*)(oa + row*64))[cq] = va;
    ((float4*)(ob + row*64))[cq] = vb;
  }
}

// ---------------- weight prep: per-lane MFMA B-fragments (bf16 hi/lo) ----------------
// blockIdx.x = layer*2 + mat (mat 0: ew1 he-slice, mat 1: ew2). Frag flat index:
// ((kc*4+nt)*64 + lane)*8 + j  with  k = kc*32 + (lane>>4)*8 + j,  n = nt*16 + (lane&15)
__global__ __launch_bounds__(256) void wprep_kernel(const float* __restrict__ ew1,
    const float* __restrict__ ew2, short* __restrict__ wfhi, short* __restrict__ wflo)
{
  const int l = blockIdx.x >> 1, m = blockIdx.x & 1;
  const float* W = (m==0) ? (ew1 + (size_t)l*256*64 + 128*64) : (ew2 + (size_t)l*64*64);
  short* oh = wfhi + (size_t)blockIdx.x*4096;
  short* ol = wflo + (size_t)blockIdx.x*4096;
  for (int i = threadIdx.x; i < 4096; i += 256){
    int j = i & 7, lane = (i>>3) & 63, nt = (i>>9) & 3, kc = i>>11;
    int k = kc*32 + (lane>>4)*8 + j;
    int n = nt*16 + (lane&15);
    float v = W[k*64 + n];
    unsigned short hi = f2bf_rne(v);
    oh[i] = (short)hi;
    ol[i] = (short)f2bf_rne(v - bf2f(hi));
  }
}

// ---------------- edge MLP via split-bf16 MFMA ----------------
// 64 edges/block, 4 waves; wave w owns rows 16w..16w+15.
// out = LN(relu(he@W1 + pa[src]+pb[dst]+ue[g] + b1) @ W2 + b2)
__global__ __launch_bounds__(256) void edge_mlp_mfma(
    const float* __restrict__ he, const float* __restrict__ pa,
    const float* __restrict__ pb, const float* __restrict__ ue,
    const int* __restrict__ srcs, const int* __restrict__ dsts,
    const short* __restrict__ w1h, const short* __restrict__ w1l,
    const short* __restrict__ w2h, const short* __restrict__ w2l,
    const float* __restrict__ b1, const float* __restrict__ b2,
    const float* __restrict__ lng, const float* __restrict__ lnb,
    float* __restrict__ outp)
{
  __shared__ float4 xs4[64*17];   // he rows, then h1 rows (stride 17 float4 = 68 f)
  __shared__ float  bsm[5][64];   // b1, b2, ln_g, ln_b, ue

  const int t = threadIdx.x;
  const int rowbase = blockIdx.x*64;
  const int g = rowbase >> 12;

  if (t < 64){ bsm[0][t] = b1[t]; bsm[4][t] = ue[(g<<6)+t]; }
  else if (t < 128) bsm[1][t-64]  = b2[t-64];
  else if (t < 192) bsm[2][t-128] = lng[t-128];
  else              bsm[3][t-192] = lnb[t-192];

  const int wv = t>>6, lane = t&63, cl = lane&15, kgrp = lane>>4;
  const int lrow  = 16*wv + cl;          // A-fragment row (this wave's slice)
  const int grow0 = rowbase + 16*wv + 4*kgrp;  // C rows grow0..grow0+3

  // early: src/dst + pa/pb gathers (coalesced 64B per 16-lane group), hidden under GEMM1
  int4 sv = ((const int4*)srcs)[grow0>>2];
  int4 dv = ((const int4*)dsts)[grow0>>2];
  float exa[4][4], exb[4][4];   // [reg][nt]
#pragma unroll
  for (int reg=0;reg<4;reg++){
    int s_ = ((const int*)&sv)[reg], d_ = ((const int*)&dv)[reg];
#pragma unroll
    for (int nt=0;nt<4;nt++){
      exa[reg][nt] = pa[(size_t)s_*64 + nt*16 + cl];
      exb[reg][nt] = pb[(size_t)d_*64 + nt*16 + cl];
    }
  }

  // stage he rows (coalesced)
  {
    const float4* heb = (const float4*)(he + (size_t)rowbase*64);
#pragma unroll
    for (int i=0;i<4;i++){
      int idx = t + i*256;
      xs4[(idx>>4)*17 + (idx&15)] = heb[idx];
    }
  }
  __syncthreads();

  const short8b* W1h = (const short8b*)w1h;
  const short8b* W1l = (const short8b*)w1l;
  const short8b* W2h = (const short8b*)w2h;
  const short8b* W2l = (const short8b*)w2l;

  // ---- GEMM1: C = he @ W1 (split bf16, 3 MFMA per tile) ----
  f32x4 acc0 = {0,0,0,0}, acc1 = {0,0,0,0}, acc2_ = {0,0,0,0}, acc3 = {0,0,0,0};
#pragma unroll
  for (int kc=0;kc<2;kc++){
    float4 a0 = xs4[lrow*17 + kc*8 + kgrp*2];
    float4 a1 = xs4[lrow*17 + kc*8 + kgrp*2 + 1];
    short8b ahi, alo; mk_frag(a0, a1, ahi, alo);
#pragma unroll
    for (int nt=0;nt<4;nt++){
      short8b bh = W1h[(kc*4+nt)*64 + lane];
      short8b bl = W1l[(kc*4+nt)*64 + lane];
      f32x4 c = (nt==0)?acc0:(nt==1)?acc1:(nt==2)?acc2_:acc3;
      c = __builtin_amdgcn_mfma_f32_16x16x32_bf16(ahi, bh, c, 0,0,0);
      c = __builtin_amdgcn_mfma_f32_16x16x32_bf16(alo, bh, c, 0,0,0);
      c = __builtin_amdgcn_mfma_f32_16x16x32_bf16(ahi, bl, c, 0,0,0);
      if (nt==0) acc0=c; else if (nt==1) acc1=c; else if (nt==2) acc2_=c; else acc3=c;
    }
  }

  // ---- epilogue1: h1 = relu(C + b1 + ue + pa[src] + pb[dst]) -> LDS [row][col] ----
  // C layout: col = nt*16 + cl, row (in wave slice) = 4*kgrp + reg
  float* xsw = (float*)xs4;
#pragma unroll
  for (int nt=0;nt<4;nt++){
    int cn = nt*16 + cl;
    float bc = bsm[0][cn] + bsm[4][cn];
    f32x4 c = (nt==0)?acc0:(nt==1)?acc1:(nt==2)?acc2_:acc3;
#pragma unroll
    for (int reg=0;reg<4;reg++){
      float h = fmaxf(c[reg] + bc + exa[reg][nt] + exb[reg][nt], 0.f);
      xsw[(16*wv + 4*kgrp + reg)*68 + cn] = h;
    }
  }
  // same-wave rows only -> no barrier needed (compiler orders LDS via lgkmcnt)

  // ---- GEMM2: C2 = h1 @ W2 ----
  f32x4 d0 = {0,0,0,0}, d1 = {0,0,0,0}, d2 = {0,0,0,0}, d3 = {0,0,0,0};
#pragma unroll
  for (int kc=0;kc<2;kc++){
    float4 a0 = xs4[lrow*17 + kc*8 + kgrp*2];
    float4 a1 = xs4[lrow*17 + kc*8 + kgrp*2 + 1];
    short8b ahi, alo; mk_frag(a0, a1, ahi, alo);
#pragma unroll
    for (int nt=0;nt<4;nt++){
      short8b bh = W2h[(kc*4+nt)*64 + lane];
      short8b bl = W2l[(kc*4+nt)*64 + lane];
      f32x4 c = (nt==0)?d0:(nt==1)?d1:(nt==2)?d2:d3;
      c = __builtin_amdgcn_mfma_f32_16x16x32_bf16(ahi, bh, c, 0,0,0);
      c = __builtin_amdgcn_mfma_f32_16x16x32_bf16(alo, bh, c, 0,0,0);
      c = __builtin_amdgcn_mfma_f32_16x16x32_bf16(ahi, bl, c, 0,0,0);
      if (nt==0) d0=c; else if (nt==1) d1=c; else if (nt==2) d2=c; else d3=c;
    }
  }

  // ---- LayerNorm (reduce across the 16 lanes of each kgrp) + store ----
#pragma unroll
  for (int reg=0;reg<4;reg++){
    float v0 = d0[reg] + bsm[1][cl];
    float v1 = d1[reg] + bsm[1][16+cl];
    float v2 = d2[reg] + bsm[1][32+cl];
    float v3 = d3[reg] + bsm[1][48+cl];
    float sA = v0+v1+v2+v3;
    float sB = v0*v0+v1*v1+v2*v2+v3*v3;
#pragma unroll
    for (int m=1;m<16;m<<=1){ sA += __shfl_xor(sA,m); sB += __shfl_xor(sB,m); }
    float mean = sA * 0.015625f;
    float var  = sB * 0.015625f - mean*mean;
    float inv  = 1.0f / sqrtf(var + 1e-5f);
    float* orow = outp + (size_t)(grow0 + reg)*64;
    orow[cl]    = (v0-mean)*inv*bsm[2][cl]    + bsm[3][cl];
    orow[16+cl] = (v1-mean)*inv*bsm[2][16+cl] + bsm[3][16+cl];
    orow[32+cl] = (v2-mean)*inv*bsm[2][32+cl] + bsm[3][32+cl];
    orow[48+cl] = (v3-mean)*inv*bsm[2][48+cl] + bsm[3][48+cl];
  }
}

// ---------------- fused LN(relu(x@w1+b1)@w2+b2) for node/global (fp32 path) ----------------
template<int MODE>
__global__ __launch_bounds__(256) void mlp_ln(
    const float* __restrict__ s0, const float* __restrict__ s1,
    const float* __restrict__ s2,
    const float* __restrict__ w1, const float* __restrict__ b1,
    const float* __restrict__ w2, const float* __restrict__ b2,
    const float* __restrict__ lng, const float* __restrict__ lnb,
    float* __restrict__ outp)
{
  constexpr int DIN  = (MODE==1) ? 128 : 192;
  constexpr int NSEG = DIN/64;
  constexpr int DP4  = DIN/4 + 1;

  __shared__ float4 xs4[32*DP4];
  __shared__ float4 ws4[1024];
  __shared__ float  bsm[5][64];

  const int t = threadIdx.x;
  const int rowbase = blockIdx.x*32;

  if (t < 64)       bsm[0][t]     = b1[t];
  else if (t < 128) bsm[1][t-64]  = b2[t-64];
  else if (t < 192) bsm[2][t-128] = lng[t-128];
  else              bsm[3][t-192] = lnb[t-192];

  if constexpr (MODE==1){
    const int g = rowbase >> 9;
    if (t < 64) bsm[4][t] = s2[(g<<6)+t];
  }

  {
    const int gi16 = t >> 4, lg = t & 15;
#pragma unroll
    for (int it = 0; it < 2*NSEG; ++it){
      int pair = gi16 + (it << 4);
      int er = pair & 31, seg = pair >> 5;
      int row = rowbase + er;
      const float* bp = ((seg==0)? s0 : (seg==1)? s1 : s2) + (size_t)64*row;
      xs4[er*DP4 + seg*16 + lg] = ((const float4*)bp)[lg];
    }
  }
  __syncthreads();

  const int r0 = (t >> 4) * 2, cq = t & 15;
  float acc[2][4] = {{0.f,0.f,0.f,0.f},{0.f,0.f,0.f,0.f}};
  const float4* w1g4 = (const float4*)w1;

  for (int kc = 0; kc < DIN; kc += 64){
    __syncthreads();
    ws4[t]     = w1g4[kc*16 + t];
    ws4[t+256] = w1g4[kc*16 + t + 256];
    ws4[t+512] = w1g4[kc*16 + t + 512];
    ws4[t+768] = w1g4[kc*16 + t + 768];
    __syncthreads();
#pragma unroll
    for (int k4=0;k4<16;k4++){
      float4 a0 = xs4[(r0  )*DP4 + (kc>>2) + k4];
      float4 a1 = xs4[(r0+1)*DP4 + (kc>>2) + k4];
      float4 bb[4];
#pragma unroll
      for (int kk=0;kk<4;kk++) bb[kk] = ws4[(k4*4+kk)*16 + cq];
      const float* a0p = (const float*)&a0;
      const float* a1p = (const float*)&a1;
#pragma unroll
      for (int kk=0;kk<4;kk++){
        acc[0][0]=fmaf(a0p[kk],bb[kk].x,acc[0][0]);
        acc[0][1]=fmaf(a0p[kk],bb[kk].y,acc[0][1]);
        acc[0][2]=fmaf(a0p[kk],bb[kk].z,acc[0][2]);
        acc[0][3]=fmaf(a0p[kk],bb[kk].w,acc[0][3]);
        acc[1][0]=fmaf(a1p[kk],bb[kk].x,acc[1][0]);
        acc[1][1]=fmaf(a1p[kk],bb[kk].y,acc[1][1]);
        acc[1][2]=fmaf(a1p[kk],bb[kk].z,acc[1][2]);
        acc[1][3]=fmaf(a1p[kk],bb[kk].w,acc[1][3]);
      }
    }
  }

  float4 ex;
  if constexpr (MODE==1){
    ex.x = bsm[4][cq*4+0]; ex.y = bsm[4][cq*4+1];
    ex.z = bsm[4][cq*4+2]; ex.w = bsm[4][cq*4+3];
  } else {
    ex.x = ex.y = ex.z = ex.w = 0.f;
  }

  __syncthreads();
  {
    float4 h0, h1v;
    h0.x  = fmaxf(acc[0][0]+bsm[0][cq*4+0]+ex.x, 0.f);
    h0.y  = fmaxf(acc[0][1]+bsm[0][cq*4+1]+ex.y, 0.f);
    h0.z  = fmaxf(acc[0][2]+bsm[0][cq*4+2]+ex.z, 0.f);
    h0.w  = fmaxf(acc[0][3]+bsm[0][cq*4+3]+ex.w, 0.f);
    h1v.x = fmaxf(acc[1][0]+bsm[0][cq*4+0]+ex.x, 0.f);
    h1v.y = fmaxf(acc[1][1]+bsm[0][cq*4+1]+ex.y, 0.f);
    h1v.z = fmaxf(acc[1][2]+bsm[0][cq*4+2]+ex.z, 0.f);
    h1v.w = fmaxf(acc[1][3]+bsm[0][cq*4+3]+ex.w, 0.f);
    xs4[(r0  )*DP4 + cq] = h0;
    xs4[(r0+1)*DP4 + cq] = h1v;
    const float4* w2g4 = (const float4*)w2;
    ws4[t]     = w2g4[t];
    ws4[t+256] = w2g4[t+256];
    ws4[t+512] = w2g4[t+512];
    ws4[t+768] = w2g4[t+768];
  }
  __syncthreads();

  float acc2[2][4] = {{0.f,0.f,0.f,0.f},{0.f,0.f,0.f,0.f}};
#pragma unroll
  for (int k4=0;k4<16;k4++){
    float4 a0 = xs4[(r0  )*DP4 + k4];
    float4 a1 = xs4[(r0+1)*DP4 + k4];
    float4 bb[4];
#pragma unroll
    for (int kk=0;kk<4;kk++) bb[kk] = ws4[(k4*4+kk)*16 + cq];
    const float* a0p = (const float*)&a0;
    const float* a1p = (const float*)&a1;
#pragma unroll
    for (int kk=0;kk<4;kk++){
      acc2[0][0]=fmaf(a0p[kk],bb[kk].x,acc2[0][0]);
      acc2[0][1]=fmaf(a0p[kk],bb[kk].y,acc2[0][1]);
      acc2[0][2]=fmaf(a0p[kk],bb[kk].z,acc2[0][2]);
      acc2[0][3]=fmaf(a0p[kk],bb[kk].w,acc2[0][3]);
      acc2[1][0]=fmaf(a1p[kk],bb[kk].x,acc2[1][0]);
      acc2[1][1]=fmaf(a1p[kk],bb[kk].y,acc2[1][1]);
      acc2[1][2]=fmaf(a1p[kk],bb[kk].z,acc2[1][2]);
      acc2[1][3]=fmaf(a1p[kk],bb[kk].w,acc2[1][3]);
    }
  }

#pragma unroll
  for (int rr=0; rr<2; rr++){
    float v0 = acc2[rr][0] + bsm[1][cq*4+0];
    float v1 = acc2[rr][1] + bsm[1][cq*4+1];
    float v2 = acc2[rr][2] + bsm[1][cq*4+2];
    float v3 = acc2[rr][3] + bsm[1][cq*4+3];
    float sA = v0+v1+v2+v3;
    float sB = v0*v0+v1*v1+v2*v2+v3*v3;
#pragma unroll
    for (int m=1;m<16;m<<=1){ sA += __shfl_xor(sA,m); sB += __shfl_xor(sB,m); }
    float mean = sA * 0.015625f;
    float var  = sB * 0.015625f - mean*mean;
    float inv  = 1.0f / sqrtf(var + 1e-5f);
    float4 o;
    o.x = (v0-mean)*inv*bsm[2][cq*4+0] + bsm[3][cq*4+0];
    o.y = (v1-mean)*inv*bsm[2][cq*4+1] + bsm[3][cq*4+1];
    o.z = (v2-mean)*inv*bsm[2][cq*4+2] + bsm[3][cq*4+2];
    o.w = (v3-mean)*inv*bsm[2][cq*4+3] + bsm[3][cq*4+3];
    ((float4*)(outp + (size_t)(rowbase + r0 + rr)*64))[cq] = o;
  }
}

// ---------------- heads ----------------
__global__ __launch_bounds__(512) void heads_kernel(
    const float* __restrict__ hn, const float* __restrict__ uvec,
    const float* __restrict__ aw, const float* __restrict__ ab,
    const float* __restrict__ cw, const float* __restrict__ cb,
    float* __restrict__ out)
{
  const int g = blockIdx.x, t = threadIdx.x;
  const int n = (g<<9) + t;
  const float4* hp = (const float4*)(hn + (size_t)n*64);
  const float4* ap = (const float4*)aw;
  float d = 0.f;
#pragma unroll
  for (int i=0;i<16;i++){
    float4 h = hp[i], a = ap[i];
    d += h.x*a.x + h.y*a.y + h.z*a.z + h.w*a.w;
  }
  d += ab[0];
  float z = 1.0f/(1.0f + expf(-d));

  unsigned o0,o1;
  threefry(0u, 42u, 0u, (unsigned)n, o0, o1);
  unsigned bits = o0 ^ o1;
  float f = __uint_as_float((bits>>9) | 0x3f800000u) - 1.0f;
  float gum = -logf(-logf(fmaxf(1.17549435e-38f, f)));

  const int lane = t & 63, wid = t >> 6;
  __shared__ float smax[8], ssum[8], sent[8], skey[8];
  __shared__ int   sidx[8];
  __shared__ float sM, sS;
  __shared__ int   sA;

  float m = z;
#pragma unroll
  for (int sh=1; sh<64; sh<<=1) m = fmaxf(m, __shfl_xor(m, sh));
  if (lane==0) smax[wid] = m;
  __syncthreads();
  if (t==0){ float mm=smax[0]; for(int i=1;i<8;i++) mm=fmaxf(mm,smax[i]); sM=mm; }
  __syncthreads();
  float M = sM;
  float ex = expf(z - M);
  float ssl = ex;
#pragma unroll
  for (int sh=1; sh<64; sh<<=1) ssl += __shfl_xor(ssl, sh);
  if (lane==0) ssum[wid] = ssl;
  __syncthreads();
  if (t==0){ float ss=0.f; for(int i=0;i<8;i++) ss+=ssum[i]; sS=ss; }
  __syncthreads();
  float logp = z - M - logf(sS);
  float p = expf(logp);
  float entl = p * logp;
#pragma unroll
  for (int sh=1; sh<64; sh<<=1) entl += __shfl_xor(entl, sh);
  if (lane==0) sent[wid] = entl;

  float kv = z + gum; int ki = t;
#pragma unroll
  for (int sh=1; sh<64; sh<<=1){
    float ov = __shfl_xor(kv, sh);
    int   oi = __shfl_xor(ki, sh);
    if (ov > kv || (ov == kv && oi < ki)){ kv = ov; ki = oi; }
  }
  if (lane==0){ skey[wid] = kv; sidx[wid] = ki; }
  __syncthreads();
  if (t==0){
    float bv = skey[0]; int bi = sidx[0];
    for (int i=1;i<8;i++) if (skey[i] > bv || (skey[i]==bv && sidx[i] < bi)){ bv=skey[i]; bi=sidx[i]; }
    sA = bi;
    float ent = 0.f; for (int i=0;i<8;i++) ent += sent[i];
    out[g]      = (float)bi;
    out[128+g]  = -ent;
  }
  __syncthreads();
  if (t == sA) out[64+g] = logp;

  if (t < 64){
    float pv = uvec[(g<<6)+t] * cw[t];
#pragma unroll
    for (int sh=1; sh<64; sh<<=1) pv += __shfl_xor(pv, sh);
    if (t==0) out[192+g] = pv + cb[0];
  }
}

// ---------------- launch ----------------
extern "C" void kernel_launch(void* const* d_in, const int* in_sizes, int n_in,
                              void* d_out, int out_size, void* d_ws, size_t ws_size,
                              hipStream_t stream)
{
  (void)in_sizes; (void)n_in; (void)out_size; (void)ws_size;
  const float* x      = (const float*)d_in[0];
  const float* eattr  = (const float*)d_in[1];
  const int*   eidx   = (const int*)d_in[2];
  const float* node_w = (const float*)d_in[5];
  const float* node_b = (const float*)d_in[6];
  const float* edge_w = (const float*)d_in[7];
  const float* edge_b = (const float*)d_in[8];
  const float* init_u = (const float*)d_in[9];
  const float* ew1 = (const float*)d_in[10]; const float* eb1 = (const float*)d_in[11];
  const float* ew2 = (const float*)d_in[12]; const float* eb2 = (const float*)d_in[13];
  const float* elg = (const float*)d_in[14]; const float* elb = (const float*)d_in[15];
  const float* nw1 = (const float*)d_in[16]; const float* nb1 = (const float*)d_in[17];
  const float* nw2 = (const float*)d_in[18]; const float* nb2 = (const float*)d_in[19];
  const float* nlg = (const float*)d_in[20]; const float* nlb = (const float*)d_in[21];
  const float* gw1 = (const float*)d_in[22]; const float* gb1 = (const float*)d_in[23];
  const float* gw2 = (const float*)d_in[24]; const float* gb2 = (const float*)d_in[25];
  const float* glg = (const float*)d_in[26]; const float* glb = (const float*)d_in[27];
  const float* aw  = (const float*)d_in[28]; const float* ab  = (const float*)d_in[29];
  const float* cw  = (const float*)d_in[30]; const float* cb  = (const float*)d_in[31];
  const int* src = eidx;
  const int* dst = eidx + EE;

  float* ws    = (float*)d_ws;
  float* hn    = ws;                         // N*64
  float* he    = hn + (size_t)NN*64;         // E*64  (dst-sorted order)
  float* agg   = he + (size_t)EE*64;         // N*64
  float* u     = agg + (size_t)NN*64;        // G*64
  float* nmean = u + GG*64;
  float* emean = nmean + GG*64;
  int* cnt     = (int*)(emean + GG*64);      // N
  int* indptr  = cnt + NN;                   // N+1
  int* fillc   = indptr + NN + 1;            // N
  int* eord    = fillc + NN;                 // E
  int* srcs    = eord + EE;                  // E
  int* dsts    = srcs + EE;                  // E
  float* pb    = (float*)(dsts + EE);        // N*64
  float* ue    = pb + (size_t)NN*64;         // G*64
  float* un    = ue + GG*64;                 // G*64
  float* pn    = un + GG*64;                 // G*4*64
  float* pe    = pn + GG*4*64;               // G*4*64
  short* wfh   = (short*)(pe + GG*4*64);     // 6*4096 shorts (edge W frags hi)
  short* wfl   = wfh + 6*4096;               // 6*4096 shorts (lo)

  float* pa = agg;   // pa aliases agg (dead during edge phase)

  float* out = (float*)d_out;

  hipMemsetAsync(cnt,   0, NN*sizeof(int), stream);
  hipMemsetAsync(fillc, 0, NN*sizeof(int), stream);

  count_kernel<<<EE/256, 256, 0, stream>>>(dst, cnt);
  scan_kernel<<<1, 1024, 0, stream>>>(cnt, indptr);
  fill_kernel<<<EE/256, 256, 0, stream>>>(dst, indptr, fillc, eord);
  sort_kernel<<<NN/256, 256, 0, stream>>>(indptr, eord);
  perm_kernel<<<EE/256, 256, 0, stream>>>(src, dst, eord, srcs, dsts);

  encode_kernel<32><<<NN/4, 256, 0, stream>>>(x, node_w, node_b, hn, NN);
  encode_gather_kernel<16><<<EE/4, 256, 0, stream>>>(eattr, edge_w, edge_b, eord, he);
  initu_kernel<<<16, 256, 0, stream>>>(init_u, u);
  wprep_kernel<<<NL*2, 256, 0, stream>>>(ew1, ew2, wfh, wfl);

  for (int l=0; l<NL; ++l){
    const float* ew1l = ew1 + (size_t)l*256*64;
    const float* nw1l = nw1 + (size_t)l*192*64;
    pre_kernel<<<NN/32, 256, 0, stream>>>(hn, ew1l, ew1l + 64*64, pa, pb, NN);
    pre_kernel<<<2, 256, 0, stream>>>(u, ew1l + 192*64, nw1l + 128*64, ue, un, GG);

    edge_mlp_mfma<<<EE/64, 256, 0, stream>>>(he, pa, pb, ue, srcs, dsts,
        wfh + (size_t)(l*2+0)*4096, wfl + (size_t)(l*2+0)*4096,
        wfh + (size_t)(l*2+1)*4096, wfl + (size_t)(l*2+1)*4096,
        eb1 + l*64, eb2 + l*64, elg + l*64, elb + l*64, he);
    agg_kernel<<<NN*16/256, 256, 0, stream>>>(he, indptr, agg);
    mlp_ln<1><<<NN/32, 256, 0, stream>>>(hn, agg, un,
        nw1l, nb1 + l*64, nw2 + (size_t)l*64*64, nb2 + l*64,
        nlg + l*64, nlb + l*64, hn);
    pmeans_kernel<<<GG*4, 256, 0, stream>>>(hn, agg, pn, pe);
    fmeans_kernel<<<GG, 64, 0, stream>>>(pn, pe, nmean, emean);
    mlp_ln<2><<<GG/32, 256, 0, stream>>>(u, nmean, emean,
        gw1 + (size_t)l*192*64, gb1 + l*64, gw2 + (size_t)l*64*64, gb2 + l*64,
        glg + l*64, glb + l*64, u);
  }

  heads_kernel<<<GG, 512, 0, stream>>>(hn, u, aw, ab, cw, cb, out);
}

// Round 7
// 416.226 us; speedup vs baseline: 3.9839x; 1.1994x over previous
//
#include <hip/hip_runtime.h>
#include <math.h>

#define GG 64
#define NPGc 512
#define NN (GG*NPGc)      // 32768 nodes
#define EE (NN*8)         // 262144 edges
#define HH 64
#define NL 3

typedef __attribute__((ext_vector_type(8))) short short8b;
typedef __attribute__((ext_vector_type(4))) float f32x4;

// ---------------- bf16 split helpers ----------------
__device__ __forceinline__ unsigned short f2bf_rne(float f){
  unsigned u = __float_as_uint(f);
  unsigned r = u + 0x7fffu + ((u>>16)&1u);
  return (unsigned short)(r>>16);
}
__device__ __forceinline__ float bf2f(unsigned short h){
  return __uint_as_float(((unsigned)h)<<16);
}
__device__ __forceinline__ void mk_frag(const float4 &u, const float4 &v, short8b &hi, short8b &lo){
  float av[8] = {u.x,u.y,u.z,u.w,v.x,v.y,v.z,v.w};
#pragma unroll
  for (int j=0;j<8;j++){
    unsigned short h = f2bf_rne(av[j]);
    hi[j] = (short)h;
    lo[j] = (short)f2bf_rne(av[j] - bf2f(h));
  }
}

// ---------------- threefry2x32 (JAX-compatible, partitionable mode) ----------------
__device__ __forceinline__ unsigned rotl32(unsigned x, int r){ return (x<<r)|(x>>(32-r)); }
__device__ __forceinline__ void threefry(unsigned k0, unsigned k1, unsigned x0, unsigned x1,
                                         unsigned &o0, unsigned &o1){
  unsigned ks2 = k0 ^ k1 ^ 0x1BD11BDAu;
  unsigned v0 = x0 + k0, v1 = x1 + k1;
#define R4(a,b,c,d) v0+=v1; v1=rotl32(v1,a); v1^=v0; v0+=v1; v1=rotl32(v1,b); v1^=v0; \
                    v0+=v1; v1=rotl32(v1,c); v1^=v0; v0+=v1; v1=rotl32(v1,d); v1^=v0;
  R4(13,15,26,6)  v0+=k1;  v1+=ks2+1u;
  R4(17,29,16,24) v0+=ks2; v1+=k0+2u;
  R4(13,15,26,6)  v0+=k0;  v1+=k1+3u;
  R4(17,29,16,24) v0+=k1;  v1+=ks2+4u;
  R4(13,15,26,6)  v0+=ks2; v1+=k0+5u;
#undef R4
  o0=v0; o1=v1;
}

// ---------------- node encoder ----------------
template<int K>
__global__ __launch_bounds__(256) void encode_kernel(const float* __restrict__ in,
    const float* __restrict__ w, const float* __restrict__ b,
    float* __restrict__ out, int rows)
{
  int wid = blockIdx.x*4 + (threadIdx.x>>6);
  int lane = threadIdx.x & 63;
  if (wid >= rows) return;
  const float* xr = in + (size_t)wid*K;
  float acc = b[lane];
#pragma unroll
  for (int i=0;i<K;i++) acc = fmaf(xr[i], w[i*64+lane], acc);
  out[(size_t)wid*64+lane] = fmaxf(acc, 0.f);
}

__global__ __launch_bounds__(256) void initu_kernel(const float* __restrict__ iu, float* __restrict__ u){
  int i = blockIdx.x*256 + threadIdx.x;
  if (i < GG*64) u[i] = iu[i & 63];
}

// ---------------- CSR build ----------------
__global__ __launch_bounds__(256) void count_kernel(const int* __restrict__ dst, int* __restrict__ cnt){
  int e = blockIdx.x*256 + threadIdx.x;
  if (e < EE) atomicAdd(&cnt[dst[e]], 1);
}
__global__ __launch_bounds__(1024) void scan_kernel(const int* __restrict__ cnt, int* __restrict__ indptr){
  __shared__ int part[1024];
  const int t = threadIdx.x;
  const int base = t*32;
  int s = 0;
  for (int i=0;i<32;i++) s += cnt[base+i];
  part[t] = s;
  __syncthreads();
  for (int off=1; off<1024; off<<=1){
    int v = part[t];
    int add = (t >= off) ? part[t-off] : 0;
    __syncthreads();
    part[t] = v + add;
    __syncthreads();
  }
  int run = (t==0) ? 0 : part[t-1];
  for (int i=0;i<32;i++){ indptr[base+i] = run; run += cnt[base+i]; }
  if (t==1023) indptr[NN] = run;
}
__global__ __launch_bounds__(256) void fill_kernel(const int* __restrict__ dst, const int* __restrict__ indptr,
                                                   int* __restrict__ fillc, int* __restrict__ eord){
  int e = blockIdx.x*256 + threadIdx.x;
  if (e < EE){ int dn = dst[e]; int p = atomicAdd(&fillc[dn], 1); eord[indptr[dn]+p] = e; }
}
__global__ __launch_bounds__(256) void sort_kernel(const int* __restrict__ indptr, int* __restrict__ eord){
  int n = blockIdx.x*256 + threadIdx.x;
  if (n >= NN) return;
  int lo = indptr[n], hi = indptr[n+1];
  for (int i=lo+1;i<hi;i++){
    int v = eord[i]; int j = i-1;
    while (j >= lo && eord[j] > v){ eord[j+1]=eord[j]; j--; }
    eord[j+1] = v;
  }
}
__global__ __launch_bounds__(256) void perm_kernel(const int* __restrict__ src, const int* __restrict__ dst,
                                                   const int* __restrict__ eord,
                                                   int* __restrict__ srcs, int* __restrict__ dsts){
  int p = blockIdx.x*256 + threadIdx.x;
  if (p < EE){ int e = eord[p]; srcs[p] = src[e]; dsts[p] = dst[e]; }
}

// ---------------- agg (contiguous, deterministic) ----------------
__global__ __launch_bounds__(256) void agg_kernel(const float* __restrict__ he, const int* __restrict__ indptr,
                                                  float* __restrict__ agg){
  int tid = blockIdx.x*256 + threadIdx.x;
  int n = tid >> 4, cq = tid & 15;
  if (n >= NN) return;
  float4 s = {0.f,0.f,0.f,0.f};
  int lo = indptr[n], hi = indptr[n+1];
  const float4* he4 = (const float4*)he;
  for (int p=lo;p<hi;++p){
    float4 v = he4[(size_t)p*16 + cq];
    s.x+=v.x; s.y+=v.y; s.z+=v.z; s.w+=v.w;
  }
  ((float4*)(agg + (size_t)n*64))[cq] = s;
}

// ---------------- per-graph means from hn + agg, 2-stage ----------------
__global__ __launch_bounds__(256) void pmeans_kernel(const float* __restrict__ hn, const float* __restrict__ agg,
                                                     float* __restrict__ pn, float* __restrict__ pe){
  const int b = blockIdx.x, g = b >> 2, c = b & 3;
  const int t = threadIdx.x, cq = t & 15, part = t >> 4;
  const float4* A = (const float4*)(hn  + ((size_t)g*512 + (size_t)c*128)*64);
  const float4* B = (const float4*)(agg + ((size_t)g*512 + (size_t)c*128)*64);
  float4 ns = {0,0,0,0}, es = {0,0,0,0};
  for (int r = part; r < 128; r += 16){
    float4 a = A[r*16 + cq], e = B[r*16 + cq];
    ns.x+=a.x; ns.y+=a.y; ns.z+=a.z; ns.w+=a.w;
    es.x+=e.x; es.y+=e.y; es.z+=e.z; es.w+=e.w;
  }
  __shared__ float4 sbn[16][16], sbe[16][16];
  sbn[part][cq] = ns; sbe[part][cq] = es;
  __syncthreads();
  if (part == 0){
    float4 sn = sbn[0][cq], se = sbe[0][cq];
    for (int p=1;p<16;p++){
      float4 vn = sbn[p][cq], ve = sbe[p][cq];
      sn.x+=vn.x; sn.y+=vn.y; sn.z+=vn.z; sn.w+=vn.w;
      se.x+=ve.x; se.y+=ve.y; se.z+=ve.z; se.w+=ve.w;
    }
    ((float4*)pn)[(g*4+c)*16 + cq] = sn;
    ((float4*)pe)[(g*4+c)*16 + cq] = se;
  }
}
__global__ __launch_bounds__(64) void fmeans_kernel(const float* __restrict__ pn, const float* __restrict__ pe,
                                                    float* __restrict__ nmean, float* __restrict__ emean){
  const int g = blockIdx.x, col = threadIdx.x;
  float ns = 0.f, es = 0.f;
  for (int c=0;c<4;c++){
    ns += pn[(g*4+c)*64 + col];
    es += pe[(g*4+c)*64 + col];
  }
  nmean[g*64+col] = ns * (1.f/512.f);
  emean[g*64+col] = es * (1.f/4096.f);
}

// ---------------- pre_kernel: oa = x@wa, ob = x@wb ----------------
__global__ __launch_bounds__(256) void pre_kernel(const float* __restrict__ x,
    const float* __restrict__ wa, const float* __restrict__ wb,
    float* __restrict__ oa, float* __restrict__ ob, int rows)
{
  __shared__ float4 xs4[32*17];
  __shared__ float4 wsa[1024], wsb[1024];
  const int t = threadIdx.x;
  const int rowbase = blockIdx.x*32;
  {
    const int gi16 = t>>4, lg = t&15;
#pragma unroll
    for (int it=0; it<2; ++it){
      int er = gi16 + (it<<4);
      xs4[er*17+lg] = ((const float4*)(x + (size_t)64*(rowbase+er)))[lg];
    }
  }
  const float4* wa4 = (const float4*)wa;
  const float4* wb4 = (const float4*)wb;
#pragma unroll
  for (int i=0;i<4;i++){ wsa[t+i*256] = wa4[t+i*256]; wsb[t+i*256] = wb4[t+i*256]; }
  __syncthreads();

  const int r0 = (t>>4)*2, cq = t&15;
  float accA[2][4] = {{0,0,0,0},{0,0,0,0}};
  float accB[2][4] = {{0,0,0,0},{0,0,0,0}};
#pragma unroll
  for (int k4=0;k4<16;k4++){
    float4 a0 = xs4[(r0  )*17 + k4];
    float4 a1 = xs4[(r0+1)*17 + k4];
    const float* a0p = (const float*)&a0;
    const float* a1p = (const float*)&a1;
#pragma unroll
    for (int kk=0;kk<4;kk++){
      float4 ba = wsa[(k4*4+kk)*16 + cq];
      float4 bb = wsb[(k4*4+kk)*16 + cq];
      accA[0][0]=fmaf(a0p[kk],ba.x,accA[0][0]); accA[0][1]=fmaf(a0p[kk],ba.y,accA[0][1]);
      accA[0][2]=fmaf(a0p[kk],ba.z,accA[0][2]); accA[0][3]=fmaf(a0p[kk],ba.w,accA[0][3]);
      accA[1][0]=fmaf(a1p[kk],ba.x,accA[1][0]); accA[1][1]=fmaf(a1p[kk],ba.y,accA[1][1]);
      accA[1][2]=fmaf(a1p[kk],ba.z,accA[1][2]); accA[1][3]=fmaf(a1p[kk],ba.w,accA[1][3]);
      accB[0][0]=fmaf(a0p[kk],bb.x,accB[0][0]); accB[0][1]=fmaf(a0p[kk],bb.y,accB[0][1]);
      accB[0][2]=fmaf(a0p[kk],bb.z,accB[0][2]); accB[0][3]=fmaf(a0p[kk],bb.w,accB[0][3]);
      accB[1][0]=fmaf(a1p[kk],bb.x,accB[1][0]); accB[1][1]=fmaf(a1p[kk],bb.y,accB[1][1]);
      accB[1][2]=fmaf(a1p[kk],bb.z,accB[1][2]); accB[1][3]=fmaf(a1p[kk],bb.w,accB[1][3]);
    }
  }
#pragma unroll
  for (int rr=0; rr<2; rr++){
    size_t row = rowbase + r0 + rr;
    float4 va = {accA[rr][0],accA[rr][1],accA[rr][2],accA[rr][3]};
    float4 vb = {accB[rr][0],accB[rr][1],accB[rr][2],accB[rr][3]};
    ((float4*)(oa + row*64))[cq] = va;
    ((float4*)(ob + row*64))[cq] = vb;
  }
}

// ---------------- weight prep: per-lane MFMA B-fragments (bf16 hi/lo) ----------------
// 13 matrices: m=0 enc (K=16 pad 32, 1 kc); per layer l: e1(K=64), e2(64), n1(128), n2(64)
// frag flat idx (relative to matrix base): ((kc*4+nt)*64+lane)*8+j ;
// k = kc*32+(lane>>4)*8+j (0 if k>=K), n = nt*16+(lane&15)
__global__ __launch_bounds__(256) void wprep_kernel(const float* __restrict__ edge_w,
    const float* __restrict__ ew1, const float* __restrict__ ew2,
    const float* __restrict__ nw1, const float* __restrict__ nw2,
    short* __restrict__ wfhi, short* __restrict__ wflo)
{
  int b = blockIdx.x;   // 31 blocks: one per (matrix, kc)
  int m = 0, kc = 0; size_t doff = 0; int rem = b;
  for (m = 0; m < 13; m++){
    int kcs = (m==0) ? 1 : ((((m-1)&3)==2) ? 4 : 2);
    if (rem < kcs){ kc = rem; break; }
    rem -= kcs; doff += (size_t)kcs*2048;
  }
  const float* W; int K;
  if (m == 0){ W = edge_w; K = 16; }
  else {
    int l = (m-1)>>2, r = (m-1)&3;
    if      (r==0){ W = ew1 + (size_t)l*16384 + 8192; K = 64;  }
    else if (r==1){ W = ew2 + (size_t)l*4096;         K = 64;  }
    else if (r==2){ W = nw1 + (size_t)l*12288;        K = 128; }
    else          { W = nw2 + (size_t)l*4096;         K = 64;  }
  }
  const int nt = threadIdx.x>>6, lane = threadIdx.x&63;
#pragma unroll
  for (int j=0;j<8;j++){
    int k = kc*32 + (lane>>4)*8 + j;
    int n = nt*16 + (lane&15);
    float v = (k < K) ? W[k*64+n] : 0.f;
    size_t o = doff + (size_t)kc*2048 + (size_t)((nt*64+lane)*8+j);
    unsigned short hi = f2bf_rne(v);
    wfhi[o] = (short)hi;
    wflo[o] = (short)f2bf_rne(v - bf2f(hi));
  }
}

// ---------------- edge MLP via split-bf16 MFMA (FUSE=1: inline edge encoder, layer 0) ----------------
// 64 edges/block, 4 waves; wave w owns rows 16w..16w+15.
template<int FUSE>
__global__ __launch_bounds__(256) void edge_mlp_mfma(
    const float* __restrict__ he, const float* __restrict__ eattr,
    const int* __restrict__ eord,
    const float* __restrict__ pa, const float* __restrict__ pb,
    const float* __restrict__ ue,
    const int* __restrict__ srcs, const int* __restrict__ dsts,
    const short* __restrict__ weh, const short* __restrict__ wel,
    const short* __restrict__ w1h, const short* __restrict__ w1l,
    const short* __restrict__ w2h, const short* __restrict__ w2l,
    const float* __restrict__ eb, const float* __restrict__ b1,
    const float* __restrict__ b2,
    const float* __restrict__ lng, const float* __restrict__ lnb,
    float* __restrict__ outp)
{
  __shared__ float4 xs4[64*17];            // he rows, then h1 rows (68 f stride)
  __shared__ float4 eas[FUSE ? 64*4 : 1];  // gathered eattr rows [64][16]f
  __shared__ float  bsm[6][64];            // b1, b2, ln_g, ln_b, ue, eb

  const int t = threadIdx.x;
  const int rowbase = blockIdx.x*64;
  const int g = rowbase >> 12;

  if (t < 64){
    bsm[0][t] = b1[t]; bsm[4][t] = ue[(g<<6)+t];
    if constexpr (FUSE) bsm[5][t] = eb[t];
  }
  else if (t < 128) bsm[1][t-64]  = b2[t-64];
  else if (t < 192) bsm[2][t-128] = lng[t-128];
  else              bsm[3][t-192] = lnb[t-192];

  const int wv = t>>6, lane = t&63, cl = lane&15, kgrp = lane>>4;
  const int lrow  = 16*wv + cl;                 // A-fragment row
  const int grow0 = rowbase + 16*wv + 4*kgrp;   // C rows grow0..grow0+3

  // early: src/dst + pa/pb gathers (hidden under GEMM1)
  int4 sv = ((const int4*)srcs)[grow0>>2];
  int4 dv = ((const int4*)dsts)[grow0>>2];
  float exa[4][4], exb[4][4];   // [reg][nt]
#pragma unroll
  for (int reg=0;reg<4;reg++){
    int s_ = ((const int*)&sv)[reg], d_ = ((const int*)&dv)[reg];
#pragma unroll
    for (int nt=0;nt<4;nt++){
      exa[reg][nt] = pa[(size_t)s_*64 + nt*16 + cl];
      exb[reg][nt] = pb[(size_t)d_*64 + nt*16 + cl];
    }
  }

  float* xsw = (float*)xs4;

  if constexpr (FUSE){
    // stage gathered eattr rows: thread t -> row t>>2, quad t&3
    {
      const int er = t>>2, q = t&3;
      int e = eord[rowbase + er];
      eas[er*4+q] = ((const float4*)(eattr + (size_t)e*16))[q];
    }
    __syncthreads();
    // encode: he_row = relu(eattr @ We + be), K=16 (padded to 32)
    f32x4 c0={0,0,0,0}, c1={0,0,0,0}, c2={0,0,0,0}, c3={0,0,0,0};
    short8b ahi, alo;
    if (kgrp < 2){
      float4 a0 = eas[lrow*4 + kgrp*2];
      float4 a1 = eas[lrow*4 + kgrp*2 + 1];
      mk_frag(a0, a1, ahi, alo);
    } else {
      ahi = (short8b){0,0,0,0,0,0,0,0};
      alo = (short8b){0,0,0,0,0,0,0,0};
    }
    const short8b* Wh = (const short8b*)weh;
    const short8b* Wl = (const short8b*)wel;
#pragma unroll
    for (int nt=0;nt<4;nt++){
      short8b bh = Wh[nt*64 + lane];
      short8b bl = Wl[nt*64 + lane];
      f32x4 c = (nt==0)?c0:(nt==1)?c1:(nt==2)?c2:c3;
      c = __builtin_amdgcn_mfma_f32_16x16x32_bf16(ahi, bh, c, 0,0,0);
      c = __builtin_amdgcn_mfma_f32_16x16x32_bf16(alo, bh, c, 0,0,0);
      c = __builtin_amdgcn_mfma_f32_16x16x32_bf16(ahi, bl, c, 0,0,0);
      if (nt==0) c0=c; else if (nt==1) c1=c; else if (nt==2) c2=c; else c3=c;
    }
    // write he rows (own wave slice) into xs4
#pragma unroll
    for (int nt=0;nt<4;nt++){
      int cn = nt*16 + cl;
      f32x4 c = (nt==0)?c0:(nt==1)?c1:(nt==2)?c2:c3;
#pragma unroll
      for (int reg=0;reg<4;reg++){
        float h = fmaxf(c[reg] + bsm[5][cn], 0.f);
        xsw[(16*wv + 4*kgrp + reg)*68 + cn] = h;
      }
    }
  } else {
    // stage he rows (coalesced)
    const float4* heb = (const float4*)(he + (size_t)rowbase*64);
#pragma unroll
    for (int i=0;i<4;i++){
      int idx = t + i*256;
      xs4[(idx>>4)*17 + (idx&15)] = heb[idx];
    }
    __syncthreads();
  }

  const short8b* W1h = (const short8b*)w1h;
  const short8b* W1l = (const short8b*)w1l;
  const short8b* W2h = (const short8b*)w2h;
  const short8b* W2l = (const short8b*)w2l;

  // ---- GEMM1: C = he @ W1 ----
  f32x4 acc0 = {0,0,0,0}, acc1 = {0,0,0,0}, acc2_ = {0,0,0,0}, acc3 = {0,0,0,0};
#pragma unroll
  for (int kc=0;kc<2;kc++){
    float4 a0 = xs4[lrow*17 + kc*8 + kgrp*2];
    float4 a1 = xs4[lrow*17 + kc*8 + kgrp*2 + 1];
    short8b ahi, alo; mk_frag(a0, a1, ahi, alo);
#pragma unroll
    for (int nt=0;nt<4;nt++){
      short8b bh = W1h[(kc*4+nt)*64 + lane];
      short8b bl = W1l[(kc*4+nt)*64 + lane];
      f32x4 c = (nt==0)?acc0:(nt==1)?acc1:(nt==2)?acc2_:acc3;
      c = __builtin_amdgcn_mfma_f32_16x16x32_bf16(ahi, bh, c, 0,0,0);
      c = __builtin_amdgcn_mfma_f32_16x16x32_bf16(alo, bh, c, 0,0,0);
      c = __builtin_amdgcn_mfma_f32_16x16x32_bf16(ahi, bl, c, 0,0,0);
      if (nt==0) acc0=c; else if (nt==1) acc1=c; else if (nt==2) acc2_=c; else acc3=c;
    }
  }

  // ---- epilogue1: h1 = relu(C + b1 + ue + pa[src] + pb[dst]) -> LDS ----
#pragma unroll
  for (int nt=0;nt<4;nt++){
    int cn = nt*16 + cl;
    float bc = bsm[0][cn] + bsm[4][cn];
    f32x4 c = (nt==0)?acc0:(nt==1)?acc1:(nt==2)?acc2_:acc3;
#pragma unroll
    for (int reg=0;reg<4;reg++){
      float h = fmaxf(c[reg] + bc + exa[reg][nt] + exb[reg][nt], 0.f);
      xsw[(16*wv + 4*kgrp + reg)*68 + cn] = h;
    }
  }
  // same-wave rows only -> no barrier needed

  // ---- GEMM2 ----
  f32x4 d0 = {0,0,0,0}, d1 = {0,0,0,0}, d2 = {0,0,0,0}, d3 = {0,0,0,0};
#pragma unroll
  for (int kc=0;kc<2;kc++){
    float4 a0 = xs4[lrow*17 + kc*8 + kgrp*2];
    float4 a1 = xs4[lrow*17 + kc*8 + kgrp*2 + 1];
    short8b ahi, alo; mk_frag(a0, a1, ahi, alo);
#pragma unroll
    for (int nt=0;nt<4;nt++){
      short8b bh = W2h[(kc*4+nt)*64 + lane];
      short8b bl = W2l[(kc*4+nt)*64 + lane];
      f32x4 c = (nt==0)?d0:(nt==1)?d1:(nt==2)?d2:d3;
      c = __builtin_amdgcn_mfma_f32_16x16x32_bf16(ahi, bh, c, 0,0,0);
      c = __builtin_amdgcn_mfma_f32_16x16x32_bf16(alo, bh, c, 0,0,0);
      c = __builtin_amdgcn_mfma_f32_16x16x32_bf16(ahi, bl, c, 0,0,0);
      if (nt==0) d0=c; else if (nt==1) d1=c; else if (nt==2) d2=c; else d3=c;
    }
  }

  // ---- LayerNorm + store ----
#pragma unroll
  for (int reg=0;reg<4;reg++){
    float v0 = d0[reg] + bsm[1][cl];
    float v1 = d1[reg] + bsm[1][16+cl];
    float v2 = d2[reg] + bsm[1][32+cl];
    float v3 = d3[reg] + bsm[1][48+cl];
    float sA = v0+v1+v2+v3;
    float sB = v0*v0+v1*v1+v2*v2+v3*v3;
#pragma unroll
    for (int m=1;m<16;m<<=1){ sA += __shfl_xor(sA,m); sB += __shfl_xor(sB,m); }
    float mean = sA * 0.015625f;
    float var  = sB * 0.015625f - mean*mean;
    float inv  = 1.0f / sqrtf(var + 1e-5f);
    float* orow = outp + (size_t)(grow0 + reg)*64;
    orow[cl]    = (v0-mean)*inv*bsm[2][cl]    + bsm[3][cl];
    orow[16+cl] = (v1-mean)*inv*bsm[2][16+cl] + bsm[3][16+cl];
    orow[32+cl] = (v2-mean)*inv*bsm[2][32+cl] + bsm[3][32+cl];
    orow[48+cl] = (v3-mean)*inv*bsm[2][48+cl] + bsm[3][48+cl];
  }
}

// ---------------- node MLP via split-bf16 MFMA (DIN=128: [hn,agg]) ----------------
__global__ __launch_bounds__(256) void node_mlp_mfma(
    const float* __restrict__ hn, const float* __restrict__ agg,
    const float* __restrict__ un,
    const short* __restrict__ w1h, const short* __restrict__ w1l,
    const short* __restrict__ w2h, const short* __restrict__ w2l,
    const float* __restrict__ b1, const float* __restrict__ b2,
    const float* __restrict__ lng, const float* __restrict__ lnb,
    float* __restrict__ outp)
{
  __shared__ float4 xs4[64*33];   // 64 rows x 128 f (+pad); reused for h1
  __shared__ float  bsm[5][64];   // b1, b2, ln_g, ln_b, un

  const int t = threadIdx.x;
  const int rowbase = blockIdx.x*64;
  const int g = rowbase >> 9;

  if (t < 64){ bsm[0][t] = b1[t]; bsm[4][t] = un[(g<<6)+t]; }
  else if (t < 128) bsm[1][t-64]  = b2[t-64];
  else if (t < 192) bsm[2][t-128] = lng[t-128];
  else              bsm[3][t-192] = lnb[t-192];

  const int wv = t>>6, lane = t&63, cl = lane&15, kgrp = lane>>4;
  const int lrow  = 16*wv + cl;
  const int grow0 = rowbase + 16*wv + 4*kgrp;

  // stage [hn | agg] rows
  {
    const float4* hn4 = (const float4*)(hn  + (size_t)rowbase*64);
    const float4* ag4 = (const float4*)(agg + (size_t)rowbase*64);
#pragma unroll
    for (int i=0;i<4;i++){
      int idx = t + i*256;
      xs4[(idx>>4)*33 + (idx&15)] = hn4[idx];
    }
#pragma unroll
    for (int i=0;i<4;i++){
      int idx = t + i*256;
      xs4[(idx>>4)*33 + 16 + (idx&15)] = ag4[idx];
    }
  }
  __syncthreads();

  const short8b* W1h = (const short8b*)w1h;
  const short8b* W1l = (const short8b*)w1l;
  const short8b* W2h = (const short8b*)w2h;
  const short8b* W2l = (const short8b*)w2l;

  // ---- GEMM1 (K=128) ----
  f32x4 acc0 = {0,0,0,0}, acc1 = {0,0,0,0}, acc2_ = {0,0,0,0}, acc3 = {0,0,0,0};
#pragma unroll
  for (int kc=0;kc<4;kc++){
    float4 a0 = xs4[lrow*33 + kc*8 + kgrp*2];
    float4 a1 = xs4[lrow*33 + kc*8 + kgrp*2 + 1];
    short8b ahi, alo; mk_frag(a0, a1, ahi, alo);
#pragma unroll
    for (int nt=0;nt<4;nt++){
      short8b bh = W1h[(kc*4+nt)*64 + lane];
      short8b bl = W1l[(kc*4+nt)*64 + lane];
      f32x4 c = (nt==0)?acc0:(nt==1)?acc1:(nt==2)?acc2_:acc3;
      c = __builtin_amdgcn_mfma_f32_16x16x32_bf16(ahi, bh, c, 0,0,0);
      c = __builtin_amdgcn_mfma_f32_16x16x32_bf16(alo, bh, c, 0,0,0);
      c = __builtin_amdgcn_mfma_f32_16x16x32_bf16(ahi, bl, c, 0,0,0);
      if (nt==0) acc0=c; else if (nt==1) acc1=c; else if (nt==2) acc2_=c; else acc3=c;
    }
  }

  // ---- epilogue1: h1 = relu(C + b1 + un) -> LDS ----
  float* xsw = (float*)xs4;
#pragma unroll
  for (int nt=0;nt<4;nt++){
    int cn = nt*16 + cl;
    float bc = bsm[0][cn] + bsm[4][cn];
    f32x4 c = (nt==0)?acc0:(nt==1)?acc1:(nt==2)?acc2_:acc3;
#pragma unroll
    for (int reg=0;reg<4;reg++){
      float h = fmaxf(c[reg] + bc, 0.f);
      xsw[(16*wv + 4*kgrp + reg)*132 + cn] = h;
    }
  }

  // ---- GEMM2 (K=64) ----
  f32x4 d0 = {0,0,0,0}, d1 = {0,0,0,0}, d2 = {0,0,0,0}, d3 = {0,0,0,0};
#pragma unroll
  for (int kc=0;kc<2;kc++){
    float4 a0 = xs4[lrow*33 + kc*8 + kgrp*2];
    float4 a1 = xs4[lrow*33 + kc*8 + kgrp*2 + 1];
    short8b ahi, alo; mk_frag(a0, a1, ahi, alo);
#pragma unroll
    for (int nt=0;nt<4;nt++){
      short8b bh = W2h[(kc*4+nt)*64 + lane];
      short8b bl = W2l[(kc*4+nt)*64 + lane];
      f32x4 c = (nt==0)?d0:(nt==1)?d1:(nt==2)?d2:d3;
      c = __builtin_amdgcn_mfma_f32_16x16x32_bf16(ahi, bh, c, 0,0,0);
      c = __builtin_amdgcn_mfma_f32_16x16x32_bf16(alo, bh, c, 0,0,0);
      c = __builtin_amdgcn_mfma_f32_16x16x32_bf16(ahi, bl, c, 0,0,0);
      if (nt==0) d0=c; else if (nt==1) d1=c; else if (nt==2) d2=c; else d3=c;
    }
  }

  // ---- LayerNorm + store ----
#pragma unroll
  for (int reg=0;reg<4;reg++){
    float v0 = d0[reg] + bsm[1][cl];
    float v1 = d1[reg] + bsm[1][16+cl];
    float v2 = d2[reg] + bsm[1][32+cl];
    float v3 = d3[reg] + bsm[1][48+cl];
    float sA = v0+v1+v2+v3;
    float sB = v0*v0+v1*v1+v2*v2+v3*v3;
#pragma unroll
    for (int m=1;m<16;m<<=1){ sA += __shfl_xor(sA,m); sB += __shfl_xor(sB,m); }
    float mean = sA * 0.015625f;
    float var  = sB * 0.015625f - mean*mean;
    float inv  = 1.0f / sqrtf(var + 1e-5f);
    float* orow = outp + (size_t)(grow0 + reg)*64;
    orow[cl]    = (v0-mean)*inv*bsm[2][cl]    + bsm[3][cl];
    orow[16+cl] = (v1-mean)*inv*bsm[2][16+cl] + bsm[3][16+cl];
    orow[32+cl] = (v2-mean)*inv*bsm[2][32+cl] + bsm[3][32+cl];
    orow[48+cl] = (v3-mean)*inv*bsm[2][48+cl] + bsm[3][48+cl];
  }
}

// ---------------- graph MLP (fp32, tiny) ----------------
__global__ __launch_bounds__(256) void gmlp_ln(
    const float* __restrict__ s0, const float* __restrict__ s1,
    const float* __restrict__ s2,
    const float* __restrict__ w1, const float* __restrict__ b1,
    const float* __restrict__ w2, const float* __restrict__ b2,
    const float* __restrict__ lng, const float* __restrict__ lnb,
    float* __restrict__ outp)
{
  constexpr int DIN  = 192;
  constexpr int DP4  = DIN/4 + 1;

  __shared__ float4 xs4[32*DP4];
  __shared__ float4 ws4[1024];
  __shared__ float  bsm[4][64];

  const int t = threadIdx.x;
  const int rowbase = blockIdx.x*32;

  if (t < 64)       bsm[0][t]     = b1[t];
  else if (t < 128) bsm[1][t-64]  = b2[t-64];
  else if (t < 192) bsm[2][t-128] = lng[t-128];
  else              bsm[3][t-192] = lnb[t-192];

  {
    const int gi16 = t >> 4, lg = t & 15;
#pragma unroll
    for (int it = 0; it < 6; ++it){
      int pair = gi16 + (it << 4);
      int er = pair & 31, seg = pair >> 5;
      int row = rowbase + er;
      const float* bp = ((seg==0)? s0 : (seg==1)? s1 : s2) + (size_t)64*row;
      xs4[er*DP4 + seg*16 + lg] = ((const float4*)bp)[lg];
    }
  }
  __syncthreads();

  const int r0 = (t >> 4) * 2, cq = t & 15;
  float acc[2][4] = {{0.f,0.f,0.f,0.f},{0.f,0.f,0.f,0.f}};
  const float4* w1g4 = (const float4*)w1;

  for (int kc = 0; kc < DIN; kc += 64){
    __syncthreads();
    ws4[t]     = w1g4[kc*16 + t];
    ws4[t+256] = w1g4[kc*16 + t + 256];
    ws4[t+512] = w1g4[kc*16 + t + 512];
    ws4[t+768] = w1g4[kc*16 + t + 768];
    __syncthreads();
#pragma unroll
    for (int k4=0;k4<16;k4++){
      float4 a0 = xs4[(r0  )*DP4 + (kc>>2) + k4];
      float4 a1 = xs4[(r0+1)*DP4 + (kc>>2) + k4];
      float4 bb[4];
#pragma unroll
      for (int kk=0;kk<4;kk++) bb[kk] = ws4[(k4*4+kk)*16 + cq];
      const float* a0p = (const float*)&a0;
      const float* a1p = (const float*)&a1;
#pragma unroll
      for (int kk=0;kk<4;kk++){
        acc[0][0]=fmaf(a0p[kk],bb[kk].x,acc[0][0]);
        acc[0][1]=fmaf(a0p[kk],bb[kk].y,acc[0][1]);
        acc[0][2]=fmaf(a0p[kk],bb[kk].z,acc[0][2]);
        acc[0][3]=fmaf(a0p[kk],bb[kk].w,acc[0][3]);
        acc[1][0]=fmaf(a1p[kk],bb[kk].x,acc[1][0]);
        acc[1][1]=fmaf(a1p[kk],bb[kk].y,acc[1][1]);
        acc[1][2]=fmaf(a1p[kk],bb[kk].z,acc[1][2]);
        acc[1][3]=fmaf(a1p[kk],bb[kk].w,acc[1][3]);
      }
    }
  }

  __syncthreads();
  {
    float4 h0, h1v;
    h0.x  = fmaxf(acc[0][0]+bsm[0][cq*4+0], 0.f);
    h0.y  = fmaxf(acc[0][1]+bsm[0][cq*4+1], 0.f);
    h0.z  = fmaxf(acc[0][2]+bsm[0][cq*4+2], 0.f);
    h0.w  = fmaxf(acc[0][3]+bsm[0][cq*4+3], 0.f);
    h1v.x = fmaxf(acc[1][0]+bsm[0][cq*4+0], 0.f);
    h1v.y = fmaxf(acc[1][1]+bsm[0][cq*4+1], 0.f);
    h1v.z = fmaxf(acc[1][2]+bsm[0][cq*4+2], 0.f);
    h1v.w = fmaxf(acc[1][3]+bsm[0][cq*4+3], 0.f);
    xs4[(r0  )*DP4 + cq] = h0;
    xs4[(r0+1)*DP4 + cq] = h1v;
    const float4* w2g4 = (const float4*)w2;
    ws4[t]     = w2g4[t];
    ws4[t+256] = w2g4[t+256];
    ws4[t+512] = w2g4[t+512];
    ws4[t+768] = w2g4[t+768];
  }
  __syncthreads();

  float acc2[2][4] = {{0.f,0.f,0.f,0.f},{0.f,0.f,0.f,0.f}};
#pragma unroll
  for (int k4=0;k4<16;k4++){
    float4 a0 = xs4[(r0  )*DP4 + k4];
    float4 a1 = xs4[(r0+1)*DP4 + k4];
    float4 bb[4];
#pragma unroll
    for (int kk=0;kk<4;kk++) bb[kk] = ws4[(k4*4+kk)*16 + cq];
    const float* a0p = (const float*)&a0;
    const float* a1p = (const float*)&a1;
#pragma unroll
    for (int kk=0;kk<4;kk++){
      acc2[0][0]=fmaf(a0p[kk],bb[kk].x,acc2[0][0]);
      acc2[0][1]=fmaf(a0p[kk],bb[kk].y,acc2[0][1]);
      acc2[0][2]=fmaf(a0p[kk],bb[kk].z,acc2[0][2]);
      acc2[0][3]=fmaf(a0p[kk],bb[kk].w,acc2[0][3]);
      acc2[1][0]=fmaf(a1p[kk],bb[kk].x,acc2[1][0]);
      acc2[1][1]=fmaf(a1p[kk],bb[kk].y,acc2[1][1]);
      acc2[1][2]=fmaf(a1p[kk],bb[kk].z,acc2[1][2]);
      acc2[1][3]=fmaf(a1p[kk],bb[kk].w,acc2[1][3]);
    }
  }

#pragma unroll
  for (int rr=0; rr<2; rr++){
    float v0 = acc2[rr][0] + bsm[1][cq*4+0];
    float v1 = acc2[rr][1] + bsm[1][cq*4+1];
    float v2 = acc2[rr][2] + bsm[1][cq*4+2];
    float v3 = acc2[rr][3] + bsm[1][cq*4+3];
    float sA = v0+v1+v2+v3;
    float sB = v0*v0+v1*v1+v2*v2+v3*v3;
#pragma unroll
    for (int m=1;m<16;m<<=1){ sA += __shfl_xor(sA,m); sB += __shfl_xor(sB,m); }
    float mean = sA * 0.015625f;
    float var  = sB * 0.015625f - mean*mean;
    float inv  = 1.0f / sqrtf(var + 1e-5f);
    float4 o;
    o.x = (v0-mean)*inv*bsm[2][cq*4+0] + bsm[3][cq*4+0];
    o.y = (v1-mean)*inv*bsm[2][cq*4+1] + bsm[3][cq*4+1];
    o.z = (v2-mean)*inv*bsm[2][cq*4+2] + bsm[3][cq*4+2];
    o.w = (v3-mean)*inv*bsm[2][cq*4+3] + bsm[3][cq*4+3];
    ((float4*)(outp + (size_t)(rowbase + r0 + rr)*64))[cq] = o;
  }
}

// ---------------- heads ----------------
__global__ __launch_bounds__(512) void heads_kernel(
    const float* __restrict__ hn, const float* __restrict__ uvec,
    const float* __restrict__ aw, const float* __restrict__ ab,
    const float* __restrict__ cw, const float* __restrict__ cb,
    float* __restrict__ out)
{
  const int g = blockIdx.x, t = threadIdx.x;
  const int n = (g<<9) + t;
  const float4* hp = (const float4*)(hn + (size_t)n*64);
  const float4* ap = (const float4*)aw;
  float d = 0.f;
#pragma unroll
  for (int i=0;i<16;i++){
    float4 h = hp[i], a = ap[i];
    d += h.x*a.x + h.y*a.y + h.z*a.z + h.w*a.w;
  }
  d += ab[0];
  float z = 1.0f/(1.0f + expf(-d));

  unsigned o0,o1;
  threefry(0u, 42u, 0u, (unsigned)n, o0, o1);
  unsigned bits = o0 ^ o1;
  float f = __uint_as_float((bits>>9) | 0x3f800000u) - 1.0f;
  float gum = -logf(-logf(fmaxf(1.17549435e-38f, f)));

  const int lane = t & 63, wid = t >> 6;
  __shared__ float smax[8], ssum[8], sent[8], skey[8];
  __shared__ int   sidx[8];
  __shared__ float sM, sS;
  __shared__ int   sA;

  float m = z;
#pragma unroll
  for (int sh=1; sh<64; sh<<=1) m = fmaxf(m, __shfl_xor(m, sh));
  if (lane==0) smax[wid] = m;
  __syncthreads();
  if (t==0){ float mm=smax[0]; for(int i=1;i<8;i++) mm=fmaxf(mm,smax[i]); sM=mm; }
  __syncthreads();
  float M = sM;
  float ex = expf(z - M);
  float ssl = ex;
#pragma unroll
  for (int sh=1; sh<64; sh<<=1) ssl += __shfl_xor(ssl, sh);
  if (lane==0) ssum[wid] = ssl;
  __syncthreads();
  if (t==0){ float ss=0.f; for(int i=0;i<8;i++) ss+=ssum[i]; sS=ss; }
  __syncthreads();
  float logp = z - M - logf(sS);
  float p = expf(logp);
  float entl = p * logp;
#pragma unroll
  for (int sh=1; sh<64; sh<<=1) entl += __shfl_xor(entl, sh);
  if (lane==0) sent[wid] = entl;

  float kv = z + gum; int ki = t;
#pragma unroll
  for (int sh=1; sh<64; sh<<=1){
    float ov = __shfl_xor(kv, sh);
    int   oi = __shfl_xor(ki, sh);
    if (ov > kv || (ov == kv && oi < ki)){ kv = ov; ki = oi; }
  }
  if (lane==0){ skey[wid] = kv; sidx[wid] = ki; }
  __syncthreads();
  if (t==0){
    float bv = skey[0]; int bi = sidx[0];
    for (int i=1;i<8;i++) if (skey[i] > bv || (skey[i]==bv && sidx[i] < bi)){ bv=skey[i]; bi=sidx[i]; }
    sA = bi;
    float ent = 0.f; for (int i=0;i<8;i++) ent += sent[i];
    out[g]      = (float)bi;
    out[128+g]  = -ent;
  }
  __syncthreads();
  if (t == sA) out[64+g] = logp;

  if (t < 64){
    float pv = uvec[(g<<6)+t] * cw[t];
#pragma unroll
    for (int sh=1; sh<64; sh<<=1) pv += __shfl_xor(pv, sh);
    if (t==0) out[192+g] = pv + cb[0];
  }
}

// ---------------- launch ----------------
extern "C" void kernel_launch(void* const* d_in, const int* in_sizes, int n_in,
                              void* d_out, int out_size, void* d_ws, size_t ws_size,
                              hipStream_t stream)
{
  (void)in_sizes; (void)n_in; (void)out_size; (void)ws_size;
  const float* x      = (const float*)d_in[0];
  const float* eattr  = (const float*)d_in[1];
  const int*   eidx   = (const int*)d_in[2];
  const float* node_w = (const float*)d_in[5];
  const float* node_b = (const float*)d_in[6];
  const float* edge_w = (const float*)d_in[7];
  const float* edge_b = (const float*)d_in[8];
  const float* init_u = (const float*)d_in[9];
  const float* ew1 = (const float*)d_in[10]; const float* eb1 = (const float*)d_in[11];
  const float* ew2 = (const float*)d_in[12]; const float* eb2 = (const float*)d_in[13];
  const float* elg = (const float*)d_in[14]; const float* elb = (const float*)d_in[15];
  const float* nw1 = (const float*)d_in[16]; const float* nb1 = (const float*)d_in[17];
  const float* nw2 = (const float*)d_in[18]; const float* nb2 = (const float*)d_in[19];
  const float* nlg = (const float*)d_in[20]; const float* nlb = (const float*)d_in[21];
  const float* gw1 = (const float*)d_in[22]; const float* gb1 = (const float*)d_in[23];
  const float* gw2 = (const float*)d_in[24]; const float* gb2 = (const float*)d_in[25];
  const float* glg = (const float*)d_in[26]; const float* glb = (const float*)d_in[27];
  const float* aw  = (const float*)d_in[28]; const float* ab  = (const float*)d_in[29];
  const float* cw  = (const float*)d_in[30]; const float* cb  = (const float*)d_in[31];
  const int* src = eidx;
  const int* dst = eidx + EE;

  float* ws    = (float*)d_ws;
  float* hn    = ws;                         // N*64
  float* he    = hn + (size_t)NN*64;         // E*64  (dst-sorted order)
  float* agg   = he + (size_t)EE*64;         // N*64
  float* u     = agg + (size_t)NN*64;        // G*64
  float* nmean = u + GG*64;
  float* emean = nmean + GG*64;
  int* cnt     = (int*)(emean + GG*64);      // N
  int* indptr  = cnt + NN;                   // N+1
  int* fillc   = indptr + NN + 1;            // N
  int* eord    = fillc + NN;                 // E
  int* srcs    = eord + EE;                  // E
  int* dsts    = srcs + EE;                  // E
  float* pb    = (float*)(dsts + EE);        // N*64
  float* ue    = pb + (size_t)NN*64;         // G*64
  float* un    = ue + GG*64;                 // G*64
  float* pn    = un + GG*64;                 // G*4*64
  float* pe    = pn + GG*4*64;               // G*4*64
  short* wfh   = (short*)(pe + GG*4*64);     // 63488 shorts (hi frags)
  short* wfl   = wfh + 63488;                // 63488 shorts (lo frags)

  float* pa = agg;   // pa aliases agg (dead during edge phase)

  float* out = (float*)d_out;

  hipMemsetAsync(cnt,   0, NN*sizeof(int), stream);
  hipMemsetAsync(fillc, 0, NN*sizeof(int), stream);

  count_kernel<<<EE/256, 256, 0, stream>>>(dst, cnt);
  scan_kernel<<<1, 1024, 0, stream>>>(cnt, indptr);
  fill_kernel<<<EE/256, 256, 0, stream>>>(dst, indptr, fillc, eord);
  sort_kernel<<<NN/256, 256, 0, stream>>>(indptr, eord);
  perm_kernel<<<EE/256, 256, 0, stream>>>(src, dst, eord, srcs, dsts);

  encode_kernel<32><<<NN/4, 256, 0, stream>>>(x, node_w, node_b, hn, NN);
  initu_kernel<<<16, 256, 0, stream>>>(init_u, u);
  wprep_kernel<<<31, 256, 0, stream>>>(edge_w, ew1, ew2, nw1, nw2, wfh, wfl);

  // frag offsets (shorts): enc=0; per layer l: e1=2048+l*20480, e2=+4096, n1=+8192, n2=+16384
  for (int l=0; l<NL; ++l){
    const float* ew1l = ew1 + (size_t)l*256*64;
    const float* nw1l = nw1 + (size_t)l*192*64;
    size_t e1o = 2048 + (size_t)l*20480;
    size_t e2o = e1o + 4096, n1o = e1o + 8192, n2o = e1o + 16384;

    pre_kernel<<<NN/32, 256, 0, stream>>>(hn, ew1l, ew1l + 64*64, pa, pb, NN);
    pre_kernel<<<2, 256, 0, stream>>>(u, ew1l + 192*64, nw1l + 128*64, ue, un, GG);

    if (l == 0)
      edge_mlp_mfma<1><<<EE/64, 256, 0, stream>>>(he, eattr, eord, pa, pb, ue, srcs, dsts,
          wfh, wfl, wfh + e1o, wfl + e1o, wfh + e2o, wfl + e2o,
          edge_b, eb1 + l*64, eb2 + l*64, elg + l*64, elb + l*64, he);
    else
      edge_mlp_mfma<0><<<EE/64, 256, 0, stream>>>(he, eattr, eord, pa, pb, ue, srcs, dsts,
          wfh, wfl, wfh + e1o, wfl + e1o, wfh + e2o, wfl + e2o,
          edge_b, eb1 + l*64, eb2 + l*64, elg + l*64, elb + l*64, he);

    agg_kernel<<<NN*16/256, 256, 0, stream>>>(he, indptr, agg);
    node_mlp_mfma<<<NN/64, 256, 0, stream>>>(hn, agg, un,
        wfh + n1o, wfl + n1o, wfh + n2o, wfl + n2o,
        nb1 + l*64, nb2 + l*64, nlg + l*64, nlb + l*64, hn);
    pmeans_kernel<<<GG*4, 256, 0, stream>>>(hn, agg, pn, pe);
    fmeans_kernel<<<GG, 64, 0, stream>>>(pn, pe, nmean, emean);
    gmlp_ln<<<GG/32, 256, 0, stream>>>(u, nmean, emean,
        gw1 + (size_t)l*192*64, gb1 + l*64, gw2 + (size_t)l*64*64, gb2 + l*64,
        glg + l*64, glb + l*64, u);
  }

  heads_kernel<<<GG, 512, 0, stream>>>(hn, u, aw, ab, cw, cb, out);
}

// Round 8
// 381.010 us; speedup vs baseline: 4.3521x; 1.0924x over previous
//
#include <hip/hip_runtime.h>
#include <math.h>

#define GG 64
#define NPGc 512
#define NN (GG*NPGc)      // 32768 nodes
#define EE (NN*8)         // 262144 edges
#define HH 64
#define NL 3

typedef __attribute__((ext_vector_type(8))) short short8b;
typedef __attribute__((ext_vector_type(4))) float f32x4;

// ---------------- bf16 split helpers ----------------
__device__ __forceinline__ unsigned short f2bf_rne(float f){
  unsigned u = __float_as_uint(f);
  unsigned r = u + 0x7fffu + ((u>>16)&1u);
  return (unsigned short)(r>>16);
}
__device__ __forceinline__ float bf2f(unsigned short h){
  return __uint_as_float(((unsigned)h)<<16);
}
__device__ __forceinline__ void mk_frag(const float4 &u, const float4 &v, short8b &hi, short8b &lo){
  float av[8] = {u.x,u.y,u.z,u.w,v.x,v.y,v.z,v.w};
#pragma unroll
  for (int j=0;j<8;j++){
    unsigned short h = f2bf_rne(av[j]);
    hi[j] = (short)h;
    lo[j] = (short)f2bf_rne(av[j] - bf2f(h));
  }
}

// ---------------- threefry2x32 (JAX-compatible, partitionable mode) ----------------
__device__ __forceinline__ unsigned rotl32(unsigned x, int r){ return (x<<r)|(x>>(32-r)); }
__device__ __forceinline__ void threefry(unsigned k0, unsigned k1, unsigned x0, unsigned x1,
                                         unsigned &o0, unsigned &o1){
  unsigned ks2 = k0 ^ k1 ^ 0x1BD11BDAu;
  unsigned v0 = x0 + k0, v1 = x1 + k1;
#define R4(a,b,c,d) v0+=v1; v1=rotl32(v1,a); v1^=v0; v0+=v1; v1=rotl32(v1,b); v1^=v0; \
                    v0+=v1; v1=rotl32(v1,c); v1^=v0; v0+=v1; v1=rotl32(v1,d); v1^=v0;
  R4(13,15,26,6)  v0+=k1;  v1+=ks2+1u;
  R4(17,29,16,24) v0+=ks2; v1+=k0+2u;
  R4(13,15,26,6)  v0+=k0;  v1+=k1+3u;
  R4(17,29,16,24) v0+=k1;  v1+=ks2+4u;
  R4(13,15,26,6)  v0+=ks2; v1+=k0+5u;
#undef R4
  o0=v0; o1=v1;
}

// ---------------- node encoder ----------------
template<int K>
__global__ __launch_bounds__(256) void encode_kernel(const float* __restrict__ in,
    const float* __restrict__ w, const float* __restrict__ b,
    float* __restrict__ out, int rows)
{
  int wid = blockIdx.x*4 + (threadIdx.x>>6);
  int lane = threadIdx.x & 63;
  if (wid >= rows) return;
  const float* xr = in + (size_t)wid*K;
  float acc = b[lane];
#pragma unroll
  for (int i=0;i<K;i++) acc = fmaf(xr[i], w[i*64+lane], acc);
  out[(size_t)wid*64+lane] = fmaxf(acc, 0.f);
}

__global__ __launch_bounds__(256) void initu_kernel(const float* __restrict__ iu, float* __restrict__ u){
  int i = blockIdx.x*256 + threadIdx.x;
  if (i < GG*64) u[i] = iu[i & 63];
}

// ---------------- CSR build ----------------
__global__ __launch_bounds__(256) void count_kernel(const int* __restrict__ dst, int* __restrict__ cnt){
  int e = blockIdx.x*256 + threadIdx.x;
  if (e < EE) atomicAdd(&cnt[dst[e]], 1);
}
__global__ __launch_bounds__(1024) void scan_kernel(const int* __restrict__ cnt, int* __restrict__ indptr){
  __shared__ int part[1024];
  const int t = threadIdx.x;
  const int base = t*32;
  int s = 0;
  for (int i=0;i<32;i++) s += cnt[base+i];
  part[t] = s;
  __syncthreads();
  for (int off=1; off<1024; off<<=1){
    int v = part[t];
    int add = (t >= off) ? part[t-off] : 0;
    __syncthreads();
    part[t] = v + add;
    __syncthreads();
  }
  int run = (t==0) ? 0 : part[t-1];
  for (int i=0;i<32;i++){ indptr[base+i] = run; run += cnt[base+i]; }
  if (t==1023) indptr[NN] = run;
}
__global__ __launch_bounds__(256) void fill_kernel(const int* __restrict__ dst, const int* __restrict__ indptr,
                                                   int* __restrict__ fillc, int* __restrict__ eord){
  int e = blockIdx.x*256 + threadIdx.x;
  if (e < EE){ int dn = dst[e]; int p = atomicAdd(&fillc[dn], 1); eord[indptr[dn]+p] = e; }
}
__global__ __launch_bounds__(256) void sort_kernel(const int* __restrict__ indptr, int* __restrict__ eord){
  int n = blockIdx.x*256 + threadIdx.x;
  if (n >= NN) return;
  int lo = indptr[n], hi = indptr[n+1];
  for (int i=lo+1;i<hi;i++){
    int v = eord[i]; int j = i-1;
    while (j >= lo && eord[j] > v){ eord[j+1]=eord[j]; j--; }
    eord[j+1] = v;
  }
}
__global__ __launch_bounds__(256) void perm_kernel(const int* __restrict__ src, const int* __restrict__ dst,
                                                   const int* __restrict__ eord,
                                                   int* __restrict__ srcs, int* __restrict__ dsts){
  int p = blockIdx.x*256 + threadIdx.x;
  if (p < EE){ int e = eord[p]; srcs[p] = src[e]; dsts[p] = dst[e]; }
}

// ---------------- agg fixup: spanning nodes + boundary zero-degree nodes ----------------
__global__ __launch_bounds__(256) void aggfix_kernel(const int* __restrict__ indptr,
    const float* __restrict__ headp, const float* __restrict__ tailp, float* __restrict__ agg){
  int idx = blockIdx.x*256 + threadIdx.x;
  int n = idx >> 4, cq = idx & 15;
  if (n >= NN) return;
  int lo = indptr[n], hi = indptr[n+1];
  if (lo == hi){
    if ((lo & 63) == 0){
      float4 z = {0,0,0,0};
      ((float4*)(agg + (size_t)n*64))[cq] = z;
    }
    return;
  }
  int b0 = lo >> 6, b1 = (hi-1) >> 6;
  if (b0 == b1) return;
  float4 a = ((const float4*)(tailp + (size_t)b0*64))[cq];
  for (int b = b0+1; b <= b1; ++b){
    float4 h = ((const float4*)(headp + (size_t)b*64))[cq];
    a.x+=h.x; a.y+=h.y; a.z+=h.z; a.w+=h.w;
  }
  ((float4*)(agg + (size_t)n*64))[cq] = a;
}

// ---------------- per-graph means, stage 2 (8 chunks per graph) ----------------
__global__ __launch_bounds__(64) void fmeans_kernel(const float* __restrict__ pn, const float* __restrict__ pe,
                                                    float* __restrict__ nmean, float* __restrict__ emean){
  const int g = blockIdx.x, col = threadIdx.x;
  float ns = 0.f, es = 0.f;
  for (int c=0;c<8;c++){
    ns += pn[(size_t)(g*8+c)*64 + col];
    es += pe[(size_t)(g*8+c)*64 + col];
  }
  nmean[g*64+col] = ns * (1.f/512.f);
  emean[g*64+col] = es * (1.f/4096.f);
}

// ---------------- pre_kernel: oa = x@wa, ob = x@wb ----------------
__global__ __launch_bounds__(256) void pre_kernel(const float* __restrict__ x,
    const float* __restrict__ wa, const float* __restrict__ wb,
    float* __restrict__ oa, float* __restrict__ ob, int rows)
{
  __shared__ float4 xs4[32*17];
  __shared__ float4 wsa[1024], wsb[1024];
  const int t = threadIdx.x;
  const int rowbase = blockIdx.x*32;
  {
    const int gi16 = t>>4, lg = t&15;
#pragma unroll
    for (int it=0; it<2; ++it){
      int er = gi16 + (it<<4);
      xs4[er*17+lg] = ((const float4*)(x + (size_t)64*(rowbase+er)))[lg];
    }
  }
  const float4* wa4 = (const float4*)wa;
  const float4* wb4 = (const float4*)wb;
#pragma unroll
  for (int i=0;i<4;i++){ wsa[t+i*256] = wa4[t+i*256]; wsb[t+i*256] = wb4[t+i*256]; }
  __syncthreads();

  const int r0 = (t>>4)*2, cq = t&15;
  float accA[2][4] = {{0,0,0,0},{0,0,0,0}};
  float accB[2][4] = {{0,0,0,0},{0,0,0,0}};
#pragma unroll
  for (int k4=0;k4<16;k4++){
    float4 a0 = xs4[(r0  )*17 + k4];
    float4 a1 = xs4[(r0+1)*17 + k4];
    const float* a0p = (const float*)&a0;
    const float* a1p = (const float*)&a1;
#pragma unroll
    for (int kk=0;kk<4;kk++){
      float4 ba = wsa[(k4*4+kk)*16 + cq];
      float4 bb = wsb[(k4*4+kk)*16 + cq];
      accA[0][0]=fmaf(a0p[kk],ba.x,accA[0][0]); accA[0][1]=fmaf(a0p[kk],ba.y,accA[0][1]);
      accA[0][2]=fmaf(a0p[kk],ba.z,accA[0][2]); accA[0][3]=fmaf(a0p[kk],ba.w,accA[0][3]);
      accA[1][0]=fmaf(a1p[kk],ba.x,accA[1][0]); accA[1][1]=fmaf(a1p[kk],ba.y,accA[1][1]);
      accA[1][2]=fmaf(a1p[kk],ba.z,accA[1][2]); accA[1][3]=fmaf(a1p[kk],ba.w,accA[1][3]);
      accB[0][0]=fmaf(a0p[kk],bb.x,accB[0][0]); accB[0][1]=fmaf(a0p[kk],bb.y,accB[0][1]);
      accB[0][2]=fmaf(a0p[kk],bb.z,accB[0][2]); accB[0][3]=fmaf(a0p[kk],bb.w,accB[0][3]);
      accB[1][0]=fmaf(a1p[kk],bb.x,accB[1][0]); accB[1][1]=fmaf(a1p[kk],bb.y,accB[1][1]);
      accB[1][2]=fmaf(a1p[kk],bb.z,accB[1][2]); accB[1][3]=fmaf(a1p[kk],bb.w,accB[1][3]);
    }
  }
#pragma unroll
  for (int rr=0; rr<2; rr++){
    size_t row = rowbase + r0 + rr;
    float4 va = {accA[rr][0],accA[rr][1],accA[rr][2],accA[rr][3]};
    float4 vb = {accB[rr][0],accB[rr][1],accB[rr][2],accB[rr][3]};
    ((float4*)(oa + row*64))[cq] = va;
    ((float4*)(ob + row*64))[cq] = vb;
  }
}

// ---------------- weight prep: per-lane MFMA B-fragments (bf16 hi/lo) ----------------
__global__ __launch_bounds__(256) void wprep_kernel(const float* __restrict__ edge_w,
    const float* __restrict__ ew1, const float* __restrict__ ew2,
    const float* __restrict__ nw1, const float* __restrict__ nw2,
    short* __restrict__ wfhi, short* __restrict__ wflo)
{
  int b = blockIdx.x;   // 31 blocks: one per (matrix, kc)
  int m = 0, kc = 0; size_t doff = 0; int rem = b;
  for (m = 0; m < 13; m++){
    int kcs = (m==0) ? 1 : ((((m-1)&3)==2) ? 4 : 2);
    if (rem < kcs){ kc = rem; break; }
    rem -= kcs; doff += (size_t)kcs*2048;
  }
  const float* W; int K;
  if (m == 0){ W = edge_w; K = 16; }
  else {
    int l = (m-1)>>2, r = (m-1)&3;
    if      (r==0){ W = ew1 + (size_t)l*16384 + 8192; K = 64;  }
    else if (r==1){ W = ew2 + (size_t)l*4096;         K = 64;  }
    else if (r==2){ W = nw1 + (size_t)l*12288;        K = 128; }
    else          { W = nw2 + (size_t)l*4096;         K = 64;  }
  }
  const int nt = threadIdx.x>>6, lane = threadIdx.x&63;
#pragma unroll
  for (int j=0;j<8;j++){
    int k = kc*32 + (lane>>4)*8 + j;
    int n = nt*16 + (lane&15);
    float v = (k < K) ? W[k*64+n] : 0.f;
    size_t o = doff + (size_t)kc*2048 + (size_t)((nt*64+lane)*8+j);
    unsigned short hi = f2bf_rne(v);
    wfhi[o] = (short)hi;
    wflo[o] = (short)f2bf_rne(v - bf2f(hi));
  }
}

// ---------------- edge MLP via split-bf16 MFMA + fused deterministic aggregation ----------------
// 64 edges/block, 4 waves. FUSE=1: inline edge encoder (layer 0). WRITE_HE=0: skip he store (last layer).
template<int FUSE, int WRITE_HE>
__global__ __launch_bounds__(256) void edge_mlp_mfma(
    const float* __restrict__ he, const float* __restrict__ eattr,
    const int* __restrict__ eord,
    const float* __restrict__ pa, const float* __restrict__ pb,
    const float* __restrict__ ue,
    const int* __restrict__ srcs, const int* __restrict__ dsts,
    const int* __restrict__ indptr,
    const short* __restrict__ weh, const short* __restrict__ wel,
    const short* __restrict__ w1h, const short* __restrict__ w1l,
    const short* __restrict__ w2h, const short* __restrict__ w2l,
    const float* __restrict__ eb, const float* __restrict__ b1,
    const float* __restrict__ b2,
    const float* __restrict__ lng, const float* __restrict__ lnb,
    float* __restrict__ outp,
    float* __restrict__ aggp, float* __restrict__ headp, float* __restrict__ tailp)
{
  __shared__ float4 xs4[64*17];            // he rows -> h1 rows -> LN-out rows (68 f stride)
  __shared__ float4 eas[FUSE ? 64*4 : 1];  // gathered eattr rows [64][16]f
  __shared__ float  bsm[6][64];            // b1, b2, ln_g, ln_b, ue, eb
  __shared__ int    ds_dst[64];

  const int t = threadIdx.x;
  const int rowbase = blockIdx.x*64;
  const int g = rowbase >> 12;

  if (t < 64){
    bsm[0][t] = b1[t]; bsm[4][t] = ue[(g<<6)+t];
    if constexpr (FUSE) bsm[5][t] = eb[t];
    ds_dst[t] = dsts[rowbase + t];
  }
  else if (t < 128) bsm[1][t-64]  = b2[t-64];
  else if (t < 192) bsm[2][t-128] = lng[t-128];
  else              bsm[3][t-192] = lnb[t-192];

  const int wv = t>>6, lane = t&63, cl = lane&15, kgrp = lane>>4;
  const int lrow  = 16*wv + cl;                 // A-fragment row
  const int grow0 = rowbase + 16*wv + 4*kgrp;   // C rows grow0..grow0+3

  // early: src/dst + pa/pb gathers (hidden under GEMM1)
  int4 sv = ((const int4*)srcs)[grow0>>2];
  int4 dv = ((const int4*)dsts)[grow0>>2];
  float exa[4][4], exb[4][4];   // [reg][nt]
#pragma unroll
  for (int reg=0;reg<4;reg++){
    int s_ = ((const int*)&sv)[reg], d_ = ((const int*)&dv)[reg];
#pragma unroll
    for (int nt=0;nt<4;nt++){
      exa[reg][nt] = pa[(size_t)s_*64 + nt*16 + cl];
      exb[reg][nt] = pb[(size_t)d_*64 + nt*16 + cl];
    }
  }

  float* xsw = (float*)xs4;

  if constexpr (FUSE){
    {
      const int er = t>>2, q = t&3;
      int e = eord[rowbase + er];
      eas[er*4+q] = ((const float4*)(eattr + (size_t)e*16))[q];
    }
    __syncthreads();
    // encode: he_row = relu(eattr @ We + be), K=16 (padded to 32)
    f32x4 c0={0,0,0,0}, c1={0,0,0,0}, c2={0,0,0,0}, c3={0,0,0,0};
    short8b ahi, alo;
    if (kgrp < 2){
      float4 a0 = eas[lrow*4 + kgrp*2];
      float4 a1 = eas[lrow*4 + kgrp*2 + 1];
      mk_frag(a0, a1, ahi, alo);
    } else {
      ahi = (short8b){0,0,0,0,0,0,0,0};
      alo = (short8b){0,0,0,0,0,0,0,0};
    }
    const short8b* Wh = (const short8b*)weh;
    const short8b* Wl = (const short8b*)wel;
#pragma unroll
    for (int nt=0;nt<4;nt++){
      short8b bh = Wh[nt*64 + lane];
      short8b bl = Wl[nt*64 + lane];
      f32x4 c = (nt==0)?c0:(nt==1)?c1:(nt==2)?c2:c3;
      c = __builtin_amdgcn_mfma_f32_16x16x32_bf16(ahi, bh, c, 0,0,0);
      c = __builtin_amdgcn_mfma_f32_16x16x32_bf16(alo, bh, c, 0,0,0);
      c = __builtin_amdgcn_mfma_f32_16x16x32_bf16(ahi, bl, c, 0,0,0);
      if (nt==0) c0=c; else if (nt==1) c1=c; else if (nt==2) c2=c; else c3=c;
    }
#pragma unroll
    for (int nt=0;nt<4;nt++){
      int cn = nt*16 + cl;
      f32x4 c = (nt==0)?c0:(nt==1)?c1:(nt==2)?c2:c3;
#pragma unroll
      for (int reg=0;reg<4;reg++){
        float h = fmaxf(c[reg] + bsm[5][cn], 0.f);
        xsw[(16*wv + 4*kgrp + reg)*68 + cn] = h;
      }
    }
  } else {
    const float4* heb = (const float4*)(he + (size_t)rowbase*64);
#pragma unroll
    for (int i=0;i<4;i++){
      int idx = t + i*256;
      xs4[(idx>>4)*17 + (idx&15)] = heb[idx];
    }
    __syncthreads();
  }

  const short8b* W1h = (const short8b*)w1h;
  const short8b* W1l = (const short8b*)w1l;
  const short8b* W2h = (const short8b*)w2h;
  const short8b* W2l = (const short8b*)w2l;

  // ---- GEMM1: C = he @ W1 ----
  f32x4 acc0 = {0,0,0,0}, acc1 = {0,0,0,0}, acc2_ = {0,0,0,0}, acc3 = {0,0,0,0};
#pragma unroll
  for (int kc=0;kc<2;kc++){
    float4 a0 = xs4[lrow*17 + kc*8 + kgrp*2];
    float4 a1 = xs4[lrow*17 + kc*8 + kgrp*2 + 1];
    short8b ahi, alo; mk_frag(a0, a1, ahi, alo);
#pragma unroll
    for (int nt=0;nt<4;nt++){
      short8b bh = W1h[(kc*4+nt)*64 + lane];
      short8b bl = W1l[(kc*4+nt)*64 + lane];
      f32x4 c = (nt==0)?acc0:(nt==1)?acc1:(nt==2)?acc2_:acc3;
      c = __builtin_amdgcn_mfma_f32_16x16x32_bf16(ahi, bh, c, 0,0,0);
      c = __builtin_amdgcn_mfma_f32_16x16x32_bf16(alo, bh, c, 0,0,0);
      c = __builtin_amdgcn_mfma_f32_16x16x32_bf16(ahi, bl, c, 0,0,0);
      if (nt==0) acc0=c; else if (nt==1) acc1=c; else if (nt==2) acc2_=c; else acc3=c;
    }
  }

  // ---- epilogue1: h1 = relu(C + b1 + ue + pa[src] + pb[dst]) -> LDS ----
#pragma unroll
  for (int nt=0;nt<4;nt++){
    int cn = nt*16 + cl;
    float bc = bsm[0][cn] + bsm[4][cn];
    f32x4 c = (nt==0)?acc0:(nt==1)?acc1:(nt==2)?acc2_:acc3;
#pragma unroll
    for (int reg=0;reg<4;reg++){
      float h = fmaxf(c[reg] + bc + exa[reg][nt] + exb[reg][nt], 0.f);
      xsw[(16*wv + 4*kgrp + reg)*68 + cn] = h;
    }
  }
  // same-wave rows only -> no barrier needed

  // ---- GEMM2 ----
  f32x4 d0 = {0,0,0,0}, d1 = {0,0,0,0}, d2 = {0,0,0,0}, d3 = {0,0,0,0};
#pragma unroll
  for (int kc=0;kc<2;kc++){
    float4 a0 = xs4[lrow*17 + kc*8 + kgrp*2];
    float4 a1 = xs4[lrow*17 + kc*8 + kgrp*2 + 1];
    short8b ahi, alo; mk_frag(a0, a1, ahi, alo);
#pragma unroll
    for (int nt=0;nt<4;nt++){
      short8b bh = W2h[(kc*4+nt)*64 + lane];
      short8b bl = W2l[(kc*4+nt)*64 + lane];
      f32x4 c = (nt==0)?d0:(nt==1)?d1:(nt==2)?d2:d3;
      c = __builtin_amdgcn_mfma_f32_16x16x32_bf16(ahi, bh, c, 0,0,0);
      c = __builtin_amdgcn_mfma_f32_16x16x32_bf16(alo, bh, c, 0,0,0);
      c = __builtin_amdgcn_mfma_f32_16x16x32_bf16(ahi, bl, c, 0,0,0);
      if (nt==0) d0=c; else if (nt==1) d1=c; else if (nt==2) d2=c; else d3=c;
    }
  }

  // ---- LayerNorm + store (global if WRITE_HE) + LDS out-tile for aggregation ----
#pragma unroll
  for (int reg=0;reg<4;reg++){
    float v0 = d0[reg] + bsm[1][cl];
    float v1 = d1[reg] + bsm[1][16+cl];
    float v2 = d2[reg] + bsm[1][32+cl];
    float v3 = d3[reg] + bsm[1][48+cl];
    float sA = v0+v1+v2+v3;
    float sB = v0*v0+v1*v1+v2*v2+v3*v3;
#pragma unroll
    for (int m=1;m<16;m<<=1){ sA += __shfl_xor(sA,m); sB += __shfl_xor(sB,m); }
    float mean = sA * 0.015625f;
    float var  = sB * 0.015625f - mean*mean;
    float inv  = 1.0f / sqrtf(var + 1e-5f);
    float o0v = (v0-mean)*inv*bsm[2][cl]    + bsm[3][cl];
    float o1v = (v1-mean)*inv*bsm[2][16+cl] + bsm[3][16+cl];
    float o2v = (v2-mean)*inv*bsm[2][32+cl] + bsm[3][32+cl];
    float o3v = (v3-mean)*inv*bsm[2][48+cl] + bsm[3][48+cl];
    float* lr = xsw + (16*wv + 4*kgrp + reg)*68;
    lr[cl] = o0v; lr[16+cl] = o1v; lr[32+cl] = o2v; lr[48+cl] = o3v;
    if constexpr (WRITE_HE){
      float* orow = outp + (size_t)(grow0 + reg)*64;
      orow[cl] = o0v; orow[16+cl] = o1v; orow[32+cl] = o2v; orow[48+cl] = o3v;
    }
  }
  __syncthreads();

  // ---- fused deterministic aggregation over dst-sorted runs ----
  {
    const int n0 = ds_dst[0], nL = ds_dst[63];
    const int s = t >> 4, cq2 = t & 15;
    const size_t b = blockIdx.x;
    for (int n = n0 + s; n <= nL; n += 16){
      int lo = indptr[n], hi = indptr[n+1];
      int lo_c = lo - rowbase; if (lo_c < 0) lo_c = 0;
      int hi_c = hi - rowbase; if (hi_c > 64) hi_c = 64;
      float4 a = {0,0,0,0};
      for (int p = lo_c; p < hi_c; ++p){
        const float* rp = xsw + p*68 + cq2*4;
        a.x += rp[0]; a.y += rp[1]; a.z += rp[2]; a.w += rp[3];
      }
      if (lo < rowbase)              ((float4*)(headp + b*64))[cq2] = a;
      else if (hi > rowbase + 64)    ((float4*)(tailp + b*64))[cq2] = a;
      else                           ((float4*)(aggp + (size_t)n*64))[cq2] = a;
    }
    if (s == 0 && !(indptr[n0] < rowbase)){
      float4 z = {0,0,0,0};
      ((float4*)(headp + b*64))[cq2] = z;
    }
    if (s == 1){
      int lo = indptr[nL], hi = indptr[nL+1];
      if (!(lo >= rowbase && hi > rowbase + 64)){
        float4 z = {0,0,0,0};
        ((float4*)(tailp + b*64))[cq2] = z;
      }
    }
  }
}

// ---------------- node MLP via split-bf16 MFMA (DIN=128) + fused per-block mean partials ----------------
__global__ __launch_bounds__(256) void node_mlp_mfma(
    const float* __restrict__ hn, const float* __restrict__ agg,
    const float* __restrict__ un,
    const short* __restrict__ w1h, const short* __restrict__ w1l,
    const short* __restrict__ w2h, const short* __restrict__ w2l,
    const float* __restrict__ b1, const float* __restrict__ b2,
    const float* __restrict__ lng, const float* __restrict__ lnb,
    float* __restrict__ outp, float* __restrict__ pn, float* __restrict__ pe)
{
  __shared__ float4 xs4[64*33];   // 64 rows x 128 f (+pad); hn|agg, h1 overwrites hn quads
  __shared__ float  bsm[5][64];
  __shared__ float  wsum[4][64], asum[4][64];

  const int t = threadIdx.x;
  const int rowbase = blockIdx.x*64;
  const int g = rowbase >> 9;

  if (t < 64){ bsm[0][t] = b1[t]; bsm[4][t] = un[(g<<6)+t]; }
  else if (t < 128) bsm[1][t-64]  = b2[t-64];
  else if (t < 192) bsm[2][t-128] = lng[t-128];
  else              bsm[3][t-192] = lnb[t-192];

  const int wv = t>>6, lane = t&63, cl = lane&15, kgrp = lane>>4;
  const int lrow  = 16*wv + cl;
  const int grow0 = rowbase + 16*wv + 4*kgrp;

  {
    const float4* hn4 = (const float4*)(hn  + (size_t)rowbase*64);
    const float4* ag4 = (const float4*)(agg + (size_t)rowbase*64);
#pragma unroll
    for (int i=0;i<4;i++){
      int idx = t + i*256;
      xs4[(idx>>4)*33 + (idx&15)] = hn4[idx];
    }
#pragma unroll
    for (int i=0;i<4;i++){
      int idx = t + i*256;
      xs4[(idx>>4)*33 + 16 + (idx&15)] = ag4[idx];
    }
  }
  __syncthreads();

  const short8b* W1h = (const short8b*)w1h;
  const short8b* W1l = (const short8b*)w1l;
  const short8b* W2h = (const short8b*)w2h;
  const short8b* W2l = (const short8b*)w2l;

  // ---- GEMM1 (K=128) ----
  f32x4 acc0 = {0,0,0,0}, acc1 = {0,0,0,0}, acc2_ = {0,0,0,0}, acc3 = {0,0,0,0};
#pragma unroll
  for (int kc=0;kc<4;kc++){
    float4 a0 = xs4[lrow*33 + kc*8 + kgrp*2];
    float4 a1 = xs4[lrow*33 + kc*8 + kgrp*2 + 1];
    short8b ahi, alo; mk_frag(a0, a1, ahi, alo);
#pragma unroll
    for (int nt=0;nt<4;nt++){
      short8b bh = W1h[(kc*4+nt)*64 + lane];
      short8b bl = W1l[(kc*4+nt)*64 + lane];
      f32x4 c = (nt==0)?acc0:(nt==1)?acc1:(nt==2)?acc2_:acc3;
      c = __builtin_amdgcn_mfma_f32_16x16x32_bf16(ahi, bh, c, 0,0,0);
      c = __builtin_amdgcn_mfma_f32_16x16x32_bf16(alo, bh, c, 0,0,0);
      c = __builtin_amdgcn_mfma_f32_16x16x32_bf16(ahi, bl, c, 0,0,0);
      if (nt==0) acc0=c; else if (nt==1) acc1=c; else if (nt==2) acc2_=c; else acc3=c;
    }
  }

  // ---- epilogue1: h1 = relu(C + b1 + un) -> LDS (quads 0..15) ----
  float* xsw = (float*)xs4;
#pragma unroll
  for (int nt=0;nt<4;nt++){
    int cn = nt*16 + cl;
    float bc = bsm[0][cn] + bsm[4][cn];
    f32x4 c = (nt==0)?acc0:(nt==1)?acc1:(nt==2)?acc2_:acc3;
#pragma unroll
    for (int reg=0;reg<4;reg++){
      float h = fmaxf(c[reg] + bc, 0.f);
      xsw[(16*wv + 4*kgrp + reg)*132 + cn] = h;
    }
  }

  // ---- GEMM2 (K=64) ----
  f32x4 d0 = {0,0,0,0}, d1 = {0,0,0,0}, d2 = {0,0,0,0}, d3 = {0,0,0,0};
#pragma unroll
  for (int kc=0;kc<2;kc++){
    float4 a0 = xs4[lrow*33 + kc*8 + kgrp*2];
    float4 a1 = xs4[lrow*33 + kc*8 + kgrp*2 + 1];
    short8b ahi, alo; mk_frag(a0, a1, ahi, alo);
#pragma unroll
    for (int nt=0;nt<4;nt++){
      short8b bh = W2h[(kc*4+nt)*64 + lane];
      short8b bl = W2l[(kc*4+nt)*64 + lane];
      f32x4 c = (nt==0)?d0:(nt==1)?d1:(nt==2)?d2:d3;
      c = __builtin_amdgcn_mfma_f32_16x16x32_bf16(ahi, bh, c, 0,0,0);
      c = __builtin_amdgcn_mfma_f32_16x16x32_bf16(alo, bh, c, 0,0,0);
      c = __builtin_amdgcn_mfma_f32_16x16x32_bf16(ahi, bl, c, 0,0,0);
      if (nt==0) d0=c; else if (nt==1) d1=c; else if (nt==2) d2=c; else d3=c;
    }
  }

  // ---- LayerNorm + store + accumulate per-block hn-out partial ----
  float ms0 = 0.f, ms1 = 0.f, ms2 = 0.f, ms3 = 0.f;
#pragma unroll
  for (int reg=0;reg<4;reg++){
    float v0 = d0[reg] + bsm[1][cl];
    float v1 = d1[reg] + bsm[1][16+cl];
    float v2 = d2[reg] + bsm[1][32+cl];
    float v3 = d3[reg] + bsm[1][48+cl];
    float sA = v0+v1+v2+v3;
    float sB = v0*v0+v1*v1+v2*v2+v3*v3;
#pragma unroll
    for (int m=1;m<16;m<<=1){ sA += __shfl_xor(sA,m); sB += __shfl_xor(sB,m); }
    float mean = sA * 0.015625f;
    float var  = sB * 0.015625f - mean*mean;
    float inv  = 1.0f / sqrtf(var + 1e-5f);
    float o0v = (v0-mean)*inv*bsm[2][cl]    + bsm[3][cl];
    float o1v = (v1-mean)*inv*bsm[2][16+cl] + bsm[3][16+cl];
    float o2v = (v2-mean)*inv*bsm[2][32+cl] + bsm[3][32+cl];
    float o3v = (v3-mean)*inv*bsm[2][48+cl] + bsm[3][48+cl];
    float* orow = outp + (size_t)(grow0 + reg)*64;
    orow[cl] = o0v; orow[16+cl] = o1v; orow[32+cl] = o2v; orow[48+cl] = o3v;
    ms0 += o0v; ms1 += o1v; ms2 += o2v; ms3 += o3v;
  }
  // reduce hn-out partials across kgrp (rows of this wave)
  ms0 += __shfl_xor(ms0,16); ms0 += __shfl_xor(ms0,32);
  ms1 += __shfl_xor(ms1,16); ms1 += __shfl_xor(ms1,32);
  ms2 += __shfl_xor(ms2,16); ms2 += __shfl_xor(ms2,32);
  ms3 += __shfl_xor(ms3,16); ms3 += __shfl_xor(ms3,32);
  if (kgrp == 0){
    wsum[wv][cl]    = ms0; wsum[wv][16+cl] = ms1;
    wsum[wv][32+cl] = ms2; wsum[wv][48+cl] = ms3;
  }
  __syncthreads();
  // agg partial from staged LDS (quads 16..31 untouched by h1)
  {
    int c = t & 63, q = t >> 6;
    float as = 0.f;
    for (int r = q*16; r < q*16+16; ++r) as += xsw[r*132 + 64 + c];
    asum[q][c] = as;
  }
  __syncthreads();
  if (t < 64){
    pn[(size_t)blockIdx.x*64 + t] = wsum[0][t]+wsum[1][t]+wsum[2][t]+wsum[3][t];
    pe[(size_t)blockIdx.x*64 + t] = asum[0][t]+asum[1][t]+asum[2][t]+asum[3][t];
  }
}

// ---------------- graph MLP (fp32, tiny) ----------------
__global__ __launch_bounds__(256) void gmlp_ln(
    const float* __restrict__ s0, const float* __restrict__ s1,
    const float* __restrict__ s2,
    const float* __restrict__ w1, const float* __restrict__ b1,
    const float* __restrict__ w2, const float* __restrict__ b2,
    const float* __restrict__ lng, const float* __restrict__ lnb,
    float* __restrict__ outp)
{
  constexpr int DIN  = 192;
  constexpr int DP4  = DIN/4 + 1;

  __shared__ float4 xs4[32*DP4];
  __shared__ float4 ws4[1024];
  __shared__ float  bsm[4][64];

  const int t = threadIdx.x;
  const int rowbase = blockIdx.x*32;

  if (t < 64)       bsm[0][t]     = b1[t];
  else if (t < 128) bsm[1][t-64]  = b2[t-64];
  else if (t < 192) bsm[2][t-128] = lng[t-128];
  else              bsm[3][t-192] = lnb[t-192];

  {
    const int gi16 = t >> 4, lg = t & 15;
#pragma unroll
    for (int it = 0; it < 6; ++it){
      int pair = gi16 + (it << 4);
      int er = pair & 31, seg = pair >> 5;
      int row = rowbase + er;
      const float* bp = ((seg==0)? s0 : (seg==1)? s1 : s2) + (size_t)64*row;
      xs4[er*DP4 + seg*16 + lg] = ((const float4*)bp)[lg];
    }
  }
  __syncthreads();

  const int r0 = (t >> 4) * 2, cq = t & 15;
  float acc[2][4] = {{0.f,0.f,0.f,0.f},{0.f,0.f,0.f,0.f}};
  const float4* w1g4 = (const float4*)w1;

  for (int kc = 0; kc < DIN; kc += 64){
    __syncthreads();
    ws4[t]     = w1g4[kc*16 + t];
    ws4[t+256] = w1g4[kc*16 + t + 256];
    ws4[t+512] = w1g4[kc*16 + t + 512];
    ws4[t+768] = w1g4[kc*16 + t + 768];
    __syncthreads();
#pragma unroll
    for (int k4=0;k4<16;k4++){
      float4 a0 = xs4[(r0  )*DP4 + (kc>>2) + k4];
      float4 a1 = xs4[(r0+1)*DP4 + (kc>>2) + k4];
      float4 bb[4];
#pragma unroll
      for (int kk=0;kk<4;kk++) bb[kk] = ws4[(k4*4+kk)*16 + cq];
      const float* a0p = (const float*)&a0;
      const float* a1p = (const float*)&a1;
#pragma unroll
      for (int kk=0;kk<4;kk++){
        acc[0][0]=fmaf(a0p[kk],bb[kk].x,acc[0][0]);
        acc[0][1]=fmaf(a0p[kk],bb[kk].y,acc[0][1]);
        acc[0][2]=fmaf(a0p[kk],bb[kk].z,acc[0][2]);
        acc[0][3]=fmaf(a0p[kk],bb[kk].w,acc[0][3]);
        acc[1][0]=fmaf(a1p[kk],bb[kk].x,acc[1][0]);
        acc[1][1]=fmaf(a1p[kk],bb[kk].y,acc[1][1]);
        acc[1][2]=fmaf(a1p[kk],bb[kk].z,acc[1][2]);
        acc[1][3]=fmaf(a1p[kk],bb[kk].w,acc[1][3]);
      }
    }
  }

  __syncthreads();
  {
    float4 h0, h1v;
    h0.x  = fmaxf(acc[0][0]+bsm[0][cq*4+0], 0.f);
    h0.y  = fmaxf(acc[0][1]+bsm[0][cq*4+1], 0.f);
    h0.z  = fmaxf(acc[0][2]+bsm[0][cq*4+2], 0.f);
    h0.w  = fmaxf(acc[0][3]+bsm[0][cq*4+3], 0.f);
    h1v.x = fmaxf(acc[1][0]+bsm[0][cq*4+0], 0.f);
    h1v.y = fmaxf(acc[1][1]+bsm[0][cq*4+1], 0.f);
    h1v.z = fmaxf(acc[1][2]+bsm[0][cq*4+2], 0.f);
    h1v.w = fmaxf(acc[1][3]+bsm[0][cq*4+3], 0.f);
    xs4[(r0  )*DP4 + cq] = h0;
    xs4[(r0+1)*DP4 + cq] = h1v;
    const float4* w2g4 = (const float4*)w2;
    ws4[t]     = w2g4[t];
    ws4[t+256] = w2g4[t+256];
    ws4[t+512] = w2g4[t+512];
    ws4[t+768] = w2g4[t+768];
  }
  __syncthreads();

  float acc2[2][4] = {{0.f,0.f,0.f,0.f},{0.f,0.f,0.f,0.f}};
#pragma unroll
  for (int k4=0;k4<16;k4++){
    float4 a0 = xs4[(r0  )*DP4 + k4];
    float4 a1 = xs4[(r0+1)*DP4 + k4];
    float4 bb[4];
#pragma unroll
    for (int kk=0;kk<4;kk++) bb[kk] = ws4[(k4*4+kk)*16 + cq];
    const float* a0p = (const float*)&a0;
    const float* a1p = (const float*)&a1;
#pragma unroll
    for (int kk=0;kk<4;kk++){
      acc2[0][0]=fmaf(a0p[kk],bb[kk].x,acc2[0][0]);
      acc2[0][1]=fmaf(a0p[kk],bb[kk].y,acc2[0][1]);
      acc2[0][2]=fmaf(a0p[kk],bb[kk].z,acc2[0][2]);
      acc2[0][3]=fmaf(a0p[kk],bb[kk].w,acc2[0][3]);
      acc2[1][0]=fmaf(a1p[kk],bb[kk].x,acc2[1][0]);
      acc2[1][1]=fmaf(a1p[kk],bb[kk].y,acc2[1][1]);
      acc2[1][2]=fmaf(a1p[kk],bb[kk].z,acc2[1][2]);
      acc2[1][3]=fmaf(a1p[kk],bb[kk].w,acc2[1][3]);
    }
  }

#pragma unroll
  for (int rr=0; rr<2; rr++){
    float v0 = acc2[rr][0] + bsm[1][cq*4+0];
    float v1 = acc2[rr][1] + bsm[1][cq*4+1];
    float v2 = acc2[rr][2] + bsm[1][cq*4+2];
    float v3 = acc2[rr][3] + bsm[1][cq*4+3];
    float sA = v0+v1+v2+v3;
    float sB = v0*v0+v1*v1+v2*v2+v3*v3;
#pragma unroll
    for (int m=1;m<16;m<<=1){ sA += __shfl_xor(sA,m); sB += __shfl_xor(sB,m); }
    float mean = sA * 0.015625f;
    float var  = sB * 0.015625f - mean*mean;
    float inv  = 1.0f / sqrtf(var + 1e-5f);
    float4 o;
    o.x = (v0-mean)*inv*bsm[2][cq*4+0] + bsm[3][cq*4+0];
    o.y = (v1-mean)*inv*bsm[2][cq*4+1] + bsm[3][cq*4+1];
    o.z = (v2-mean)*inv*bsm[2][cq*4+2] + bsm[3][cq*4+2];
    o.w = (v3-mean)*inv*bsm[2][cq*4+3] + bsm[3][cq*4+3];
    ((float4*)(outp + (size_t)(rowbase + r0 + rr)*64))[cq] = o;
  }
}

// ---------------- heads ----------------
__global__ __launch_bounds__(512) void heads_kernel(
    const float* __restrict__ hn, const float* __restrict__ uvec,
    const float* __restrict__ aw, const float* __restrict__ ab,
    const float* __restrict__ cw, const float* __restrict__ cb,
    float* __restrict__ out)
{
  const int g = blockIdx.x, t = threadIdx.x;
  const int n = (g<<9) + t;
  const float4* hp = (const float4*)(hn + (size_t)n*64);
  const float4* ap = (const float4*)aw;
  float d = 0.f;
#pragma unroll
  for (int i=0;i<16;i++){
    float4 h = hp[i], a = ap[i];
    d += h.x*a.x + h.y*a.y + h.z*a.z + h.w*a.w;
  }
  d += ab[0];
  float z = 1.0f/(1.0f + expf(-d));

  unsigned o0,o1;
  threefry(0u, 42u, 0u, (unsigned)n, o0, o1);
  unsigned bits = o0 ^ o1;
  float f = __uint_as_float((bits>>9) | 0x3f800000u) - 1.0f;
  float gum = -logf(-logf(fmaxf(1.17549435e-38f, f)));

  const int lane = t & 63, wid = t >> 6;
  __shared__ float smax[8], ssum[8], sent[8], skey[8];
  __shared__ int   sidx[8];
  __shared__ float sM, sS;
  __shared__ int   sA;

  float m = z;
#pragma unroll
  for (int sh=1; sh<64; sh<<=1) m = fmaxf(m, __shfl_xor(m, sh));
  if (lane==0) smax[wid] = m;
  __syncthreads();
  if (t==0){ float mm=smax[0]; for(int i=1;i<8;i++) mm=fmaxf(mm,smax[i]); sM=mm; }
  __syncthreads();
  float M = sM;
  float ex = expf(z - M);
  float ssl = ex;
#pragma unroll
  for (int sh=1; sh<64; sh<<=1) ssl += __shfl_xor(ssl, sh);
  if (lane==0) ssum[wid] = ssl;
  __syncthreads();
  if (t==0){ float ss=0.f; for(int i=0;i<8;i++) ss+=ssum[i]; sS=ss; }
  __syncthreads();
  float logp = z - M - logf(sS);
  float p = expf(logp);
  float entl = p * logp;
#pragma unroll
  for (int sh=1; sh<64; sh<<=1) entl += __shfl_xor(entl, sh);
  if (lane==0) sent[wid] = entl;

  float kv = z + gum; int ki = t;
#pragma unroll
  for (int sh=1; sh<64; sh<<=1){
    float ov = __shfl_xor(kv, sh);
    int   oi = __shfl_xor(ki, sh);
    if (ov > kv || (ov == kv && oi < ki)){ kv = ov; ki = oi; }
  }
  if (lane==0){ skey[wid] = kv; sidx[wid] = ki; }
  __syncthreads();
  if (t==0){
    float bv = skey[0]; int bi = sidx[0];
    for (int i=1;i<8;i++) if (skey[i] > bv || (skey[i]==bv && sidx[i] < bi)){ bv=skey[i]; bi=sidx[i]; }
    sA = bi;
    float ent = 0.f; for (int i=0;i<8;i++) ent += sent[i];
    out[g]      = (float)bi;
    out[128+g]  = -ent;
  }
  __syncthreads();
  if (t == sA) out[64+g] = logp;

  if (t < 64){
    float pv = uvec[(g<<6)+t] * cw[t];
#pragma unroll
    for (int sh=1; sh<64; sh<<=1) pv += __shfl_xor(pv, sh);
    if (t==0) out[192+g] = pv + cb[0];
  }
}

// ---------------- launch ----------------
extern "C" void kernel_launch(void* const* d_in, const int* in_sizes, int n_in,
                              void* d_out, int out_size, void* d_ws, size_t ws_size,
                              hipStream_t stream)
{
  (void)in_sizes; (void)n_in; (void)out_size; (void)ws_size;
  const float* x      = (const float*)d_in[0];
  const float* eattr  = (const float*)d_in[1];
  const int*   eidx   = (const int*)d_in[2];
  const float* node_w = (const float*)d_in[5];
  const float* node_b = (const float*)d_in[6];
  const float* edge_w = (const float*)d_in[7];
  const float* edge_b = (const float*)d_in[8];
  const float* init_u = (const float*)d_in[9];
  const float* ew1 = (const float*)d_in[10]; const float* eb1 = (const float*)d_in[11];
  const float* ew2 = (const float*)d_in[12]; const float* eb2 = (const float*)d_in[13];
  const float* elg = (const float*)d_in[14]; const float* elb = (const float*)d_in[15];
  const float* nw1 = (const float*)d_in[16]; const float* nb1 = (const float*)d_in[17];
  const float* nw2 = (const float*)d_in[18]; const float* nb2 = (const float*)d_in[19];
  const float* nlg = (const float*)d_in[20]; const float* nlb = (const float*)d_in[21];
  const float* gw1 = (const float*)d_in[22]; const float* gb1 = (const float*)d_in[23];
  const float* gw2 = (const float*)d_in[24]; const float* gb2 = (const float*)d_in[25];
  const float* glg = (const float*)d_in[26]; const float* glb = (const float*)d_in[27];
  const float* aw  = (const float*)d_in[28]; const float* ab  = (const float*)d_in[29];
  const float* cw  = (const float*)d_in[30]; const float* cb  = (const float*)d_in[31];
  const int* src = eidx;
  const int* dst = eidx + EE;

  float* ws    = (float*)d_ws;
  float* hn    = ws;                         // N*64
  float* he    = hn + (size_t)NN*64;         // E*64  (dst-sorted order)
  float* agg   = he + (size_t)EE*64;         // N*64
  float* u     = agg + (size_t)NN*64;        // G*64
  float* nmean = u + GG*64;
  float* emean = nmean + GG*64;
  int* cnt     = (int*)(emean + GG*64);      // N
  int* indptr  = cnt + NN;                   // N+1
  int* fillc   = indptr + NN + 1;            // N
  int* eord    = fillc + NN;                 // E
  int* srcs    = eord + EE;                  // E
  int* dsts    = srcs + EE;                  // E
  float* pb    = (float*)(dsts + EE);        // N*64
  float* pa    = pb + (size_t)NN*64;         // N*64 (own buffer: agg written during edge phase)
  float* ue    = pa + (size_t)NN*64;         // G*64
  float* un    = ue + GG*64;                 // G*64
  float* pn    = un + GG*64;                 // 512*64
  float* pe    = pn + 512*64;                // 512*64
  float* headp = pe + 512*64;                // 4096*64
  float* tailp = headp + 4096*64;            // 4096*64
  short* wfh   = (short*)(tailp + 4096*64);  // 63488 shorts
  short* wfl   = wfh + 63488;                // 63488 shorts

  float* out = (float*)d_out;

  hipMemsetAsync(cnt,   0, NN*sizeof(int), stream);
  hipMemsetAsync(fillc, 0, NN*sizeof(int), stream);

  count_kernel<<<EE/256, 256, 0, stream>>>(dst, cnt);
  scan_kernel<<<1, 1024, 0, stream>>>(cnt, indptr);
  fill_kernel<<<EE/256, 256, 0, stream>>>(dst, indptr, fillc, eord);
  sort_kernel<<<NN/256, 256, 0, stream>>>(indptr, eord);
  perm_kernel<<<EE/256, 256, 0, stream>>>(src, dst, eord, srcs, dsts);

  encode_kernel<32><<<NN/4, 256, 0, stream>>>(x, node_w, node_b, hn, NN);
  initu_kernel<<<16, 256, 0, stream>>>(init_u, u);
  wprep_kernel<<<31, 256, 0, stream>>>(edge_w, ew1, ew2, nw1, nw2, wfh, wfl);

  // frag offsets (shorts): enc=0; per layer l: e1=2048+l*20480, e2=+4096, n1=+8192, n2=+16384
  for (int l=0; l<NL; ++l){
    const float* ew1l = ew1 + (size_t)l*256*64;
    const float* nw1l = nw1 + (size_t)l*192*64;
    size_t e1o = 2048 + (size_t)l*20480;
    size_t e2o = e1o + 4096, n1o = e1o + 8192, n2o = e1o + 16384;

    pre_kernel<<<NN/32, 256, 0, stream>>>(hn, ew1l, ew1l + 64*64, pa, pb, NN);
    pre_kernel<<<2, 256, 0, stream>>>(u, ew1l + 192*64, nw1l + 128*64, ue, un, GG);

    if (l == 0)
      edge_mlp_mfma<1,1><<<EE/64, 256, 0, stream>>>(he, eattr, eord, pa, pb, ue, srcs, dsts, indptr,
          wfh, wfl, wfh + e1o, wfl + e1o, wfh + e2o, wfl + e2o,
          edge_b, eb1 + l*64, eb2 + l*64, elg + l*64, elb + l*64, he, agg, headp, tailp);
    else if (l == 1)
      edge_mlp_mfma<0,1><<<EE/64, 256, 0, stream>>>(he, eattr, eord, pa, pb, ue, srcs, dsts, indptr,
          wfh, wfl, wfh + e1o, wfl + e1o, wfh + e2o, wfl + e2o,
          edge_b, eb1 + l*64, eb2 + l*64, elg + l*64, elb + l*64, he, agg, headp, tailp);
    else
      edge_mlp_mfma<0,0><<<EE/64, 256, 0, stream>>>(he, eattr, eord, pa, pb, ue, srcs, dsts, indptr,
          wfh, wfl, wfh + e1o, wfl + e1o, wfh + e2o, wfl + e2o,
          edge_b, eb1 + l*64, eb2 + l*64, elg + l*64, elb + l*64, he, agg, headp, tailp);

    aggfix_kernel<<<NN*16/256, 256, 0, stream>>>(indptr, headp, tailp, agg);
    node_mlp_mfma<<<NN/64, 256, 0, stream>>>(hn, agg, un,
        wfh + n1o, wfl + n1o, wfh + n2o, wfl + n2o,
        nb1 + l*64, nb2 + l*64, nlg + l*64, nlb + l*64, hn, pn, pe);
    fmeans_kernel<<<GG, 64, 0, stream>>>(pn, pe, nmean, emean);
    gmlp_ln<<<GG/32, 256, 0, stream>>>(u, nmean, emean,
        gw1 + (size_t)l*192*64, gb1 + l*64, gw2 + (size_t)l*64*64, gb2 + l*64,
        glg + l*64, glb + l*64, u);
  }

  heads_kernel<<<GG, 512, 0, stream>>>(hn, u, aw, ab, cw, cb, out);
}

// Round 9
// 348.643 us; speedup vs baseline: 4.7562x; 1.0928x over previous
//
#include <hip/hip_runtime.h>
#include <hip/hip_bf16.h>
#include <math.h>

#define GG 64
#define NPGc 512
#define NN (GG*NPGc)      // 32768 nodes
#define EE (NN*8)         // 262144 edges
#define HH 64
#define NL 3

typedef __attribute__((ext_vector_type(8))) short short8b;
typedef __attribute__((ext_vector_type(4))) float f32x4;

// ---------------- bf16 split helpers (native cvt -> compiler packs v_cvt_pk_bf16_f32) ----------------
__device__ __forceinline__ unsigned short f2bf_rne(float f){
  unsigned u = __float_as_uint(f);
  unsigned r = u + 0x7fffu + ((u>>16)&1u);
  return (unsigned short)(r>>16);
}
__device__ __forceinline__ float bf2f(unsigned short h){
  return __uint_as_float(((unsigned)h)<<16);
}
__device__ __forceinline__ void mk_frag(const float4 &u, const float4 &v, short8b &hi, short8b &lo){
  float av[8] = {u.x,u.y,u.z,u.w,v.x,v.y,v.z,v.w};
#pragma unroll
  for (int j=0;j<8;j++){
    __hip_bfloat16 h = __float2bfloat16(av[j]);
    hi[j] = (short)__builtin_bit_cast(unsigned short, h);
    float rem = av[j] - __bfloat162float(h);
    __hip_bfloat16 l = __float2bfloat16(rem);
    lo[j] = (short)__builtin_bit_cast(unsigned short, l);
  }
}

// ---------------- threefry2x32 (JAX-compatible, partitionable mode) ----------------
__device__ __forceinline__ unsigned rotl32(unsigned x, int r){ return (x<<r)|(x>>(32-r)); }
__device__ __forceinline__ void threefry(unsigned k0, unsigned k1, unsigned x0, unsigned x1,
                                         unsigned &o0, unsigned &o1){
  unsigned ks2 = k0 ^ k1 ^ 0x1BD11BDAu;
  unsigned v0 = x0 + k0, v1 = x1 + k1;
#define R4(a,b,c,d) v0+=v1; v1=rotl32(v1,a); v1^=v0; v0+=v1; v1=rotl32(v1,b); v1^=v0; \
                    v0+=v1; v1=rotl32(v1,c); v1^=v0; v0+=v1; v1=rotl32(v1,d); v1^=v0;
  R4(13,15,26,6)  v0+=k1;  v1+=ks2+1u;
  R4(17,29,16,24) v0+=ks2; v1+=k0+2u;
  R4(13,15,26,6)  v0+=k0;  v1+=k1+3u;
  R4(17,29,16,24) v0+=k1;  v1+=ks2+4u;
  R4(13,15,26,6)  v0+=ks2; v1+=k0+5u;
#undef R4
  o0=v0; o1=v1;
}

// ---------------- node encoder ----------------
template<int K>
__global__ __launch_bounds__(256) void encode_kernel(const float* __restrict__ in,
    const float* __restrict__ w, const float* __restrict__ b,
    float* __restrict__ out, int rows)
{
  int wid = blockIdx.x*4 + (threadIdx.x>>6);
  int lane = threadIdx.x & 63;
  if (wid >= rows) return;
  const float* xr = in + (size_t)wid*K;
  float acc = b[lane];
#pragma unroll
  for (int i=0;i<K;i++) acc = fmaf(xr[i], w[i*64+lane], acc);
  out[(size_t)wid*64+lane] = fmaxf(acc, 0.f);
}

__global__ __launch_bounds__(256) void initu_kernel(const float* __restrict__ iu, float* __restrict__ u){
  int i = blockIdx.x*256 + threadIdx.x;
  if (i < GG*64) u[i] = iu[i & 63];
}

// ---------------- CSR build ----------------
__global__ __launch_bounds__(256) void count_kernel(const int* __restrict__ dst, int* __restrict__ cnt){
  int e = blockIdx.x*256 + threadIdx.x;
  if (e < EE) atomicAdd(&cnt[dst[e]], 1);
}
__global__ __launch_bounds__(1024) void scan_kernel(const int* __restrict__ cnt, int* __restrict__ indptr){
  __shared__ int part[1024];
  const int t = threadIdx.x;
  const int base = t*32;
  int s = 0;
  for (int i=0;i<32;i++) s += cnt[base+i];
  part[t] = s;
  __syncthreads();
  for (int off=1; off<1024; off<<=1){
    int v = part[t];
    int add = (t >= off) ? part[t-off] : 0;
    __syncthreads();
    part[t] = v + add;
    __syncthreads();
  }
  int run = (t==0) ? 0 : part[t-1];
  for (int i=0;i<32;i++){ indptr[base+i] = run; run += cnt[base+i]; }
  if (t==1023) indptr[NN] = run;
}
__global__ __launch_bounds__(256) void fill_kernel(const int* __restrict__ dst, const int* __restrict__ indptr,
                                                   int* __restrict__ fillc, int* __restrict__ eord){
  int e = blockIdx.x*256 + threadIdx.x;
  if (e < EE){ int dn = dst[e]; int p = atomicAdd(&fillc[dn], 1); eord[indptr[dn]+p] = e; }
}
__global__ __launch_bounds__(256) void sort_kernel(const int* __restrict__ indptr, int* __restrict__ eord){
  int n = blockIdx.x*256 + threadIdx.x;
  if (n >= NN) return;
  int lo = indptr[n], hi = indptr[n+1];
  for (int i=lo+1;i<hi;i++){
    int v = eord[i]; int j = i-1;
    while (j >= lo && eord[j] > v){ eord[j+1]=eord[j]; j--; }
    eord[j+1] = v;
  }
}
__global__ __launch_bounds__(256) void perm_kernel(const int* __restrict__ src, const int* __restrict__ dst,
                                                   const int* __restrict__ eord,
                                                   int* __restrict__ srcs, int* __restrict__ dsts){
  int p = blockIdx.x*256 + threadIdx.x;
  if (p < EE){ int e = eord[p]; srcs[p] = src[e]; dsts[p] = dst[e]; }
}

// ---------------- agg fixup: spanning nodes + boundary zero-degree nodes ----------------
__global__ __launch_bounds__(256) void aggfix_kernel(const int* __restrict__ indptr,
    const float* __restrict__ headp, const float* __restrict__ tailp, float* __restrict__ agg){
  int idx = blockIdx.x*256 + threadIdx.x;
  int n = idx >> 4, cq = idx & 15;
  if (n >= NN) return;
  int lo = indptr[n], hi = indptr[n+1];
  if (lo == hi){
    if ((lo & 63) == 0){
      float4 z = {0,0,0,0};
      ((float4*)(agg + (size_t)n*64))[cq] = z;
    }
    return;
  }
  int b0 = lo >> 6, b1 = (hi-1) >> 6;
  if (b0 == b1) return;
  float4 a = ((const float4*)(tailp + (size_t)b0*64))[cq];
  for (int b = b0+1; b <= b1; ++b){
    float4 h = ((const float4*)(headp + (size_t)b*64))[cq];
    a.x+=h.x; a.y+=h.y; a.z+=h.z; a.w+=h.w;
  }
  ((float4*)(agg + (size_t)n*64))[cq] = a;
}

// ---------------- pre_kernel: oa = x@wa, ob = x@wb (layer 0 only) ----------------
__global__ __launch_bounds__(256) void pre_kernel(const float* __restrict__ x,
    const float* __restrict__ wa, const float* __restrict__ wb,
    float* __restrict__ oa, float* __restrict__ ob, int rows)
{
  __shared__ float4 xs4[32*17];
  __shared__ float4 wsa[1024], wsb[1024];
  const int t = threadIdx.x;
  const int rowbase = blockIdx.x*32;
  {
    const int gi16 = t>>4, lg = t&15;
#pragma unroll
    for (int it=0; it<2; ++it){
      int er = gi16 + (it<<4);
      xs4[er*17+lg] = ((const float4*)(x + (size_t)64*(rowbase+er)))[lg];
    }
  }
  const float4* wa4 = (const float4*)wa;
  const float4* wb4 = (const float4*)wb;
#pragma unroll
  for (int i=0;i<4;i++){ wsa[t+i*256] = wa4[t+i*256]; wsb[t+i*256] = wb4[t+i*256]; }
  __syncthreads();

  const int r0 = (t>>4)*2, cq = t&15;
  float accA[2][4] = {{0,0,0,0},{0,0,0,0}};
  float accB[2][4] = {{0,0,0,0},{0,0,0,0}};
#pragma unroll
  for (int k4=0;k4<16;k4++){
    float4 a0 = xs4[(r0  )*17 + k4];
    float4 a1 = xs4[(r0+1)*17 + k4];
    const float* a0p = (const float*)&a0;
    const float* a1p = (const float*)&a1;
#pragma unroll
    for (int kk=0;kk<4;kk++){
      float4 ba = wsa[(k4*4+kk)*16 + cq];
      float4 bb = wsb[(k4*4+kk)*16 + cq];
      accA[0][0]=fmaf(a0p[kk],ba.x,accA[0][0]); accA[0][1]=fmaf(a0p[kk],ba.y,accA[0][1]);
      accA[0][2]=fmaf(a0p[kk],ba.z,accA[0][2]); accA[0][3]=fmaf(a0p[kk],ba.w,accA[0][3]);
      accA[1][0]=fmaf(a1p[kk],ba.x,accA[1][0]); accA[1][1]=fmaf(a1p[kk],ba.y,accA[1][1]);
      accA[1][2]=fmaf(a1p[kk],ba.z,accA[1][2]); accA[1][3]=fmaf(a1p[kk],ba.w,accA[1][3]);
      accB[0][0]=fmaf(a0p[kk],bb.x,accB[0][0]); accB[0][1]=fmaf(a0p[kk],bb.y,accB[0][1]);
      accB[0][2]=fmaf(a0p[kk],bb.z,accB[0][2]); accB[0][3]=fmaf(a0p[kk],bb.w,accB[0][3]);
      accB[1][0]=fmaf(a1p[kk],bb.x,accB[1][0]); accB[1][1]=fmaf(a1p[kk],bb.y,accB[1][1]);
      accB[1][2]=fmaf(a1p[kk],bb.w,accB[1][3]); accB[1][3]=fmaf(a1p[kk],bb.w,accB[1][3]);
      accB[1][2]=fmaf(a1p[kk],bb.z,accB[1][2]);
    }
  }
#pragma unroll
  for (int rr=0; rr<2; rr++){
    size_t row = rowbase + r0 + rr;
    float4 va = {accA[rr][0],accA[rr][1],accA[rr][2],accA[rr][3]};
    float4 vb = {accB[rr][0],accB[rr][1],accB[rr][2],accB[rr][3]};
    ((float4*)(oa + row*64))[cq] = va;
    ((float4*)(ob + row*64))[cq] = vb;
  }
}

// ---------------- weight prep: per-lane MFMA B-fragments (bf16 hi/lo) ----------------
// b<31: 13 matrices {enc(K16), per-l: e1,e2,n1(K128),n2}; b>=31: 6 matrices {per-l: ew1[0:64], ew1[64:128]}
__global__ __launch_bounds__(256) void wprep_kernel(const float* __restrict__ edge_w,
    const float* __restrict__ ew1, const float* __restrict__ ew2,
    const float* __restrict__ nw1, const float* __restrict__ nw2,
    short* __restrict__ wfhi, short* __restrict__ wflo)
{
  int b = blockIdx.x;
  const float* W; int K; int kc; size_t doff;
  if (b < 31){
    int m = 0; kc = 0; doff = 0; int rem = b;
    for (m = 0; m < 13; m++){
      int kcs = (m==0) ? 1 : ((((m-1)&3)==2) ? 4 : 2);
      if (rem < kcs){ kc = rem; break; }
      rem -= kcs; doff += (size_t)kcs*2048;
    }
    if (m == 0){ W = edge_w; K = 16; }
    else {
      int l = (m-1)>>2, r = (m-1)&3;
      if      (r==0){ W = ew1 + (size_t)l*16384 + 8192; K = 64;  }
      else if (r==1){ W = ew2 + (size_t)l*4096;         K = 64;  }
      else if (r==2){ W = nw1 + (size_t)l*12288;        K = 128; }
      else          { W = nw2 + (size_t)l*4096;         K = 64;  }
    }
  } else {
    int idx = b - 31;
    int mi = idx >> 1; kc = idx & 1;
    int l = mi >> 1, which = mi & 1;
    W = ew1 + (size_t)l*16384 + (size_t)which*4096; K = 64;
    doff = 63488 + (size_t)mi*4096;
  }
  const int nt = threadIdx.x>>6, lane = threadIdx.x&63;
#pragma unroll
  for (int j=0;j<8;j++){
    int k = kc*32 + (lane>>4)*8 + j;
    int n = nt*16 + (lane&15);
    float v = (k < K) ? W[k*64+n] : 0.f;
    size_t o = doff + (size_t)kc*2048 + (size_t)((nt*64+lane)*8+j);
    unsigned short hi = f2bf_rne(v);
    wfhi[o] = (short)hi;
    wflo[o] = (short)f2bf_rne(v - bf2f(hi));
  }
}

// ---------------- edge MLP via split-bf16 MFMA + fused deterministic aggregation ----------------
template<int FUSE, int WRITE_HE>
__global__ __launch_bounds__(256) void edge_mlp_mfma(
    const float* __restrict__ he, const float* __restrict__ eattr,
    const int* __restrict__ eord,
    const float* __restrict__ pa, const float* __restrict__ pb,
    const float* __restrict__ ue,
    const int* __restrict__ srcs, const int* __restrict__ dsts,
    const int* __restrict__ indptr,
    const short* __restrict__ weh, const short* __restrict__ wel,
    const short* __restrict__ w1h, const short* __restrict__ w1l,
    const short* __restrict__ w2h, const short* __restrict__ w2l,
    const float* __restrict__ eb, const float* __restrict__ b1,
    const float* __restrict__ b2,
    const float* __restrict__ lng, const float* __restrict__ lnb,
    float* __restrict__ outp,
    float* __restrict__ aggp, float* __restrict__ headp, float* __restrict__ tailp)
{
  __shared__ float4 xs4[64*17];            // he rows -> h1 rows -> LN-out rows (68 f stride)
  __shared__ float4 eas[FUSE ? 64*4 : 1];  // gathered eattr rows [64][16]f
  __shared__ float  bsm[6][64];            // b1, b2, ln_g, ln_b, ue, eb
  __shared__ int    ds_dst[64];

  const int t = threadIdx.x;
  const int rowbase = blockIdx.x*64;
  const int g = rowbase >> 12;

  if (t < 64){
    bsm[0][t] = b1[t]; bsm[4][t] = ue[(g<<6)+t];
    if constexpr (FUSE) bsm[5][t] = eb[t];
    ds_dst[t] = dsts[rowbase + t];
  }
  else if (t < 128) bsm[1][t-64]  = b2[t-64];
  else if (t < 192) bsm[2][t-128] = lng[t-128];
  else              bsm[3][t-192] = lnb[t-192];

  const int wv = t>>6, lane = t&63, cl = lane&15, kgrp = lane>>4;
  const int lrow  = 16*wv + cl;
  const int grow0 = rowbase + 16*wv + 4*kgrp;

  int4 sv = ((const int4*)srcs)[grow0>>2];
  int4 dv = ((const int4*)dsts)[grow0>>2];
  float exa[4][4], exb[4][4];
#pragma unroll
  for (int reg=0;reg<4;reg++){
    int s_ = ((const int*)&sv)[reg], d_ = ((const int*)&dv)[reg];
#pragma unroll
    for (int nt=0;nt<4;nt++){
      exa[reg][nt] = pa[(size_t)s_*64 + nt*16 + cl];
      exb[reg][nt] = pb[(size_t)d_*64 + nt*16 + cl];
    }
  }

  float* xsw = (float*)xs4;

  if constexpr (FUSE){
    {
      const int er = t>>2, q = t&3;
      int e = eord[rowbase + er];
      eas[er*4+q] = ((const float4*)(eattr + (size_t)e*16))[q];
    }
    __syncthreads();
    f32x4 c0={0,0,0,0}, c1={0,0,0,0}, c2={0,0,0,0}, c3={0,0,0,0};
    short8b ahi, alo;
    if (kgrp < 2){
      float4 a0 = eas[lrow*4 + kgrp*2];
      float4 a1 = eas[lrow*4 + kgrp*2 + 1];
      mk_frag(a0, a1, ahi, alo);
    } else {
      ahi = (short8b){0,0,0,0,0,0,0,0};
      alo = (short8b){0,0,0,0,0,0,0,0};
    }
    const short8b* Wh = (const short8b*)weh;
    const short8b* Wl = (const short8b*)wel;
#pragma unroll
    for (int nt=0;nt<4;nt++){
      short8b bh = Wh[nt*64 + lane];
      short8b bl = Wl[nt*64 + lane];
      f32x4 c = (nt==0)?c0:(nt==1)?c1:(nt==2)?c2:c3;
      c = __builtin_amdgcn_mfma_f32_16x16x32_bf16(ahi, bh, c, 0,0,0);
      c = __builtin_amdgcn_mfma_f32_16x16x32_bf16(alo, bh, c, 0,0,0);
      c = __builtin_amdgcn_mfma_f32_16x16x32_bf16(ahi, bl, c, 0,0,0);
      if (nt==0) c0=c; else if (nt==1) c1=c; else if (nt==2) c2=c; else c3=c;
    }
#pragma unroll
    for (int nt=0;nt<4;nt++){
      int cn = nt*16 + cl;
      f32x4 c = (nt==0)?c0:(nt==1)?c1:(nt==2)?c2:c3;
#pragma unroll
      for (int reg=0;reg<4;reg++){
        float h = fmaxf(c[reg] + bsm[5][cn], 0.f);
        xsw[(16*wv + 4*kgrp + reg)*68 + cn] = h;
      }
    }
  } else {
    const float4* heb = (const float4*)(he + (size_t)rowbase*64);
#pragma unroll
    for (int i=0;i<4;i++){
      int idx = t + i*256;
      xs4[(idx>>4)*17 + (idx&15)] = heb[idx];
    }
    __syncthreads();
  }

  const short8b* W1h = (const short8b*)w1h;
  const short8b* W1l = (const short8b*)w1l;
  const short8b* W2h = (const short8b*)w2h;
  const short8b* W2l = (const short8b*)w2l;

  // ---- GEMM1 ----
  f32x4 acc0 = {0,0,0,0}, acc1 = {0,0,0,0}, acc2_ = {0,0,0,0}, acc3 = {0,0,0,0};
#pragma unroll
  for (int kc=0;kc<2;kc++){
    float4 a0 = xs4[lrow*17 + kc*8 + kgrp*2];
    float4 a1 = xs4[lrow*17 + kc*8 + kgrp*2 + 1];
    short8b ahi, alo; mk_frag(a0, a1, ahi, alo);
#pragma unroll
    for (int nt=0;nt<4;nt++){
      short8b bh = W1h[(kc*4+nt)*64 + lane];
      short8b bl = W1l[(kc*4+nt)*64 + lane];
      f32x4 c = (nt==0)?acc0:(nt==1)?acc1:(nt==2)?acc2_:acc3;
      c = __builtin_amdgcn_mfma_f32_16x16x32_bf16(ahi, bh, c, 0,0,0);
      c = __builtin_amdgcn_mfma_f32_16x16x32_bf16(alo, bh, c, 0,0,0);
      c = __builtin_amdgcn_mfma_f32_16x16x32_bf16(ahi, bl, c, 0,0,0);
      if (nt==0) acc0=c; else if (nt==1) acc1=c; else if (nt==2) acc2_=c; else acc3=c;
    }
  }

  // ---- epilogue1: h1 ----
#pragma unroll
  for (int nt=0;nt<4;nt++){
    int cn = nt*16 + cl;
    float bc = bsm[0][cn] + bsm[4][cn];
    f32x4 c = (nt==0)?acc0:(nt==1)?acc1:(nt==2)?acc2_:acc3;
#pragma unroll
    for (int reg=0;reg<4;reg++){
      float h = fmaxf(c[reg] + bc + exa[reg][nt] + exb[reg][nt], 0.f);
      xsw[(16*wv + 4*kgrp + reg)*68 + cn] = h;
    }
  }

  // ---- GEMM2 ----
  f32x4 d0 = {0,0,0,0}, d1 = {0,0,0,0}, d2 = {0,0,0,0}, d3 = {0,0,0,0};
#pragma unroll
  for (int kc=0;kc<2;kc++){
    float4 a0 = xs4[lrow*17 + kc*8 + kgrp*2];
    float4 a1 = xs4[lrow*17 + kc*8 + kgrp*2 + 1];
    short8b ahi, alo; mk_frag(a0, a1, ahi, alo);
#pragma unroll
    for (int nt=0;nt<4;nt++){
      short8b bh = W2h[(kc*4+nt)*64 + lane];
      short8b bl = W2l[(kc*4+nt)*64 + lane];
      f32x4 c = (nt==0)?d0:(nt==1)?d1:(nt==2)?d2:d3;
      c = __builtin_amdgcn_mfma_f32_16x16x32_bf16(ahi, bh, c, 0,0,0);
      c = __builtin_amdgcn_mfma_f32_16x16x32_bf16(alo, bh, c, 0,0,0);
      c = __builtin_amdgcn_mfma_f32_16x16x32_bf16(ahi, bl, c, 0,0,0);
      if (nt==0) d0=c; else if (nt==1) d1=c; else if (nt==2) d2=c; else d3=c;
    }
  }

  // ---- LayerNorm + stores ----
#pragma unroll
  for (int reg=0;reg<4;reg++){
    float v0 = d0[reg] + bsm[1][cl];
    float v1 = d1[reg] + bsm[1][16+cl];
    float v2 = d2[reg] + bsm[1][32+cl];
    float v3 = d3[reg] + bsm[1][48+cl];
    float sA = v0+v1+v2+v3;
    float sB = v0*v0+v1*v1+v2*v2+v3*v3;
#pragma unroll
    for (int m=1;m<16;m<<=1){ sA += __shfl_xor(sA,m); sB += __shfl_xor(sB,m); }
    float mean = sA * 0.015625f;
    float var  = sB * 0.015625f - mean*mean;
    float inv  = 1.0f / sqrtf(var + 1e-5f);
    float o0v = (v0-mean)*inv*bsm[2][cl]    + bsm[3][cl];
    float o1v = (v1-mean)*inv*bsm[2][16+cl] + bsm[3][16+cl];
    float o2v = (v2-mean)*inv*bsm[2][32+cl] + bsm[3][32+cl];
    float o3v = (v3-mean)*inv*bsm[2][48+cl] + bsm[3][48+cl];
    float* lr = xsw + (16*wv + 4*kgrp + reg)*68;
    lr[cl] = o0v; lr[16+cl] = o1v; lr[32+cl] = o2v; lr[48+cl] = o3v;
    if constexpr (WRITE_HE){
      float* orow = outp + (size_t)(grow0 + reg)*64;
      orow[cl] = o0v; orow[16+cl] = o1v; orow[32+cl] = o2v; orow[48+cl] = o3v;
    }
  }
  __syncthreads();

  // ---- fused deterministic aggregation (float4 LDS reads) ----
  {
    const int n0 = ds_dst[0], nL = ds_dst[63];
    const int s = t >> 4, cq2 = t & 15;
    const size_t b = blockIdx.x;
    for (int n = n0 + s; n <= nL; n += 16){
      int lo = indptr[n], hi = indptr[n+1];
      int lo_c = lo - rowbase; if (lo_c < 0) lo_c = 0;
      int hi_c = hi - rowbase; if (hi_c > 64) hi_c = 64;
      float4 a = {0,0,0,0};
      for (int p = lo_c; p < hi_c; ++p){
        float4 v = xs4[p*17 + cq2];
        a.x += v.x; a.y += v.y; a.z += v.z; a.w += v.w;
      }
      if (lo < rowbase)              ((float4*)(headp + b*64))[cq2] = a;
      else if (hi > rowbase + 64)    ((float4*)(tailp + b*64))[cq2] = a;
      else                           ((float4*)(aggp + (size_t)n*64))[cq2] = a;
    }
    if (s == 0 && !(indptr[n0] < rowbase)){
      float4 z = {0,0,0,0};
      ((float4*)(headp + b*64))[cq2] = z;
    }
    if (s == 1){
      int lo = indptr[nL], hi = indptr[nL+1];
      if (!(lo >= rowbase && hi > rowbase + 64)){
        float4 z = {0,0,0,0};
        ((float4*)(tailp + b*64))[cq2] = z;
      }
    }
  }
}

// ---------------- node MLP (split-bf16 MFMA) + mean partials + fused NEXT-layer pa/pb prep ----------------
template<int PREP>
__global__ __launch_bounds__(256) void node_mlp_mfma(
    const float* __restrict__ hn, const float* __restrict__ agg,
    const float* __restrict__ un,
    const short* __restrict__ w1h, const short* __restrict__ w1l,
    const short* __restrict__ w2h, const short* __restrict__ w2l,
    const short* __restrict__ wah, const short* __restrict__ wal,
    const short* __restrict__ wbh, const short* __restrict__ wbl,
    const float* __restrict__ b1, const float* __restrict__ b2,
    const float* __restrict__ lng, const float* __restrict__ lnb,
    float* __restrict__ outp, float* __restrict__ pn, float* __restrict__ pe,
    float* __restrict__ pa, float* __restrict__ pb)
{
  __shared__ float4 xs4[64*33];   // 64 rows x 128 f (+pad); hn|agg; h1 then LN-out in quads 0..15
  __shared__ float  bsm[5][64];
  __shared__ float  wsum[4][64], asum[4][64];

  const int t = threadIdx.x;
  const int rowbase = blockIdx.x*64;
  const int g = rowbase >> 9;

  if (t < 64){ bsm[0][t] = b1[t]; bsm[4][t] = un[(g<<6)+t]; }
  else if (t < 128) bsm[1][t-64]  = b2[t-64];
  else if (t < 192) bsm[2][t-128] = lng[t-128];
  else              bsm[3][t-192] = lnb[t-192];

  const int wv = t>>6, lane = t&63, cl = lane&15, kgrp = lane>>4;
  const int lrow  = 16*wv + cl;
  const int grow0 = rowbase + 16*wv + 4*kgrp;

  {
    const float4* hn4 = (const float4*)(hn  + (size_t)rowbase*64);
    const float4* ag4 = (const float4*)(agg + (size_t)rowbase*64);
#pragma unroll
    for (int i=0;i<4;i++){
      int idx = t + i*256;
      xs4[(idx>>4)*33 + (idx&15)] = hn4[idx];
    }
#pragma unroll
    for (int i=0;i<4;i++){
      int idx = t + i*256;
      xs4[(idx>>4)*33 + 16 + (idx&15)] = ag4[idx];
    }
  }
  __syncthreads();

  const short8b* W1h = (const short8b*)w1h;
  const short8b* W1l = (const short8b*)w1l;
  const short8b* W2h = (const short8b*)w2h;
  const short8b* W2l = (const short8b*)w2l;

  // ---- GEMM1 (K=128) ----
  f32x4 acc0 = {0,0,0,0}, acc1 = {0,0,0,0}, acc2_ = {0,0,0,0}, acc3 = {0,0,0,0};
#pragma unroll
  for (int kc=0;kc<4;kc++){
    float4 a0 = xs4[lrow*33 + kc*8 + kgrp*2];
    float4 a1 = xs4[lrow*33 + kc*8 + kgrp*2 + 1];
    short8b ahi, alo; mk_frag(a0, a1, ahi, alo);
#pragma unroll
    for (int nt=0;nt<4;nt++){
      short8b bh = W1h[(kc*4+nt)*64 + lane];
      short8b bl = W1l[(kc*4+nt)*64 + lane];
      f32x4 c = (nt==0)?acc0:(nt==1)?acc1:(nt==2)?acc2_:acc3;
      c = __builtin_amdgcn_mfma_f32_16x16x32_bf16(ahi, bh, c, 0,0,0);
      c = __builtin_amdgcn_mfma_f32_16x16x32_bf16(alo, bh, c, 0,0,0);
      c = __builtin_amdgcn_mfma_f32_16x16x32_bf16(ahi, bl, c, 0,0,0);
      if (nt==0) acc0=c; else if (nt==1) acc1=c; else if (nt==2) acc2_=c; else acc3=c;
    }
  }

  // ---- epilogue1: h1 -> LDS quads 0..15 ----
  float* xsw = (float*)xs4;
#pragma unroll
  for (int nt=0;nt<4;nt++){
    int cn = nt*16 + cl;
    float bc = bsm[0][cn] + bsm[4][cn];
    f32x4 c = (nt==0)?acc0:(nt==1)?acc1:(nt==2)?acc2_:acc3;
#pragma unroll
    for (int reg=0;reg<4;reg++){
      float h = fmaxf(c[reg] + bc, 0.f);
      xsw[(16*wv + 4*kgrp + reg)*132 + cn] = h;
    }
  }

  // ---- GEMM2 (K=64) ----
  f32x4 d0 = {0,0,0,0}, d1 = {0,0,0,0}, d2 = {0,0,0,0}, d3 = {0,0,0,0};
#pragma unroll
  for (int kc=0;kc<2;kc++){
    float4 a0 = xs4[lrow*33 + kc*8 + kgrp*2];
    float4 a1 = xs4[lrow*33 + kc*8 + kgrp*2 + 1];
    short8b ahi, alo; mk_frag(a0, a1, ahi, alo);
#pragma unroll
    for (int nt=0;nt<4;nt++){
      short8b bh = W2h[(kc*4+nt)*64 + lane];
      short8b bl = W2l[(kc*4+nt)*64 + lane];
      f32x4 c = (nt==0)?d0:(nt==1)?d1:(nt==2)?d2:d3;
      c = __builtin_amdgcn_mfma_f32_16x16x32_bf16(ahi, bh, c, 0,0,0);
      c = __builtin_amdgcn_mfma_f32_16x16x32_bf16(alo, bh, c, 0,0,0);
      c = __builtin_amdgcn_mfma_f32_16x16x32_bf16(ahi, bl, c, 0,0,0);
      if (nt==0) d0=c; else if (nt==1) d1=c; else if (nt==2) d2=c; else d3=c;
    }
  }

  // ---- LayerNorm + store + LDS LN-out (quads 0..15, overwrite dead h1) ----
  float ms0 = 0.f, ms1 = 0.f, ms2 = 0.f, ms3 = 0.f;
#pragma unroll
  for (int reg=0;reg<4;reg++){
    float v0 = d0[reg] + bsm[1][cl];
    float v1 = d1[reg] + bsm[1][16+cl];
    float v2 = d2[reg] + bsm[1][32+cl];
    float v3 = d3[reg] + bsm[1][48+cl];
    float sA = v0+v1+v2+v3;
    float sB = v0*v0+v1*v1+v2*v2+v3*v3;
#pragma unroll
    for (int m=1;m<16;m<<=1){ sA += __shfl_xor(sA,m); sB += __shfl_xor(sB,m); }
    float mean = sA * 0.015625f;
    float var  = sB * 0.015625f - mean*mean;
    float inv  = 1.0f / sqrtf(var + 1e-5f);
    float o0v = (v0-mean)*inv*bsm[2][cl]    + bsm[3][cl];
    float o1v = (v1-mean)*inv*bsm[2][16+cl] + bsm[3][16+cl];
    float o2v = (v2-mean)*inv*bsm[2][32+cl] + bsm[3][32+cl];
    float o3v = (v3-mean)*inv*bsm[2][48+cl] + bsm[3][48+cl];
    float* orow = outp + (size_t)(grow0 + reg)*64;
    orow[cl] = o0v; orow[16+cl] = o1v; orow[32+cl] = o2v; orow[48+cl] = o3v;
    float* lr = xsw + (16*wv + 4*kgrp + reg)*132;
    lr[cl] = o0v; lr[16+cl] = o1v; lr[32+cl] = o2v; lr[48+cl] = o3v;
    ms0 += o0v; ms1 += o1v; ms2 += o2v; ms3 += o3v;
  }

  // ---- PREP: pa/pb for next layer from LN-out rows (same-wave LDS) ----
  if constexpr (PREP){
#pragma unroll
    for (int m2=0;m2<2;m2++){
      const short8b* Wh = (const short8b*)(m2==0 ? wah : wbh);
      const short8b* Wl = (const short8b*)(m2==0 ? wal : wbl);
      f32x4 e0 = {0,0,0,0}, e1 = {0,0,0,0}, e2 = {0,0,0,0}, e3 = {0,0,0,0};
#pragma unroll
      for (int kc=0;kc<2;kc++){
        float4 a0 = xs4[lrow*33 + kc*8 + kgrp*2];
        float4 a1 = xs4[lrow*33 + kc*8 + kgrp*2 + 1];
        short8b ahi, alo; mk_frag(a0, a1, ahi, alo);
#pragma unroll
        for (int nt=0;nt<4;nt++){
          short8b bh = Wh[(kc*4+nt)*64 + lane];
          short8b bl = Wl[(kc*4+nt)*64 + lane];
          f32x4 c = (nt==0)?e0:(nt==1)?e1:(nt==2)?e2:e3;
          c = __builtin_amdgcn_mfma_f32_16x16x32_bf16(ahi, bh, c, 0,0,0);
          c = __builtin_amdgcn_mfma_f32_16x16x32_bf16(alo, bh, c, 0,0,0);
          c = __builtin_amdgcn_mfma_f32_16x16x32_bf16(ahi, bl, c, 0,0,0);
          if (nt==0) e0=c; else if (nt==1) e1=c; else if (nt==2) e2=c; else e3=c;
        }
      }
      float* dstp = (m2==0) ? pa : pb;
#pragma unroll
      for (int nt=0;nt<4;nt++){
        int cn = nt*16 + cl;
        f32x4 c = (nt==0)?e0:(nt==1)?e1:(nt==2)?e2:e3;
#pragma unroll
        for (int reg=0;reg<4;reg++)
          dstp[(size_t)(grow0+reg)*64 + cn] = c[reg];
      }
    }
  }

  // ---- mean partials ----
  ms0 += __shfl_xor(ms0,16); ms0 += __shfl_xor(ms0,32);
  ms1 += __shfl_xor(ms1,16); ms1 += __shfl_xor(ms1,32);
  ms2 += __shfl_xor(ms2,16); ms2 += __shfl_xor(ms2,32);
  ms3 += __shfl_xor(ms3,16); ms3 += __shfl_xor(ms3,32);
  if (kgrp == 0){
    wsum[wv][cl]    = ms0; wsum[wv][16+cl] = ms1;
    wsum[wv][32+cl] = ms2; wsum[wv][48+cl] = ms3;
  }
  __syncthreads();
  {
    int c = t & 63, q = t >> 6;
    float as = 0.f;
    for (int r = q*16; r < q*16+16; ++r) as += xsw[r*132 + 64 + c];
    asum[q][c] = as;
  }
  __syncthreads();
  if (t < 64){
    pn[(size_t)blockIdx.x*64 + t] = wsum[0][t]+wsum[1][t]+wsum[2][t]+wsum[3][t];
    pe[(size_t)blockIdx.x*64 + t] = asum[0][t]+asum[1][t]+asum[2][t]+asum[3][t];
  }
}

// ---------------- graphk: means reduce + graph MLP + LN + next-layer ue/un (64 blocks x 64 thr) ----------------
__global__ __launch_bounds__(64) void graphk(
    const float* __restrict__ pn, const float* __restrict__ pe,
    float* __restrict__ u,
    const float* __restrict__ w1, const float* __restrict__ b1,
    const float* __restrict__ w2, const float* __restrict__ b2,
    const float* __restrict__ lng, const float* __restrict__ lnb,
    const float* __restrict__ wue, const float* __restrict__ wun,
    float* __restrict__ ue, float* __restrict__ un)
{
  const int g = blockIdx.x, t = threadIdx.x;
  __shared__ float xin[192];
  __shared__ float h1[64];
  __shared__ float us[64];
  float uo = u[(g<<6)+t];
  float ns = 0.f, es = 0.f;
#pragma unroll
  for (int c=0;c<8;c++){
    ns += pn[(size_t)(g*8+c)*64 + t];
    es += pe[(size_t)(g*8+c)*64 + t];
  }
  xin[t] = uo; xin[64+t] = ns*(1.f/512.f); xin[128+t] = es*(1.f/4096.f);
  __syncthreads();
  float acc = b1[t];
  for (int k=0;k<192;k++) acc = fmaf(xin[k], w1[k*64+t], acc);
  h1[t] = fmaxf(acc, 0.f);
  __syncthreads();
  float v = b2[t];
  for (int k=0;k<64;k++) v = fmaf(h1[k], w2[k*64+t], v);
  float sA = v, sB = v*v;
#pragma unroll
  for (int m=1;m<64;m<<=1){ sA += __shfl_xor(sA,m); sB += __shfl_xor(sB,m); }
  float mean = sA * 0.015625f;
  float var  = sB * 0.015625f - mean*mean;
  float inv  = 1.0f / sqrtf(var + 1e-5f);
  float unew = (v-mean)*inv*lng[t] + lnb[t];
  u[(g<<6)+t] = unew;
  if (wue){
    us[t] = unew;
    __syncthreads();
    float a1 = 0.f, a2 = 0.f;
    for (int k=0;k<64;k++){
      float xv = us[k];
      a1 = fmaf(xv, wue[k*64+t], a1);
      a2 = fmaf(xv, wun[k*64+t], a2);
    }
    ue[(g<<6)+t] = a1;
    un[(g<<6)+t] = a2;
  }
}

// ---------------- heads ----------------
__global__ __launch_bounds__(512) void heads_kernel(
    const float* __restrict__ hn, const float* __restrict__ uvec,
    const float* __restrict__ aw, const float* __restrict__ ab,
    const float* __restrict__ cw, const float* __restrict__ cb,
    float* __restrict__ out)
{
  const int g = blockIdx.x, t = threadIdx.x;
  const int n = (g<<9) + t;
  const float4* hp = (const float4*)(hn + (size_t)n*64);
  const float4* ap = (const float4*)aw;
  float d = 0.f;
#pragma unroll
  for (int i=0;i<16;i++){
    float4 h = hp[i], a = ap[i];
    d += h.x*a.x + h.y*a.y + h.z*a.z + h.w*a.w;
  }
  d += ab[0];
  float z = 1.0f/(1.0f + expf(-d));

  unsigned o0,o1;
  threefry(0u, 42u, 0u, (unsigned)n, o0, o1);
  unsigned bits = o0 ^ o1;
  float f = __uint_as_float((bits>>9) | 0x3f800000u) - 1.0f;
  float gum = -logf(-logf(fmaxf(1.17549435e-38f, f)));

  const int lane = t & 63, wid = t >> 6;
  __shared__ float smax[8], ssum[8], sent[8], skey[8];
  __shared__ int   sidx[8];
  __shared__ float sM, sS;
  __shared__ int   sA;

  float m = z;
#pragma unroll
  for (int sh=1; sh<64; sh<<=1) m = fmaxf(m, __shfl_xor(m, sh));
  if (lane==0) smax[wid] = m;
  __syncthreads();
  if (t==0){ float mm=smax[0]; for(int i=1;i<8;i++) mm=fmaxf(mm,smax[i]); sM=mm; }
  __syncthreads();
  float M = sM;
  float ex = expf(z - M);
  float ssl = ex;
#pragma unroll
  for (int sh=1; sh<64; sh<<=1) ssl += __shfl_xor(ssl, sh);
  if (lane==0) ssum[wid] = ssl;
  __syncthreads();
  if (t==0){ float ss=0.f; for(int i=0;i<8;i++) ss+=ssum[i]; sS=ss; }
  __syncthreads();
  float logp = z - M - logf(sS);
  float p = expf(logp);
  float entl = p * logp;
#pragma unroll
  for (int sh=1; sh<64; sh<<=1) entl += __shfl_xor(entl, sh);
  if (lane==0) sent[wid] = entl;

  float kv = z + gum; int ki = t;
#pragma unroll
  for (int sh=1; sh<64; sh<<=1){
    float ov = __shfl_xor(kv, sh);
    int   oi = __shfl_xor(ki, sh);
    if (ov > kv || (ov == kv && oi < ki)){ kv = ov; ki = oi; }
  }
  if (lane==0){ skey[wid] = kv; sidx[wid] = ki; }
  __syncthreads();
  if (t==0){
    float bv = skey[0]; int bi = sidx[0];
    for (int i=1;i<8;i++) if (skey[i] > bv || (skey[i]==bv && sidx[i] < bi)){ bv=skey[i]; bi=sidx[i]; }
    sA = bi;
    float ent = 0.f; for (int i=0;i<8;i++) ent += sent[i];
    out[g]      = (float)bi;
    out[128+g]  = -ent;
  }
  __syncthreads();
  if (t == sA) out[64+g] = logp;

  if (t < 64){
    float pv = uvec[(g<<6)+t] * cw[t];
#pragma unroll
    for (int sh=1; sh<64; sh<<=1) pv += __shfl_xor(pv, sh);
    if (t==0) out[192+g] = pv + cb[0];
  }
}

// ---------------- launch ----------------
extern "C" void kernel_launch(void* const* d_in, const int* in_sizes, int n_in,
                              void* d_out, int out_size, void* d_ws, size_t ws_size,
                              hipStream_t stream)
{
  (void)in_sizes; (void)n_in; (void)out_size; (void)ws_size;
  const float* x      = (const float*)d_in[0];
  const float* eattr  = (const float*)d_in[1];
  const int*   eidx   = (const int*)d_in[2];
  const float* node_w = (const float*)d_in[5];
  const float* node_b = (const float*)d_in[6];
  const float* edge_w = (const float*)d_in[7];
  const float* edge_b = (const float*)d_in[8];
  const float* init_u = (const float*)d_in[9];
  const float* ew1 = (const float*)d_in[10]; const float* eb1 = (const float*)d_in[11];
  const float* ew2 = (const float*)d_in[12]; const float* eb2 = (const float*)d_in[13];
  const float* elg = (const float*)d_in[14]; const float* elb = (const float*)d_in[15];
  const float* nw1 = (const float*)d_in[16]; const float* nb1 = (const float*)d_in[17];
  const float* nw2 = (const float*)d_in[18]; const float* nb2 = (const float*)d_in[19];
  const float* nlg = (const float*)d_in[20]; const float* nlb = (const float*)d_in[21];
  const float* gw1 = (const float*)d_in[22]; const float* gb1 = (const float*)d_in[23];
  const float* gw2 = (const float*)d_in[24]; const float* gb2 = (const float*)d_in[25];
  const float* glg = (const float*)d_in[26]; const float* glb = (const float*)d_in[27];
  const float* aw  = (const float*)d_in[28]; const float* ab  = (const float*)d_in[29];
  const float* cw  = (const float*)d_in[30]; const float* cb  = (const float*)d_in[31];
  const int* src = eidx;
  const int* dst = eidx + EE;

  float* ws    = (float*)d_ws;
  float* hn    = ws;                         // N*64
  float* he    = hn + (size_t)NN*64;         // E*64  (dst-sorted order)
  float* agg   = he + (size_t)EE*64;         // N*64
  float* u     = agg + (size_t)NN*64;        // G*64
  int* cnt     = (int*)(u + GG*64);          // N
  int* indptr  = cnt + NN;                   // N+1
  int* fillc   = indptr + NN + 1;            // N
  int* eord    = fillc + NN;                 // E
  int* srcs    = eord + EE;                  // E
  int* dsts    = srcs + EE;                  // E
  float* pb    = (float*)(dsts + EE);        // N*64
  float* pa    = pb + (size_t)NN*64;         // N*64
  float* ue    = pa + (size_t)NN*64;         // G*64
  float* un    = ue + GG*64;                 // G*64
  float* pn    = un + GG*64;                 // 512*64
  float* pe    = pn + 512*64;                // 512*64
  float* headp = pe + 512*64;                // 4096*64
  float* tailp = headp + 4096*64;            // 4096*64
  short* wfh   = (short*)(tailp + 4096*64);  // 88064 shorts
  short* wfl   = wfh + 88064;                // 88064 shorts

  float* out = (float*)d_out;

  hipMemsetAsync(cnt,   0, NN*sizeof(int), stream);
  hipMemsetAsync(fillc, 0, NN*sizeof(int), stream);

  count_kernel<<<EE/256, 256, 0, stream>>>(dst, cnt);
  scan_kernel<<<1, 1024, 0, stream>>>(cnt, indptr);
  fill_kernel<<<EE/256, 256, 0, stream>>>(dst, indptr, fillc, eord);
  sort_kernel<<<NN/256, 256, 0, stream>>>(indptr, eord);
  perm_kernel<<<EE/256, 256, 0, stream>>>(src, dst, eord, srcs, dsts);

  encode_kernel<32><<<NN/4, 256, 0, stream>>>(x, node_w, node_b, hn, NN);
  initu_kernel<<<16, 256, 0, stream>>>(init_u, u);
  wprep_kernel<<<43, 256, 0, stream>>>(edge_w, ew1, ew2, nw1, nw2, wfh, wfl);

  // layer-0 pa/pb, ue/un
  pre_kernel<<<NN/32, 256, 0, stream>>>(hn, ew1, ew1 + 64*64, pa, pb, NN);
  pre_kernel<<<2, 256, 0, stream>>>(u, ew1 + 192*64, nw1 + 128*64, ue, un, GG);

  // frag offsets (shorts): enc=0; per layer l: e1=2048+l*20480, e2=+4096, n1=+8192, n2=+16384
  // prep frags: pa(l)=63488+l*8192, pb(l)=+4096  (weights of LAYER l's ew1[0:64]/[64:128])
  for (int l=0; l<NL; ++l){
    size_t e1o = 2048 + (size_t)l*20480;
    size_t e2o = e1o + 4096, n1o = e1o + 8192, n2o = e1o + 16384;
    size_t pao = 63488 + (size_t)(l+1)*8192, pbo = pao + 4096;  // next layer

    if (l == 0)
      edge_mlp_mfma<1,1><<<EE/64, 256, 0, stream>>>(he, eattr, eord, pa, pb, ue, srcs, dsts, indptr,
          wfh, wfl, wfh + e1o, wfl + e1o, wfh + e2o, wfl + e2o,
          edge_b, eb1 + l*64, eb2 + l*64, elg + l*64, elb + l*64, he, agg, headp, tailp);
    else if (l == 1)
      edge_mlp_mfma<0,1><<<EE/64, 256, 0, stream>>>(he, eattr, eord, pa, pb, ue, srcs, dsts, indptr,
          wfh, wfl, wfh + e1o, wfl + e1o, wfh + e2o, wfl + e2o,
          edge_b, eb1 + l*64, eb2 + l*64, elg + l*64, elb + l*64, he, agg, headp, tailp);
    else
      edge_mlp_mfma<0,0><<<EE/64, 256, 0, stream>>>(he, eattr, eord, pa, pb, ue, srcs, dsts, indptr,
          wfh, wfl, wfh + e1o, wfl + e1o, wfh + e2o, wfl + e2o,
          edge_b, eb1 + l*64, eb2 + l*64, elg + l*64, elb + l*64, he, agg, headp, tailp);

    aggfix_kernel<<<NN*16/256, 256, 0, stream>>>(indptr, headp, tailp, agg);

    if (l < NL-1)
      node_mlp_mfma<1><<<NN/64, 256, 0, stream>>>(hn, agg, un,
          wfh + n1o, wfl + n1o, wfh + n2o, wfl + n2o,
          wfh + pao, wfl + pao, wfh + pbo, wfl + pbo,
          nb1 + l*64, nb2 + l*64, nlg + l*64, nlb + l*64, hn, pn, pe, pa, pb);
    else
      node_mlp_mfma<0><<<NN/64, 256, 0, stream>>>(hn, agg, un,
          wfh + n1o, wfl + n1o, wfh + n2o, wfl + n2o,
          nullptr, nullptr, nullptr, nullptr,
          nb1 + l*64, nb2 + l*64, nlg + l*64, nlb + l*64, hn, pn, pe, pa, pb);

    const float* wue = (l < NL-1) ? (ew1 + (size_t)(l+1)*16384 + 192*64) : nullptr;
    const float* wun = (l < NL-1) ? (nw1 + (size_t)(l+1)*12288 + 128*64) : nullptr;
    graphk<<<GG, 64, 0, stream>>>(pn, pe, u,
        gw1 + (size_t)l*192*64, gb1 + l*64, gw2 + (size_t)l*64*64, gb2 + l*64,
        glg + l*64, glb + l*64, wue, wun, ue, un);
  }

  heads_kernel<<<GG, 512, 0, stream>>>(hn, u, aw, ab, cw, cb, out);
}

// Round 10
// 328.397 us; speedup vs baseline: 5.0494x; 1.0617x over previous
//
#include <hip/hip_runtime.h>
#include <hip/hip_bf16.h>
#include <math.h>

#define GG 64
#define NPGc 512
#define NN (GG*NPGc)      // 32768 nodes
#define EE (NN*8)         // 262144 edges
#define HH 64
#define NL 3

typedef __attribute__((ext_vector_type(8))) short short8b;
typedef __attribute__((ext_vector_type(4))) float f32x4;

// ---------------- bf16 split helpers ----------------
__device__ __forceinline__ unsigned short f2bf_rne(float f){
  unsigned u = __float_as_uint(f);
  unsigned r = u + 0x7fffu + ((u>>16)&1u);
  return (unsigned short)(r>>16);
}
__device__ __forceinline__ float bf2f(unsigned short h){
  return __uint_as_float(((unsigned)h)<<16);
}
__device__ __forceinline__ void mk_frag(const float4 &u, const float4 &v, short8b &hi, short8b &lo){
  float av[8] = {u.x,u.y,u.z,u.w,v.x,v.y,v.z,v.w};
#pragma unroll
  for (int j=0;j<8;j++){
    __hip_bfloat16 h = __float2bfloat16(av[j]);
    hi[j] = (short)__builtin_bit_cast(unsigned short, h);
    float rem = av[j] - __bfloat162float(h);
    __hip_bfloat16 l = __float2bfloat16(rem);
    lo[j] = (short)__builtin_bit_cast(unsigned short, l);
  }
}

// ---------------- threefry2x32 (JAX-compatible, partitionable mode) ----------------
__device__ __forceinline__ unsigned rotl32(unsigned x, int r){ return (x<<r)|(x>>(32-r)); }
__device__ __forceinline__ void threefry(unsigned k0, unsigned k1, unsigned x0, unsigned x1,
                                         unsigned &o0, unsigned &o1){
  unsigned ks2 = k0 ^ k1 ^ 0x1BD11BDAu;
  unsigned v0 = x0 + k0, v1 = x1 + k1;
#define R4(a,b,c,d) v0+=v1; v1=rotl32(v1,a); v1^=v0; v0+=v1; v1=rotl32(v1,b); v1^=v0; \
                    v0+=v1; v1=rotl32(v1,c); v1^=v0; v0+=v1; v1=rotl32(v1,d); v1^=v0;
  R4(13,15,26,6)  v0+=k1;  v1+=ks2+1u;
  R4(17,29,16,24) v0+=ks2; v1+=k0+2u;
  R4(13,15,26,6)  v0+=k0;  v1+=k1+3u;
  R4(17,29,16,24) v0+=k1;  v1+=ks2+4u;
  R4(13,15,26,6)  v0+=ks2; v1+=k0+5u;
#undef R4
  o0=v0; o1=v1;
}

// ---------------- node encoder ----------------
template<int K>
__global__ __launch_bounds__(256) void encode_kernel(const float* __restrict__ in,
    const float* __restrict__ w, const float* __restrict__ b,
    float* __restrict__ out, int rows)
{
  int wid = blockIdx.x*4 + (threadIdx.x>>6);
  int lane = threadIdx.x & 63;
  if (wid >= rows) return;
  const float* xr = in + (size_t)wid*K;
  float acc = b[lane];
#pragma unroll
  for (int i=0;i<K;i++) acc = fmaf(xr[i], w[i*64+lane], acc);
  out[(size_t)wid*64+lane] = fmaxf(acc, 0.f);
}

__global__ __launch_bounds__(256) void initu_kernel(const float* __restrict__ iu, float* __restrict__ u){
  int i = blockIdx.x*256 + threadIdx.x;
  if (i < GG*64) u[i] = iu[i & 63];
}

// ---------------- CSR build ----------------
__global__ __launch_bounds__(256) void count_kernel(const int* __restrict__ dst, int* __restrict__ cnt){
  int e = blockIdx.x*256 + threadIdx.x;
  if (e < EE) atomicAdd(&cnt[dst[e]], 1);
}
__global__ __launch_bounds__(1024) void scan_kernel(const int* __restrict__ cnt, int* __restrict__ indptr){
  __shared__ int part[1024];
  const int t = threadIdx.x;
  const int base = t*32;
  int s = 0;
  for (int i=0;i<32;i++) s += cnt[base+i];
  part[t] = s;
  __syncthreads();
  for (int off=1; off<1024; off<<=1){
    int v = part[t];
    int add = (t >= off) ? part[t-off] : 0;
    __syncthreads();
    part[t] = v + add;
    __syncthreads();
  }
  int run = (t==0) ? 0 : part[t-1];
  for (int i=0;i<32;i++){ indptr[base+i] = run; run += cnt[base+i]; }
  if (t==1023) indptr[NN] = run;
}
__global__ __launch_bounds__(256) void fill_kernel(const int* __restrict__ dst, const int* __restrict__ indptr,
                                                   int* __restrict__ fillc, int* __restrict__ eord){
  int e = blockIdx.x*256 + threadIdx.x;
  if (e < EE){ int dn = dst[e]; int p = atomicAdd(&fillc[dn], 1); eord[indptr[dn]+p] = e; }
}
__global__ __launch_bounds__(256) void sort_kernel(const int* __restrict__ indptr, int* __restrict__ eord){
  int n = blockIdx.x*256 + threadIdx.x;
  if (n >= NN) return;
  int lo = indptr[n], hi = indptr[n+1];
  for (int i=lo+1;i<hi;i++){
    int v = eord[i]; int j = i-1;
    while (j >= lo && eord[j] > v){ eord[j+1]=eord[j]; j--; }
    eord[j+1] = v;
  }
}
__global__ __launch_bounds__(256) void perm_kernel(const int* __restrict__ src, const int* __restrict__ dst,
                                                   const int* __restrict__ eord,
                                                   int* __restrict__ srcs, int* __restrict__ dsts){
  int p = blockIdx.x*256 + threadIdx.x;
  if (p < EE){ int e = eord[p]; srcs[p] = src[e]; dsts[p] = dst[e]; }
}

// ---------------- pre_kernel: oa = x@wa, ob = x@wb (layer 0 only) ----------------
__global__ __launch_bounds__(256) void pre_kernel(const float* __restrict__ x,
    const float* __restrict__ wa, const float* __restrict__ wb,
    float* __restrict__ oa, float* __restrict__ ob, int rows)
{
  __shared__ float4 xs4[32*17];
  __shared__ float4 wsa[1024], wsb[1024];
  const int t = threadIdx.x;
  const int rowbase = blockIdx.x*32;
  {
    const int gi16 = t>>4, lg = t&15;
#pragma unroll
    for (int it=0; it<2; ++it){
      int er = gi16 + (it<<4);
      xs4[er*17+lg] = ((const float4*)(x + (size_t)64*(rowbase+er)))[lg];
    }
  }
  const float4* wa4 = (const float4*)wa;
  const float4* wb4 = (const float4*)wb;
#pragma unroll
  for (int i=0;i<4;i++){ wsa[t+i*256] = wa4[t+i*256]; wsb[t+i*256] = wb4[t+i*256]; }
  __syncthreads();

  const int r0 = (t>>4)*2, cq = t&15;
  float accA[2][4] = {{0,0,0,0},{0,0,0,0}};
  float accB[2][4] = {{0,0,0,0},{0,0,0,0}};
#pragma unroll
  for (int k4=0;k4<16;k4++){
    float4 a0 = xs4[(r0  )*17 + k4];
    float4 a1 = xs4[(r0+1)*17 + k4];
    const float* a0p = (const float*)&a0;
    const float* a1p = (const float*)&a1;
#pragma unroll
    for (int kk=0;kk<4;kk++){
      float4 ba = wsa[(k4*4+kk)*16 + cq];
      float4 bb = wsb[(k4*4+kk)*16 + cq];
      accA[0][0]=fmaf(a0p[kk],ba.x,accA[0][0]); accA[0][1]=fmaf(a0p[kk],ba.y,accA[0][1]);
      accA[0][2]=fmaf(a0p[kk],ba.z,accA[0][2]); accA[0][3]=fmaf(a0p[kk],ba.w,accA[0][3]);
      accA[1][0]=fmaf(a1p[kk],ba.x,accA[1][0]); accA[1][1]=fmaf(a1p[kk],ba.y,accA[1][1]);
      accA[1][2]=fmaf(a1p[kk],ba.z,accA[1][2]); accA[1][3]=fmaf(a1p[kk],ba.w,accA[1][3]);
      accB[0][0]=fmaf(a0p[kk],bb.x,accB[0][0]); accB[0][1]=fmaf(a0p[kk],bb.y,accB[0][1]);
      accB[0][2]=fmaf(a0p[kk],bb.z,accB[0][2]); accB[0][3]=fmaf(a0p[kk],bb.w,accB[0][3]);
      accB[1][0]=fmaf(a1p[kk],bb.x,accB[1][0]); accB[1][1]=fmaf(a1p[kk],bb.y,accB[1][1]);
      accB[1][2]=fmaf(a1p[kk],bb.z,accB[1][2]); accB[1][3]=fmaf(a1p[kk],bb.w,accB[1][3]);
    }
  }
#pragma unroll
  for (int rr=0; rr<2; rr++){
    size_t row = rowbase + r0 + rr;
    float4 va = {accA[rr][0],accA[rr][1],accA[rr][2],accA[rr][3]};
    float4 vb = {accB[rr][0],accB[rr][1],accB[rr][2],accB[rr][3]};
    ((float4*)(oa + row*64))[cq] = va;
    ((float4*)(ob + row*64))[cq] = vb;
  }
}

// ---------------- weight prep: per-lane MFMA B-fragments (bf16 hi/lo) ----------------
__global__ __launch_bounds__(256) void wprep_kernel(const float* __restrict__ edge_w,
    const float* __restrict__ ew1, const float* __restrict__ ew2,
    const float* __restrict__ nw1, const float* __restrict__ nw2,
    short* __restrict__ wfhi, short* __restrict__ wflo)
{
  int b = blockIdx.x;
  const float* W; int K; int kc; size_t doff;
  if (b < 31){
    int m = 0; kc = 0; doff = 0; int rem = b;
    for (m = 0; m < 13; m++){
      int kcs = (m==0) ? 1 : ((((m-1)&3)==2) ? 4 : 2);
      if (rem < kcs){ kc = rem; break; }
      rem -= kcs; doff += (size_t)kcs*2048;
    }
    if (m == 0){ W = edge_w; K = 16; }
    else {
      int l = (m-1)>>2, r = (m-1)&3;
      if      (r==0){ W = ew1 + (size_t)l*16384 + 8192; K = 64;  }
      else if (r==1){ W = ew2 + (size_t)l*4096;         K = 64;  }
      else if (r==2){ W = nw1 + (size_t)l*12288;        K = 128; }
      else          { W = nw2 + (size_t)l*4096;         K = 64;  }
    }
  } else {
    int idx = b - 31;
    int mi = idx >> 1; kc = idx & 1;
    int l = mi >> 1, which = mi & 1;
    W = ew1 + (size_t)l*16384 + (size_t)which*4096; K = 64;
    doff = 63488 + (size_t)mi*4096;
  }
  const int nt = threadIdx.x>>6, lane = threadIdx.x&63;
#pragma unroll
  for (int j=0;j<8;j++){
    int k = kc*32 + (lane>>4)*8 + j;
    int n = nt*16 + (lane&15);
    float v = (k < K) ? W[k*64+n] : 0.f;
    size_t o = doff + (size_t)kc*2048 + (size_t)((nt*64+lane)*8+j);
    unsigned short hi = f2bf_rne(v);
    wfhi[o] = (short)hi;
    wflo[o] = (short)f2bf_rne(v - bf2f(hi));
  }
}

// ---------------- edge MLP via split-bf16 MFMA + fused deterministic aggregation ----------------
// XCD-swizzled block id; 64 edges/block, 4 waves.
template<int FUSE, int WRITE_HE>
__global__ __launch_bounds__(256) void edge_mlp_mfma(
    const float* __restrict__ he, const float* __restrict__ eattr,
    const int* __restrict__ eord,
    const float* __restrict__ pa, const float* __restrict__ pb,
    const float* __restrict__ ue,
    const int* __restrict__ srcs, const int* __restrict__ dsts,
    const int* __restrict__ indptr,
    const short* __restrict__ weh, const short* __restrict__ wel,
    const short* __restrict__ w1h, const short* __restrict__ w1l,
    const short* __restrict__ w2h, const short* __restrict__ w2l,
    const float* __restrict__ eb, const float* __restrict__ b1,
    const float* __restrict__ b2,
    const float* __restrict__ lng, const float* __restrict__ lnb,
    float* __restrict__ outp,
    float* __restrict__ aggp, float* __restrict__ headp, float* __restrict__ tailp)
{
  __shared__ float4 xs4[64*17];            // he rows -> h1 rows -> LN-out rows (68 f stride)
  __shared__ float4 eas[FUSE ? 64*4 : 1];
  __shared__ float  bsm[6][64];
  __shared__ int    ds_dst[64];

  const int t = threadIdx.x;
  const int bid = ((blockIdx.x & 7) << 9) | (blockIdx.x >> 3);   // XCD swizzle, 4096 = 8*512
  const int rowbase = bid*64;
  const int g = rowbase >> 12;

  if (t < 64){
    bsm[0][t] = b1[t]; bsm[4][t] = ue[(g<<6)+t];
    if constexpr (FUSE) bsm[5][t] = eb[t];
    ds_dst[t] = dsts[rowbase + t];
  }
  else if (t < 128) bsm[1][t-64]  = b2[t-64];
  else if (t < 192) bsm[2][t-128] = lng[t-128];
  else              bsm[3][t-192] = lnb[t-192];

  const int wv = t>>6, lane = t&63, cl = lane&15, kgrp = lane>>4;
  const int lrow  = 16*wv + cl;
  const int grow0 = rowbase + 16*wv + 4*kgrp;

  int4 sv = ((const int4*)srcs)[grow0>>2];
  int4 dv = ((const int4*)dsts)[grow0>>2];
  float exa[4][4], exb[4][4];
#pragma unroll
  for (int reg=0;reg<4;reg++){
    int s_ = ((const int*)&sv)[reg], d_ = ((const int*)&dv)[reg];
#pragma unroll
    for (int nt=0;nt<4;nt++){
      exa[reg][nt] = pa[(size_t)s_*64 + nt*16 + cl];
      exb[reg][nt] = pb[(size_t)d_*64 + nt*16 + cl];
    }
  }

  float* xsw = (float*)xs4;

  if constexpr (FUSE){
    {
      const int er = t>>2, q = t&3;
      int e = eord[rowbase + er];
      eas[er*4+q] = ((const float4*)(eattr + (size_t)e*16))[q];
    }
    __syncthreads();
    f32x4 c0={0,0,0,0}, c1={0,0,0,0}, c2={0,0,0,0}, c3={0,0,0,0};
    short8b ahi, alo;
    if (kgrp < 2){
      float4 a0 = eas[lrow*4 + kgrp*2];
      float4 a1 = eas[lrow*4 + kgrp*2 + 1];
      mk_frag(a0, a1, ahi, alo);
    } else {
      ahi = (short8b){0,0,0,0,0,0,0,0};
      alo = (short8b){0,0,0,0,0,0,0,0};
    }
    const short8b* Wh = (const short8b*)weh;
    const short8b* Wl = (const short8b*)wel;
#pragma unroll
    for (int nt=0;nt<4;nt++){
      short8b bh = Wh[nt*64 + lane];
      short8b bl = Wl[nt*64 + lane];
      f32x4 c = (nt==0)?c0:(nt==1)?c1:(nt==2)?c2:c3;
      c = __builtin_amdgcn_mfma_f32_16x16x32_bf16(ahi, bh, c, 0,0,0);
      c = __builtin_amdgcn_mfma_f32_16x16x32_bf16(alo, bh, c, 0,0,0);
      c = __builtin_amdgcn_mfma_f32_16x16x32_bf16(ahi, bl, c, 0,0,0);
      if (nt==0) c0=c; else if (nt==1) c1=c; else if (nt==2) c2=c; else c3=c;
    }
#pragma unroll
    for (int nt=0;nt<4;nt++){
      int cn = nt*16 + cl;
      f32x4 c = (nt==0)?c0:(nt==1)?c1:(nt==2)?c2:c3;
#pragma unroll
      for (int reg=0;reg<4;reg++){
        float h = fmaxf(c[reg] + bsm[5][cn], 0.f);
        xsw[(16*wv + 4*kgrp + reg)*68 + cn] = h;
      }
    }
  } else {
    const float4* heb = (const float4*)(he + (size_t)rowbase*64);
#pragma unroll
    for (int i=0;i<4;i++){
      int idx = t + i*256;
      xs4[(idx>>4)*17 + (idx&15)] = heb[idx];
    }
    __syncthreads();
  }

  const short8b* W1h = (const short8b*)w1h;
  const short8b* W1l = (const short8b*)w1l;
  const short8b* W2h = (const short8b*)w2h;
  const short8b* W2l = (const short8b*)w2l;

  // ---- GEMM1 ----
  f32x4 acc0 = {0,0,0,0}, acc1 = {0,0,0,0}, acc2_ = {0,0,0,0}, acc3 = {0,0,0,0};
#pragma unroll
  for (int kc=0;kc<2;kc++){
    float4 a0 = xs4[lrow*17 + kc*8 + kgrp*2];
    float4 a1 = xs4[lrow*17 + kc*8 + kgrp*2 + 1];
    short8b ahi, alo; mk_frag(a0, a1, ahi, alo);
#pragma unroll
    for (int nt=0;nt<4;nt++){
      short8b bh = W1h[(kc*4+nt)*64 + lane];
      short8b bl = W1l[(kc*4+nt)*64 + lane];
      f32x4 c = (nt==0)?acc0:(nt==1)?acc1:(nt==2)?acc2_:acc3;
      c = __builtin_amdgcn_mfma_f32_16x16x32_bf16(ahi, bh, c, 0,0,0);
      c = __builtin_amdgcn_mfma_f32_16x16x32_bf16(alo, bh, c, 0,0,0);
      c = __builtin_amdgcn_mfma_f32_16x16x32_bf16(ahi, bl, c, 0,0,0);
      if (nt==0) acc0=c; else if (nt==1) acc1=c; else if (nt==2) acc2_=c; else acc3=c;
    }
  }

  // ---- epilogue1: h1 ----
#pragma unroll
  for (int nt=0;nt<4;nt++){
    int cn = nt*16 + cl;
    float bc = bsm[0][cn] + bsm[4][cn];
    f32x4 c = (nt==0)?acc0:(nt==1)?acc1:(nt==2)?acc2_:acc3;
#pragma unroll
    for (int reg=0;reg<4;reg++){
      float h = fmaxf(c[reg] + bc + exa[reg][nt] + exb[reg][nt], 0.f);
      xsw[(16*wv + 4*kgrp + reg)*68 + cn] = h;
    }
  }

  // ---- GEMM2 ----
  f32x4 d0 = {0,0,0,0}, d1 = {0,0,0,0}, d2 = {0,0,0,0}, d3 = {0,0,0,0};
#pragma unroll
  for (int kc=0;kc<2;kc++){
    float4 a0 = xs4[lrow*17 + kc*8 + kgrp*2];
    float4 a1 = xs4[lrow*17 + kc*8 + kgrp*2 + 1];
    short8b ahi, alo; mk_frag(a0, a1, ahi, alo);
#pragma unroll
    for (int nt=0;nt<4;nt++){
      short8b bh = W2h[(kc*4+nt)*64 + lane];
      short8b bl = W2l[(kc*4+nt)*64 + lane];
      f32x4 c = (nt==0)?d0:(nt==1)?d1:(nt==2)?d2:d3;
      c = __builtin_amdgcn_mfma_f32_16x16x32_bf16(ahi, bh, c, 0,0,0);
      c = __builtin_amdgcn_mfma_f32_16x16x32_bf16(alo, bh, c, 0,0,0);
      c = __builtin_amdgcn_mfma_f32_16x16x32_bf16(ahi, bl, c, 0,0,0);
      if (nt==0) d0=c; else if (nt==1) d1=c; else if (nt==2) d2=c; else d3=c;
    }
  }

  // ---- LayerNorm -> LDS only ----
#pragma unroll
  for (int reg=0;reg<4;reg++){
    float v0 = d0[reg] + bsm[1][cl];
    float v1 = d1[reg] + bsm[1][16+cl];
    float v2 = d2[reg] + bsm[1][32+cl];
    float v3 = d3[reg] + bsm[1][48+cl];
    float sA = v0+v1+v2+v3;
    float sB = v0*v0+v1*v1+v2*v2+v3*v3;
#pragma unroll
    for (int m=1;m<16;m<<=1){ sA += __shfl_xor(sA,m); sB += __shfl_xor(sB,m); }
    float mean = sA * 0.015625f;
    float var  = sB * 0.015625f - mean*mean;
    float inv  = 1.0f / sqrtf(var + 1e-5f);
    float o0v = (v0-mean)*inv*bsm[2][cl]    + bsm[3][cl];
    float o1v = (v1-mean)*inv*bsm[2][16+cl] + bsm[3][16+cl];
    float o2v = (v2-mean)*inv*bsm[2][32+cl] + bsm[3][32+cl];
    float o3v = (v3-mean)*inv*bsm[2][48+cl] + bsm[3][48+cl];
    float* lr = xsw + (16*wv + 4*kgrp + reg)*68;
    lr[cl] = o0v; lr[16+cl] = o1v; lr[32+cl] = o2v; lr[48+cl] = o3v;
  }
  __syncthreads();

  // ---- he store: coalesced float4 from LDS ----
  if constexpr (WRITE_HE){
    float4* he4 = (float4*)outp;
#pragma unroll
    for (int i=0;i<4;i++){
      int idx = t + i*256;
      he4[(size_t)rowbase*16 + idx] = xs4[(idx>>4)*17 + (idx&15)];
    }
  }

  // ---- fused deterministic aggregation (float4 LDS reads) ----
  {
    const int n0 = ds_dst[0], nL = ds_dst[63];
    const int s = t >> 4, cq2 = t & 15;
    const size_t b = (size_t)bid;
    for (int n = n0 + s; n <= nL; n += 16){
      int lo = indptr[n], hi = indptr[n+1];
      int lo_c = lo - rowbase; if (lo_c < 0) lo_c = 0;
      int hi_c = hi - rowbase; if (hi_c > 64) hi_c = 64;
      float4 a = {0,0,0,0};
      for (int p = lo_c; p < hi_c; ++p){
        float4 v = xs4[p*17 + cq2];
        a.x += v.x; a.y += v.y; a.z += v.z; a.w += v.w;
      }
      if (lo < rowbase)              ((float4*)(headp + b*64))[cq2] = a;
      else if (hi > rowbase + 64)    ((float4*)(tailp + b*64))[cq2] = a;
      else                           ((float4*)(aggp + (size_t)n*64))[cq2] = a;
    }
    if (s == 0 && !(indptr[n0] < rowbase)){
      float4 z = {0,0,0,0};
      ((float4*)(headp + b*64))[cq2] = z;
    }
    if (s == 1){
      int lo = indptr[nL], hi = indptr[nL+1];
      if (!(lo >= rowbase && hi > rowbase + 64)){
        float4 z = {0,0,0,0};
        ((float4*)(tailp + b*64))[cq2] = z;
      }
    }
  }
}

// ---------------- node MLP (split-bf16 MFMA) + agg fixup staging + mean partials + PREP ----------------
template<int PREP>
__global__ __launch_bounds__(256) void node_mlp_mfma(
    const float* __restrict__ hn, const float* __restrict__ agg,
    const float* __restrict__ un,
    const int* __restrict__ indptr,
    const float* __restrict__ headp, const float* __restrict__ tailp,
    const short* __restrict__ w1h, const short* __restrict__ w1l,
    const short* __restrict__ w2h, const short* __restrict__ w2l,
    const short* __restrict__ wah, const short* __restrict__ wal,
    const short* __restrict__ wbh, const short* __restrict__ wbl,
    const float* __restrict__ b1, const float* __restrict__ b2,
    const float* __restrict__ lng, const float* __restrict__ lnb,
    float* __restrict__ outp, float* __restrict__ pn, float* __restrict__ pe,
    float* __restrict__ pa, float* __restrict__ pb)
{
  __shared__ float4 xs4[64*33];   // 64 rows x 128 f (+pad); hn|agg; h1/LN-out in quads 0..15
  __shared__ float  bsm[5][64];
  __shared__ float  wsum[4][64], asum[4][64];

  const int t = threadIdx.x;
  const int bid = ((blockIdx.x & 7) << 6) | (blockIdx.x >> 3);   // XCD swizzle, 512 = 8*64
  const int rowbase = bid*64;
  const int g = rowbase >> 9;

  if (t < 64){ bsm[0][t] = b1[t]; bsm[4][t] = un[(g<<6)+t]; }
  else if (t < 128) bsm[1][t-64]  = b2[t-64];
  else if (t < 192) bsm[2][t-128] = lng[t-128];
  else              bsm[3][t-192] = lnb[t-192];

  const int wv = t>>6, lane = t&63, cl = lane&15, kgrp = lane>>4;
  const int lrow  = 16*wv + cl;
  const int grow0 = rowbase + 16*wv + 4*kgrp;

  // stage hn (quads 0..15)
  {
    const float4* hn4 = (const float4*)(hn + (size_t)rowbase*64);
#pragma unroll
    for (int i=0;i<4;i++){
      int idx = t + i*256;
      xs4[(idx>>4)*33 + (idx&15)] = hn4[idx];
    }
  }
  // stage agg with fused fixup (quads 16..31); 16-lane group per row
  {
    const int rs = t >> 4, cq2 = t & 15;
#pragma unroll
    for (int it=0; it<4; ++it){
      int r = rs + it*16;
      int n = rowbase + r;
      int lo = indptr[n], hi = indptr[n+1];
      float4 a = {0,0,0,0};
      if (lo < hi){
        int b0 = lo >> 6, b1 = (hi-1) >> 6;
        if (b0 == b1){
          a = ((const float4*)(agg + (size_t)n*64))[cq2];
        } else {
          a = ((const float4*)(tailp + (size_t)b0*64))[cq2];
          for (int b = b0+1; b <= b1; ++b){
            float4 h = ((const float4*)(headp + (size_t)b*64))[cq2];
            a.x+=h.x; a.y+=h.y; a.z+=h.z; a.w+=h.w;
          }
        }
      }
      xs4[r*33 + 16 + cq2] = a;
    }
  }
  __syncthreads();

  const short8b* W1h = (const short8b*)w1h;
  const short8b* W1l = (const short8b*)w1l;
  const short8b* W2h = (const short8b*)w2h;
  const short8b* W2l = (const short8b*)w2l;

  // ---- GEMM1 (K=128) ----
  f32x4 acc0 = {0,0,0,0}, acc1 = {0,0,0,0}, acc2_ = {0,0,0,0}, acc3 = {0,0,0,0};
#pragma unroll
  for (int kc=0;kc<4;kc++){
    float4 a0 = xs4[lrow*33 + kc*8 + kgrp*2];
    float4 a1 = xs4[lrow*33 + kc*8 + kgrp*2 + 1];
    short8b ahi, alo; mk_frag(a0, a1, ahi, alo);
#pragma unroll
    for (int nt=0;nt<4;nt++){
      short8b bh = W1h[(kc*4+nt)*64 + lane];
      short8b bl = W1l[(kc*4+nt)*64 + lane];
      f32x4 c = (nt==0)?acc0:(nt==1)?acc1:(nt==2)?acc2_:acc3;
      c = __builtin_amdgcn_mfma_f32_16x16x32_bf16(ahi, bh, c, 0,0,0);
      c = __builtin_amdgcn_mfma_f32_16x16x32_bf16(alo, bh, c, 0,0,0);
      c = __builtin_amdgcn_mfma_f32_16x16x32_bf16(ahi, bl, c, 0,0,0);
      if (nt==0) acc0=c; else if (nt==1) acc1=c; else if (nt==2) acc2_=c; else acc3=c;
    }
  }

  // ---- epilogue1: h1 -> LDS quads 0..15 ----
  float* xsw = (float*)xs4;
#pragma unroll
  for (int nt=0;nt<4;nt++){
    int cn = nt*16 + cl;
    float bc = bsm[0][cn] + bsm[4][cn];
    f32x4 c = (nt==0)?acc0:(nt==1)?acc1:(nt==2)?acc2_:acc3;
#pragma unroll
    for (int reg=0;reg<4;reg++){
      float h = fmaxf(c[reg] + bc, 0.f);
      xsw[(16*wv + 4*kgrp + reg)*132 + cn] = h;
    }
  }

  // ---- GEMM2 (K=64) ----
  f32x4 d0 = {0,0,0,0}, d1 = {0,0,0,0}, d2 = {0,0,0,0}, d3 = {0,0,0,0};
#pragma unroll
  for (int kc=0;kc<2;kc++){
    float4 a0 = xs4[lrow*33 + kc*8 + kgrp*2];
    float4 a1 = xs4[lrow*33 + kc*8 + kgrp*2 + 1];
    short8b ahi, alo; mk_frag(a0, a1, ahi, alo);
#pragma unroll
    for (int nt=0;nt<4;nt++){
      short8b bh = W2h[(kc*4+nt)*64 + lane];
      short8b bl = W2l[(kc*4+nt)*64 + lane];
      f32x4 c = (nt==0)?d0:(nt==1)?d1:(nt==2)?d2:d3;
      c = __builtin_amdgcn_mfma_f32_16x16x32_bf16(ahi, bh, c, 0,0,0);
      c = __builtin_amdgcn_mfma_f32_16x16x32_bf16(alo, bh, c, 0,0,0);
      c = __builtin_amdgcn_mfma_f32_16x16x32_bf16(ahi, bl, c, 0,0,0);
      if (nt==0) d0=c; else if (nt==1) d1=c; else if (nt==2) d2=c; else d3=c;
    }
  }

  // ---- LayerNorm -> LDS (quads 0..15, overwrite dead h1) + mean partial ----
  float ms0 = 0.f, ms1 = 0.f, ms2 = 0.f, ms3 = 0.f;
#pragma unroll
  for (int reg=0;reg<4;reg++){
    float v0 = d0[reg] + bsm[1][cl];
    float v1 = d1[reg] + bsm[1][16+cl];
    float v2 = d2[reg] + bsm[1][32+cl];
    float v3 = d3[reg] + bsm[1][48+cl];
    float sA = v0+v1+v2+v3;
    float sB = v0*v0+v1*v1+v2*v2+v3*v3;
#pragma unroll
    for (int m=1;m<16;m<<=1){ sA += __shfl_xor(sA,m); sB += __shfl_xor(sB,m); }
    float mean = sA * 0.015625f;
    float var  = sB * 0.015625f - mean*mean;
    float inv  = 1.0f / sqrtf(var + 1e-5f);
    float o0v = (v0-mean)*inv*bsm[2][cl]    + bsm[3][cl];
    float o1v = (v1-mean)*inv*bsm[2][16+cl] + bsm[3][16+cl];
    float o2v = (v2-mean)*inv*bsm[2][32+cl] + bsm[3][32+cl];
    float o3v = (v3-mean)*inv*bsm[2][48+cl] + bsm[3][48+cl];
    float* lr = xsw + (16*wv + 4*kgrp + reg)*132;
    lr[cl] = o0v; lr[16+cl] = o1v; lr[32+cl] = o2v; lr[48+cl] = o3v;
    ms0 += o0v; ms1 += o1v; ms2 += o2v; ms3 += o3v;
  }

  // ---- PREP: pa/pb for next layer from LN-out rows (same-wave LDS, no barrier) ----
  if constexpr (PREP){
#pragma unroll
    for (int m2=0;m2<2;m2++){
      const short8b* Wh = (const short8b*)(m2==0 ? wah : wbh);
      const short8b* Wl = (const short8b*)(m2==0 ? wal : wbl);
      f32x4 e0 = {0,0,0,0}, e1 = {0,0,0,0}, e2 = {0,0,0,0}, e3 = {0,0,0,0};
#pragma unroll
      for (int kc=0;kc<2;kc++){
        float4 a0 = xs4[lrow*33 + kc*8 + kgrp*2];
        float4 a1 = xs4[lrow*33 + kc*8 + kgrp*2 + 1];
        short8b ahi, alo; mk_frag(a0, a1, ahi, alo);
#pragma unroll
        for (int nt=0;nt<4;nt++){
          short8b bh = Wh[(kc*4+nt)*64 + lane];
          short8b bl = Wl[(kc*4+nt)*64 + lane];
          f32x4 c = (nt==0)?e0:(nt==1)?e1:(nt==2)?e2:e3;
          c = __builtin_amdgcn_mfma_f32_16x16x32_bf16(ahi, bh, c, 0,0,0);
          c = __builtin_amdgcn_mfma_f32_16x16x32_bf16(alo, bh, c, 0,0,0);
          c = __builtin_amdgcn_mfma_f32_16x16x32_bf16(ahi, bl, c, 0,0,0);
          if (nt==0) e0=c; else if (nt==1) e1=c; else if (nt==2) e2=c; else e3=c;
        }
      }
      float* dstp = (m2==0) ? pa : pb;
#pragma unroll
      for (int nt=0;nt<4;nt++){
        int cn = nt*16 + cl;
        f32x4 c = (nt==0)?e0:(nt==1)?e1:(nt==2)?e2:e3;
#pragma unroll
        for (int reg=0;reg<4;reg++)
          dstp[(size_t)(grow0+reg)*64 + cn] = c[reg];
      }
    }
  }

  // ---- mean partials + hn store ----
  ms0 += __shfl_xor(ms0,16); ms0 += __shfl_xor(ms0,32);
  ms1 += __shfl_xor(ms1,16); ms1 += __shfl_xor(ms1,32);
  ms2 += __shfl_xor(ms2,16); ms2 += __shfl_xor(ms2,32);
  ms3 += __shfl_xor(ms3,16); ms3 += __shfl_xor(ms3,32);
  if (kgrp == 0){
    wsum[wv][cl]    = ms0; wsum[wv][16+cl] = ms1;
    wsum[wv][32+cl] = ms2; wsum[wv][48+cl] = ms3;
  }
  __syncthreads();
  // hn store: coalesced float4 from LDS (quads 0..15 = LN-out)
  {
    float4* hn4o = (float4*)outp;
#pragma unroll
    for (int i=0;i<4;i++){
      int idx = t + i*256;
      hn4o[(size_t)rowbase*16 + idx] = xs4[(idx>>4)*33 + (idx&15)];
    }
  }
  // agg partial from staged (fixed) LDS quads 16..31
  {
    int c = t & 63, q = t >> 6;
    float as = 0.f;
    for (int r = q*16; r < q*16+16; ++r) as += xsw[r*132 + 64 + c];
    asum[q][c] = as;
  }
  __syncthreads();
  if (t < 64){
    pn[(size_t)bid*64 + t] = wsum[0][t]+wsum[1][t]+wsum[2][t]+wsum[3][t];
    pe[(size_t)bid*64 + t] = asum[0][t]+asum[1][t]+asum[2][t]+asum[3][t];
  }
}

// ---------------- graphk: means reduce + graph MLP + LN + next-layer ue/un ----------------
__global__ __launch_bounds__(64) void graphk(
    const float* __restrict__ pn, const float* __restrict__ pe,
    float* __restrict__ u,
    const float* __restrict__ w1, const float* __restrict__ b1,
    const float* __restrict__ w2, const float* __restrict__ b2,
    const float* __restrict__ lng, const float* __restrict__ lnb,
    const float* __restrict__ wue, const float* __restrict__ wun,
    float* __restrict__ ue, float* __restrict__ un)
{
  const int g = blockIdx.x, t = threadIdx.x;
  __shared__ float xin[192];
  __shared__ float h1[64];
  __shared__ float us[64];
  float uo = u[(g<<6)+t];
  float ns = 0.f, es = 0.f;
#pragma unroll
  for (int c=0;c<8;c++){
    ns += pn[(size_t)(g*8+c)*64 + t];
    es += pe[(size_t)(g*8+c)*64 + t];
  }
  xin[t] = uo; xin[64+t] = ns*(1.f/512.f); xin[128+t] = es*(1.f/4096.f);
  __syncthreads();
  float acc = b1[t];
  for (int k=0;k<192;k++) acc = fmaf(xin[k], w1[k*64+t], acc);
  h1[t] = fmaxf(acc, 0.f);
  __syncthreads();
  float v = b2[t];
  for (int k=0;k<64;k++) v = fmaf(h1[k], w2[k*64+t], v);
  float sA = v, sB = v*v;
#pragma unroll
  for (int m=1;m<64;m<<=1){ sA += __shfl_xor(sA,m); sB += __shfl_xor(sB,m); }
  float mean = sA * 0.015625f;
  float var  = sB * 0.015625f - mean*mean;
  float inv  = 1.0f / sqrtf(var + 1e-5f);
  float unew = (v-mean)*inv*lng[t] + lnb[t];
  u[(g<<6)+t] = unew;
  if (wue){
    us[t] = unew;
    __syncthreads();
    float a1 = 0.f, a2 = 0.f;
    for (int k=0;k<64;k++){
      float xv = us[k];
      a1 = fmaf(xv, wue[k*64+t], a1);
      a2 = fmaf(xv, wun[k*64+t], a2);
    }
    ue[(g<<6)+t] = a1;
    un[(g<<6)+t] = a2;
  }
}

// ---------------- heads ----------------
__global__ __launch_bounds__(512) void heads_kernel(
    const float* __restrict__ hn, const float* __restrict__ uvec,
    const float* __restrict__ aw, const float* __restrict__ ab,
    const float* __restrict__ cw, const float* __restrict__ cb,
    float* __restrict__ out)
{
  const int g = blockIdx.x, t = threadIdx.x;
  const int n = (g<<9) + t;
  const float4* hp = (const float4*)(hn + (size_t)n*64);
  const float4* ap = (const float4*)aw;
  float d = 0.f;
#pragma unroll
  for (int i=0;i<16;i++){
    float4 h = hp[i], a = ap[i];
    d += h.x*a.x + h.y*a.y + h.z*a.z + h.w*a.w;
  }
  d += ab[0];
  float z = 1.0f/(1.0f + expf(-d));

  unsigned o0,o1;
  threefry(0u, 42u, 0u, (unsigned)n, o0, o1);
  unsigned bits = o0 ^ o1;
  float f = __uint_as_float((bits>>9) | 0x3f800000u) - 1.0f;
  float gum = -logf(-logf(fmaxf(1.17549435e-38f, f)));

  const int lane = t & 63, wid = t >> 6;
  __shared__ float smax[8], ssum[8], sent[8], skey[8];
  __shared__ int   sidx[8];
  __shared__ float sM, sS;
  __shared__ int   sA;

  float m = z;
#pragma unroll
  for (int sh=1; sh<64; sh<<=1) m = fmaxf(m, __shfl_xor(m, sh));
  if (lane==0) smax[wid] = m;
  __syncthreads();
  if (t==0){ float mm=smax[0]; for(int i=1;i<8;i++) mm=fmaxf(mm,smax[i]); sM=mm; }
  __syncthreads();
  float M = sM;
  float ex = expf(z - M);
  float ssl = ex;
#pragma unroll
  for (int sh=1; sh<64; sh<<=1) ssl += __shfl_xor(ssl, sh);
  if (lane==0) ssum[wid] = ssl;
  __syncthreads();
  if (t==0){ float ss=0.f; for(int i=0;i<8;i++) ss+=ssum[i]; sS=ss; }
  __syncthreads();
  float logp = z - M - logf(sS);
  float p = expf(logp);
  float entl = p * logp;
#pragma unroll
  for (int sh=1; sh<64; sh<<=1) entl += __shfl_xor(entl, sh);
  if (lane==0) sent[wid] = entl;

  float kv = z + gum; int ki = t;
#pragma unroll
  for (int sh=1; sh<64; sh<<=1){
    float ov = __shfl_xor(kv, sh);
    int   oi = __shfl_xor(ki, sh);
    if (ov > kv || (ov == kv && oi < ki)){ kv = ov; ki = oi; }
  }
  if (lane==0){ skey[wid] = kv; sidx[wid] = ki; }
  __syncthreads();
  if (t==0){
    float bv = skey[0]; int bi = sidx[0];
    for (int i=1;i<8;i++) if (skey[i] > bv || (skey[i]==bv && sidx[i] < bi)){ bv=skey[i]; bi=sidx[i]; }
    sA = bi;
    float ent = 0.f; for (int i=0;i<8;i++) ent += sent[i];
    out[g]      = (float)bi;
    out[128+g]  = -ent;
  }
  __syncthreads();
  if (t == sA) out[64+g] = logp;

  if (t < 64){
    float pv = uvec[(g<<6)+t] * cw[t];
#pragma unroll
    for (int sh=1; sh<64; sh<<=1) pv += __shfl_xor(pv, sh);
    if (t==0) out[192+g] = pv + cb[0];
  }
}

// ---------------- launch ----------------
extern "C" void kernel_launch(void* const* d_in, const int* in_sizes, int n_in,
                              void* d_out, int out_size, void* d_ws, size_t ws_size,
                              hipStream_t stream)
{
  (void)in_sizes; (void)n_in; (void)out_size; (void)ws_size;
  const float* x      = (const float*)d_in[0];
  const float* eattr  = (const float*)d_in[1];
  const int*   eidx   = (const int*)d_in[2];
  const float* node_w = (const float*)d_in[5];
  const float* node_b = (const float*)d_in[6];
  const float* edge_w = (const float*)d_in[7];
  const float* edge_b = (const float*)d_in[8];
  const float* init_u = (const float*)d_in[9];
  const float* ew1 = (const float*)d_in[10]; const float* eb1 = (const float*)d_in[11];
  const float* ew2 = (const float*)d_in[12]; const float* eb2 = (const float*)d_in[13];
  const float* elg = (const float*)d_in[14]; const float* elb = (const float*)d_in[15];
  const float* nw1 = (const float*)d_in[16]; const float* nb1 = (const float*)d_in[17];
  const float* nw2 = (const float*)d_in[18]; const float* nb2 = (const float*)d_in[19];
  const float* nlg = (const float*)d_in[20]; const float* nlb = (const float*)d_in[21];
  const float* gw1 = (const float*)d_in[22]; const float* gb1 = (const float*)d_in[23];
  const float* gw2 = (const float*)d_in[24]; const float* gb2 = (const float*)d_in[25];
  const float* glg = (const float*)d_in[26]; const float* glb = (const float*)d_in[27];
  const float* aw  = (const float*)d_in[28]; const float* ab  = (const float*)d_in[29];
  const float* cw  = (const float*)d_in[30]; const float* cb  = (const float*)d_in[31];
  const int* src = eidx;
  const int* dst = eidx + EE;

  float* ws    = (float*)d_ws;
  float* hn    = ws;                         // N*64
  float* he    = hn + (size_t)NN*64;         // E*64  (dst-sorted order)
  float* agg   = he + (size_t)EE*64;         // N*64
  float* u     = agg + (size_t)NN*64;        // G*64
  int* cnt     = (int*)(u + GG*64);          // N
  int* indptr  = cnt + NN;                   // N+1
  int* fillc   = indptr + NN + 1;            // N
  int* eord    = fillc + NN;                 // E
  int* srcs    = eord + EE;                  // E
  int* dsts    = srcs + EE;                  // E
  float* pb    = (float*)(dsts + EE);        // N*64
  float* pa    = pb + (size_t)NN*64;         // N*64
  float* ue    = pa + (size_t)NN*64;         // G*64
  float* un    = ue + GG*64;                 // G*64
  float* pn    = un + GG*64;                 // 512*64
  float* pe    = pn + 512*64;                // 512*64
  float* headp = pe + 512*64;                // 4096*64
  float* tailp = headp + 4096*64;            // 4096*64
  short* wfh   = (short*)(tailp + 4096*64);  // 88064 shorts
  short* wfl   = wfh + 88064;                // 88064 shorts

  float* out = (float*)d_out;

  hipMemsetAsync(cnt,   0, NN*sizeof(int), stream);
  hipMemsetAsync(fillc, 0, NN*sizeof(int), stream);

  count_kernel<<<EE/256, 256, 0, stream>>>(dst, cnt);
  scan_kernel<<<1, 1024, 0, stream>>>(cnt, indptr);
  fill_kernel<<<EE/256, 256, 0, stream>>>(dst, indptr, fillc, eord);
  sort_kernel<<<NN/256, 256, 0, stream>>>(indptr, eord);
  perm_kernel<<<EE/256, 256, 0, stream>>>(src, dst, eord, srcs, dsts);

  encode_kernel<32><<<NN/4, 256, 0, stream>>>(x, node_w, node_b, hn, NN);
  initu_kernel<<<16, 256, 0, stream>>>(init_u, u);
  wprep_kernel<<<43, 256, 0, stream>>>(edge_w, ew1, ew2, nw1, nw2, wfh, wfl);

  // layer-0 pa/pb, ue/un
  pre_kernel<<<NN/32, 256, 0, stream>>>(hn, ew1, ew1 + 64*64, pa, pb, NN);
  pre_kernel<<<2, 256, 0, stream>>>(u, ew1 + 192*64, nw1 + 128*64, ue, un, GG);

  // frag offsets (shorts): enc=0; per layer l: e1=2048+l*20480, e2=+4096, n1=+8192, n2=+16384
  // prep frags: pa(l)=63488+l*8192, pb(l)=+4096
  for (int l=0; l<NL; ++l){
    size_t e1o = 2048 + (size_t)l*20480;
    size_t e2o = e1o + 4096, n1o = e1o + 8192, n2o = e1o + 16384;
    size_t pao = 63488 + (size_t)(l+1)*8192, pbo = pao + 4096;  // next layer

    if (l == 0)
      edge_mlp_mfma<1,1><<<EE/64, 256, 0, stream>>>(he, eattr, eord, pa, pb, ue, srcs, dsts, indptr,
          wfh, wfl, wfh + e1o, wfl + e1o, wfh + e2o, wfl + e2o,
          edge_b, eb1 + l*64, eb2 + l*64, elg + l*64, elb + l*64, he, agg, headp, tailp);
    else if (l == 1)
      edge_mlp_mfma<0,1><<<EE/64, 256, 0, stream>>>(he, eattr, eord, pa, pb, ue, srcs, dsts, indptr,
          wfh, wfl, wfh + e1o, wfl + e1o, wfh + e2o, wfl + e2o,
          edge_b, eb1 + l*64, eb2 + l*64, elg + l*64, elb + l*64, he, agg, headp, tailp);
    else
      edge_mlp_mfma<0,0><<<EE/64, 256, 0, stream>>>(he, eattr, eord, pa, pb, ue, srcs, dsts, indptr,
          wfh, wfl, wfh + e1o, wfl + e1o, wfh + e2o, wfl + e2o,
          edge_b, eb1 + l*64, eb2 + l*64, elg + l*64, elb + l*64, he, agg, headp, tailp);

    if (l < NL-1)
      node_mlp_mfma<1><<<NN/64, 256, 0, stream>>>(hn, agg, un, indptr, headp, tailp,
          wfh + n1o, wfl + n1o, wfh + n2o, wfl + n2o,
          wfh + pao, wfl + pao, wfh + pbo, wfl + pbo,
          nb1 + l*64, nb2 + l*64, nlg + l*64, nlb + l*64, hn, pn, pe, pa, pb);
    else
      node_mlp_mfma<0><<<NN/64, 256, 0, stream>>>(hn, agg, un, indptr, headp, tailp,
          wfh + n1o, wfl + n1o, wfh + n2o, wfl + n2o,
          nullptr, nullptr, nullptr, nullptr,
          nb1 + l*64, nb2 + l*64, nlg + l*64, nlb + l*64, hn, pn, pe, pa, pb);

    const float* wue = (l < NL-1) ? (ew1 + (size_t)(l+1)*16384 + 192*64) : nullptr;
    const float* wun = (l < NL-1) ? (nw1 + (size_t)(l+1)*12288 + 128*64) : nullptr;
    graphk<<<GG, 64, 0, stream>>>(pn, pe, u,
        gw1 + (size_t)l*192*64, gb1 + l*64, gw2 + (size_t)l*64*64, gb2 + l*64,
        glg + l*64, glb + l*64, wue, wun, ue, un);
  }

  heads_kernel<<<GG, 512, 0, stream>>>(hn, u, aw, ab, cw, cb, out);
}

// Round 11
// 323.761 us; speedup vs baseline: 5.1217x; 1.0143x over previous
//
#include <hip/hip_runtime.h>
#include <hip/hip_bf16.h>
#include <math.h>

#define GG 64
#define NPGc 512
#define NN (GG*NPGc)      // 32768 nodes
#define EE (NN*8)         // 262144 edges
#define HH 64
#define NL 3

typedef __attribute__((ext_vector_type(8))) short short8b;
typedef __attribute__((ext_vector_type(4))) float f32x4;

// ---------------- bf16 split helpers ----------------
__device__ __forceinline__ unsigned short f2bf_rne(float f){
  unsigned u = __float_as_uint(f);
  unsigned r = u + 0x7fffu + ((u>>16)&1u);
  return (unsigned short)(r>>16);
}
__device__ __forceinline__ float bf2f(unsigned short h){
  return __uint_as_float(((unsigned)h)<<16);
}
__device__ __forceinline__ void mk_frag(const float4 &u, const float4 &v, short8b &hi, short8b &lo){
  float av[8] = {u.x,u.y,u.z,u.w,v.x,v.y,v.z,v.w};
#pragma unroll
  for (int j=0;j<8;j++){
    __hip_bfloat16 h = __float2bfloat16(av[j]);
    hi[j] = (short)__builtin_bit_cast(unsigned short, h);
    float rem = av[j] - __bfloat162float(h);
    __hip_bfloat16 l = __float2bfloat16(rem);
    lo[j] = (short)__builtin_bit_cast(unsigned short, l);
  }
}

// ---------------- threefry2x32 (JAX-compatible, partitionable mode) ----------------
__device__ __forceinline__ unsigned rotl32(unsigned x, int r){ return (x<<r)|(x>>(32-r)); }
__device__ __forceinline__ void threefry(unsigned k0, unsigned k1, unsigned x0, unsigned x1,
                                         unsigned &o0, unsigned &o1){
  unsigned ks2 = k0 ^ k1 ^ 0x1BD11BDAu;
  unsigned v0 = x0 + k0, v1 = x1 + k1;
#define R4(a,b,c,d) v0+=v1; v1=rotl32(v1,a); v1^=v0; v0+=v1; v1=rotl32(v1,b); v1^=v0; \
                    v0+=v1; v1=rotl32(v1,c); v1^=v0; v0+=v1; v1=rotl32(v1,d); v1^=v0;
  R4(13,15,26,6)  v0+=k1;  v1+=ks2+1u;
  R4(17,29,16,24) v0+=ks2; v1+=k0+2u;
  R4(13,15,26,6)  v0+=k0;  v1+=k1+3u;
  R4(17,29,16,24) v0+=k1;  v1+=ks2+4u;
  R4(13,15,26,6)  v0+=ks2; v1+=k0+5u;
#undef R4
  o0=v0; o1=v1;
}

// ---------------- node encoder ----------------
template<int K>
__global__ __launch_bounds__(256) void encode_kernel(const float* __restrict__ in,
    const float* __restrict__ w, const float* __restrict__ b,
    float* __restrict__ out, int rows)
{
  int wid = blockIdx.x*4 + (threadIdx.x>>6);
  int lane = threadIdx.x & 63;
  if (wid >= rows) return;
  const float* xr = in + (size_t)wid*K;
  float acc = b[lane];
#pragma unroll
  for (int i=0;i<K;i++) acc = fmaf(xr[i], w[i*64+lane], acc);
  out[(size_t)wid*64+lane] = fmaxf(acc, 0.f);
}

__global__ __launch_bounds__(256) void initu_kernel(const float* __restrict__ iu, float* __restrict__ u){
  int i = blockIdx.x*256 + threadIdx.x;
  if (i < GG*64) u[i] = iu[i & 63];
}

// ---------------- CSR build ----------------
__global__ __launch_bounds__(256) void count_kernel(const int* __restrict__ dst, int* __restrict__ cnt){
  int e = blockIdx.x*256 + threadIdx.x;
  if (e < EE) atomicAdd(&cnt[dst[e]], 1);
}
__global__ __launch_bounds__(1024) void scan_kernel(const int* __restrict__ cnt, int* __restrict__ indptr){
  __shared__ int part[1024];
  const int t = threadIdx.x;
  const int base = t*32;
  int s = 0;
  for (int i=0;i<32;i++) s += cnt[base+i];
  part[t] = s;
  __syncthreads();
  for (int off=1; off<1024; off<<=1){
    int v = part[t];
    int add = (t >= off) ? part[t-off] : 0;
    __syncthreads();
    part[t] = v + add;
    __syncthreads();
  }
  int run = (t==0) ? 0 : part[t-1];
  for (int i=0;i<32;i++){ indptr[base+i] = run; run += cnt[base+i]; }
  if (t==1023) indptr[NN] = run;
}
__global__ __launch_bounds__(256) void fill_kernel(const int* __restrict__ dst, const int* __restrict__ indptr,
                                                   int* __restrict__ fillc, int* __restrict__ eord){
  int e = blockIdx.x*256 + threadIdx.x;
  if (e < EE){ int dn = dst[e]; int p = atomicAdd(&fillc[dn], 1); eord[indptr[dn]+p] = e; }
}
__global__ __launch_bounds__(256) void sort_kernel(const int* __restrict__ indptr, int* __restrict__ eord){
  int n = blockIdx.x*256 + threadIdx.x;
  if (n >= NN) return;
  int lo = indptr[n], hi = indptr[n+1];
  for (int i=lo+1;i<hi;i++){
    int v = eord[i]; int j = i-1;
    while (j >= lo && eord[j] > v){ eord[j+1]=eord[j]; j--; }
    eord[j+1] = v;
  }
}
__global__ __launch_bounds__(256) void perm_kernel(const int* __restrict__ src, const int* __restrict__ dst,
                                                   const int* __restrict__ eord,
                                                   int* __restrict__ srcs, int* __restrict__ dsts){
  int p = blockIdx.x*256 + threadIdx.x;
  if (p < EE){ int e = eord[p]; srcs[p] = src[e]; dsts[p] = dst[e]; }
}

// ---------------- pre_kernel: oa = x@wa, ob = x@wb (layer 0 only) ----------------
__global__ __launch_bounds__(256) void pre_kernel(const float* __restrict__ x,
    const float* __restrict__ wa, const float* __restrict__ wb,
    float* __restrict__ oa, float* __restrict__ ob, int rows)
{
  __shared__ float4 xs4[32*17];
  __shared__ float4 wsa[1024], wsb[1024];
  const int t = threadIdx.x;
  const int rowbase = blockIdx.x*32;
  {
    const int gi16 = t>>4, lg = t&15;
#pragma unroll
    for (int it=0; it<2; ++it){
      int er = gi16 + (it<<4);
      xs4[er*17+lg] = ((const float4*)(x + (size_t)64*(rowbase+er)))[lg];
    }
  }
  const float4* wa4 = (const float4*)wa;
  const float4* wb4 = (const float4*)wb;
#pragma unroll
  for (int i=0;i<4;i++){ wsa[t+i*256] = wa4[t+i*256]; wsb[t+i*256] = wb4[t+i*256]; }
  __syncthreads();

  const int r0 = (t>>4)*2, cq = t&15;
  float accA[2][4] = {{0,0,0,0},{0,0,0,0}};
  float accB[2][4] = {{0,0,0,0},{0,0,0,0}};
#pragma unroll
  for (int k4=0;k4<16;k4++){
    float4 a0 = xs4[(r0  )*17 + k4];
    float4 a1 = xs4[(r0+1)*17 + k4];
    const float* a0p = (const float*)&a0;
    const float* a1p = (const float*)&a1;
#pragma unroll
    for (int kk=0;kk<4;kk++){
      float4 ba = wsa[(k4*4+kk)*16 + cq];
      float4 bb = wsb[(k4*4+kk)*16 + cq];
      accA[0][0]=fmaf(a0p[kk],ba.x,accA[0][0]); accA[0][1]=fmaf(a0p[kk],ba.y,accA[0][1]);
      accA[0][2]=fmaf(a0p[kk],ba.z,accA[0][2]); accA[0][3]=fmaf(a0p[kk],ba.w,accA[0][3]);
      accA[1][0]=fmaf(a1p[kk],ba.x,accA[1][0]); accA[1][1]=fmaf(a1p[kk],ba.y,accA[1][1]);
      accA[1][2]=fmaf(a1p[kk],ba.z,accA[1][2]); accA[1][3]=fmaf(a1p[kk],ba.w,accA[1][3]);
      accB[0][0]=fmaf(a0p[kk],bb.x,accB[0][0]); accB[0][1]=fmaf(a0p[kk],bb.y,accB[0][1]);
      accB[0][2]=fmaf(a0p[kk],bb.z,accB[0][2]); accB[0][3]=fmaf(a0p[kk],bb.w,accB[0][3]);
      accB[1][0]=fmaf(a1p[kk],bb.x,accB[1][0]); accB[1][1]=fmaf(a1p[kk],bb.y,accB[1][1]);
      accB[1][2]=fmaf(a1p[kk],bb.z,accB[1][2]); accB[1][3]=fmaf(a1p[kk],bb.w,accB[1][3]);
    }
  }
#pragma unroll
  for (int rr=0; rr<2; rr++){
    size_t row = rowbase + r0 + rr;
    float4 va = {accA[rr][0],accA[rr][1],accA[rr][2],accA[rr][3]};
    float4 vb = {accB[rr][0],accB[rr][1],accB[rr][2],accB[rr][3]};
    ((float4*)(oa + row*64))[cq] = va;
    ((float4*)(ob + row*64))[cq] = vb;
  }
}

// ---------------- weight prep: per-lane MFMA B-fragments (bf16 hi/lo) ----------------
__global__ __launch_bounds__(256) void wprep_kernel(const float* __restrict__ edge_w,
    const float* __restrict__ ew1, const float* __restrict__ ew2,
    const float* __restrict__ nw1, const float* __restrict__ nw2,
    short* __restrict__ wfhi, short* __restrict__ wflo)
{
  int b = blockIdx.x;
  const float* W; int K; int kc; size_t doff;
  if (b < 31){
    int m = 0; kc = 0; doff = 0; int rem = b;
    for (m = 0; m < 13; m++){
      int kcs = (m==0) ? 1 : ((((m-1)&3)==2) ? 4 : 2);
      if (rem < kcs){ kc = rem; break; }
      rem -= kcs; doff += (size_t)kcs*2048;
    }
    if (m == 0){ W = edge_w; K = 16; }
    else {
      int l = (m-1)>>2, r = (m-1)&3;
      if      (r==0){ W = ew1 + (size_t)l*16384 + 8192; K = 64;  }
      else if (r==1){ W = ew2 + (size_t)l*4096;         K = 64;  }
      else if (r==2){ W = nw1 + (size_t)l*12288;        K = 128; }
      else          { W = nw2 + (size_t)l*4096;         K = 64;  }
    }
  } else {
    int idx = b - 31;
    int mi = idx >> 1; kc = idx & 1;
    int l = mi >> 1, which = mi & 1;
    W = ew1 + (size_t)l*16384 + (size_t)which*4096; K = 64;
    doff = 63488 + (size_t)mi*4096;
  }
  const int nt = threadIdx.x>>6, lane = threadIdx.x&63;
#pragma unroll
  for (int j=0;j<8;j++){
    int k = kc*32 + (lane>>4)*8 + j;
    int n = nt*16 + (lane&15);
    float v = (k < K) ? W[k*64+n] : 0.f;
    size_t o = doff + (size_t)kc*2048 + (size_t)((nt*64+lane)*8+j);
    unsigned short hi = f2bf_rne(v);
    wfhi[o] = (short)hi;
    wflo[o] = (short)f2bf_rne(v - bf2f(hi));
  }
}

// ---------------- edge MLP: barrier-free, per-wave 16-edge slices ----------------
// 128 threads (2 waves), 32 edges/block. Slice id = bid*2 + wv (16384 slices).
template<int FUSE, int WRITE_HE>
__global__ __launch_bounds__(128) void edge_mlp_mfma(
    const float* __restrict__ he, const float* __restrict__ eattr,
    const int* __restrict__ eord,
    const float* __restrict__ pa, const float* __restrict__ pb,
    const float* __restrict__ ue,
    const int* __restrict__ srcs, const int* __restrict__ dsts,
    const int* __restrict__ indptr,
    const short* __restrict__ weh, const short* __restrict__ wel,
    const short* __restrict__ w1h, const short* __restrict__ w1l,
    const short* __restrict__ w2h, const short* __restrict__ w2l,
    const float* __restrict__ eb, const float* __restrict__ b1,
    const float* __restrict__ b2,
    const float* __restrict__ lng, const float* __restrict__ lnb,
    float* __restrict__ outp,
    float* __restrict__ aggp, float* __restrict__ headp, float* __restrict__ tailp)
{
  __shared__ float4 xs4[32*17];            // 32 rows, stride 17 float4
  __shared__ float4 eas[FUSE ? 32*4 : 1];

  const int t = threadIdx.x;
  const int bid = ((blockIdx.x & 7) << 10) | (blockIdx.x >> 3);  // XCD swizzle, 8192 = 8*1024
  const int rowbase = bid*32;
  const int g = rowbase >> 12;
  const int wv = t>>6, lane = t&63, cl = lane&15, kgrp = lane>>4;
  const int sbase = rowbase + 16*wv;       // this wave's slice start
  const int sid   = bid*2 + wv;
  const int lrow  = 16*wv + cl;
  const int grow0 = sbase + 4*kgrp;

  // register-resident params (coalesced 64B per 16-lane group)
  float b1c[4], b2c[4], lngc[4], lnbc[4], uec[4], ebc[4];
#pragma unroll
  for (int nt=0;nt<4;nt++){
    int cn = nt*16 + cl;
    b1c[nt] = b1[cn]; b2c[nt] = b2[cn];
    lngc[nt] = lng[cn]; lnbc[nt] = lnb[cn];
    uec[nt] = ue[(g<<6)+cn];
    if constexpr (FUSE) ebc[nt] = eb[cn]; else ebc[nt] = 0.f;
  }

  // epilogue gathers (issued early, hidden under GEMM1)
  int4 sv = ((const int4*)srcs)[grow0>>2];
  int4 dv = ((const int4*)dsts)[grow0>>2];
  float exa[4][4], exb[4][4];
#pragma unroll
  for (int reg=0;reg<4;reg++){
    int s_ = ((const int*)&sv)[reg], d_ = ((const int*)&dv)[reg];
#pragma unroll
    for (int nt=0;nt<4;nt++){
      exa[reg][nt] = pa[(size_t)s_*64 + nt*16 + cl];
      exb[reg][nt] = pb[(size_t)d_*64 + nt*16 + cl];
    }
  }

  float* xsw = (float*)xs4;

  if constexpr (FUSE){
    {
      int r = lane>>2, q = lane&3;           // wave stages its own 16 eattr rows
      int e = eord[sbase + r];
      eas[(16*wv + r)*4 + q] = ((const float4*)(eattr + (size_t)e*16))[q];
    }
    f32x4 c0={0,0,0,0}, c1={0,0,0,0}, c2={0,0,0,0}, c3={0,0,0,0};
    short8b ahi, alo;
    if (kgrp < 2){
      float4 a0 = eas[(16*wv+cl)*4 + kgrp*2];
      float4 a1 = eas[(16*wv+cl)*4 + kgrp*2 + 1];
      mk_frag(a0, a1, ahi, alo);
    } else {
      ahi = (short8b){0,0,0,0,0,0,0,0};
      alo = (short8b){0,0,0,0,0,0,0,0};
    }
    const short8b* Wh = (const short8b*)weh;
    const short8b* Wl = (const short8b*)wel;
#pragma unroll
    for (int nt=0;nt<4;nt++){
      short8b bh = Wh[nt*64 + lane];
      short8b bl = Wl[nt*64 + lane];
      f32x4 c = (nt==0)?c0:(nt==1)?c1:(nt==2)?c2:c3;
      c = __builtin_amdgcn_mfma_f32_16x16x32_bf16(ahi, bh, c, 0,0,0);
      c = __builtin_amdgcn_mfma_f32_16x16x32_bf16(alo, bh, c, 0,0,0);
      c = __builtin_amdgcn_mfma_f32_16x16x32_bf16(ahi, bl, c, 0,0,0);
      if (nt==0) c0=c; else if (nt==1) c1=c; else if (nt==2) c2=c; else c3=c;
    }
#pragma unroll
    for (int nt=0;nt<4;nt++){
      int cn = nt*16 + cl;
      f32x4 c = (nt==0)?c0:(nt==1)?c1:(nt==2)?c2:c3;
#pragma unroll
      for (int reg=0;reg<4;reg++){
        float h = fmaxf(c[reg] + ebc[nt], 0.f);
        xsw[(16*wv + 4*kgrp + reg)*68 + cn] = h;
      }
    }
  } else {
    // wave stages its own 16 he rows
    const float4* heb = (const float4*)(he + (size_t)rowbase*64);
#pragma unroll
    for (int it=0;it<4;it++){
      int r = 16*wv + (lane>>4) + it*4;
      xs4[r*17 + cl] = heb[r*16 + cl];
    }
  }

  const short8b* W1h = (const short8b*)w1h;
  const short8b* W1l = (const short8b*)w1l;
  const short8b* W2h = (const short8b*)w2h;
  const short8b* W2l = (const short8b*)w2l;

  // ---- GEMM1 ----
  f32x4 acc0 = {0,0,0,0}, acc1 = {0,0,0,0}, acc2_ = {0,0,0,0}, acc3 = {0,0,0,0};
#pragma unroll
  for (int kc=0;kc<2;kc++){
    float4 a0 = xs4[lrow*17 + kc*8 + kgrp*2];
    float4 a1 = xs4[lrow*17 + kc*8 + kgrp*2 + 1];
    short8b ahi, alo; mk_frag(a0, a1, ahi, alo);
#pragma unroll
    for (int nt=0;nt<4;nt++){
      short8b bh = W1h[(kc*4+nt)*64 + lane];
      short8b bl = W1l[(kc*4+nt)*64 + lane];
      f32x4 c = (nt==0)?acc0:(nt==1)?acc1:(nt==2)?acc2_:acc3;
      c = __builtin_amdgcn_mfma_f32_16x16x32_bf16(ahi, bh, c, 0,0,0);
      c = __builtin_amdgcn_mfma_f32_16x16x32_bf16(alo, bh, c, 0,0,0);
      c = __builtin_amdgcn_mfma_f32_16x16x32_bf16(ahi, bl, c, 0,0,0);
      if (nt==0) acc0=c; else if (nt==1) acc1=c; else if (nt==2) acc2_=c; else acc3=c;
    }
  }

  // ---- epilogue1: h1 = relu(C + b1 + ue + pa[src] + pb[dst]) -> LDS (own rows) ----
#pragma unroll
  for (int nt=0;nt<4;nt++){
    int cn = nt*16 + cl;
    float bc = b1c[nt] + uec[nt];
    f32x4 c = (nt==0)?acc0:(nt==1)?acc1:(nt==2)?acc2_:acc3;
#pragma unroll
    for (int reg=0;reg<4;reg++){
      float h = fmaxf(c[reg] + bc + exa[reg][nt] + exb[reg][nt], 0.f);
      xsw[(16*wv + 4*kgrp + reg)*68 + cn] = h;
    }
  }

  // ---- GEMM2 ----
  f32x4 d0 = {0,0,0,0}, d1 = {0,0,0,0}, d2 = {0,0,0,0}, d3 = {0,0,0,0};
#pragma unroll
  for (int kc=0;kc<2;kc++){
    float4 a0 = xs4[lrow*17 + kc*8 + kgrp*2];
    float4 a1 = xs4[lrow*17 + kc*8 + kgrp*2 + 1];
    short8b ahi, alo; mk_frag(a0, a1, ahi, alo);
#pragma unroll
    for (int nt=0;nt<4;nt++){
      short8b bh = W2h[(kc*4+nt)*64 + lane];
      short8b bl = W2l[(kc*4+nt)*64 + lane];
      f32x4 c = (nt==0)?d0:(nt==1)?d1:(nt==2)?d2:d3;
      c = __builtin_amdgcn_mfma_f32_16x16x32_bf16(ahi, bh, c, 0,0,0);
      c = __builtin_amdgcn_mfma_f32_16x16x32_bf16(alo, bh, c, 0,0,0);
      c = __builtin_amdgcn_mfma_f32_16x16x32_bf16(ahi, bl, c, 0,0,0);
      if (nt==0) d0=c; else if (nt==1) d1=c; else if (nt==2) d2=c; else d3=c;
    }
  }

  // ---- LayerNorm -> LDS (own rows) ----
#pragma unroll
  for (int reg=0;reg<4;reg++){
    float v0 = d0[reg] + b2c[0];
    float v1 = d1[reg] + b2c[1];
    float v2 = d2[reg] + b2c[2];
    float v3 = d3[reg] + b2c[3];
    float sA = v0+v1+v2+v3;
    float sB = v0*v0+v1*v1+v2*v2+v3*v3;
#pragma unroll
    for (int m=1;m<16;m<<=1){ sA += __shfl_xor(sA,m); sB += __shfl_xor(sB,m); }
    float mean = sA * 0.015625f;
    float var  = sB * 0.015625f - mean*mean;
    float inv  = 1.0f / sqrtf(var + 1e-5f);
    float* lr = xsw + (16*wv + 4*kgrp + reg)*68;
    lr[cl]    = (v0-mean)*inv*lngc[0] + lnbc[0];
    lr[16+cl] = (v1-mean)*inv*lngc[1] + lnbc[1];
    lr[32+cl] = (v2-mean)*inv*lngc[2] + lnbc[2];
    lr[48+cl] = (v3-mean)*inv*lngc[3] + lnbc[3];
  }

  // ---- he store (own rows, coalesced float4) ----
  if constexpr (WRITE_HE){
    float4* he4 = (float4*)outp;
#pragma unroll
    for (int it=0;it<4;it++){
      int r = 16*wv + (lane>>4) + it*4;
      he4[(size_t)rowbase*16 + r*16 + cl] = xs4[r*17 + cl];
    }
  }

  // ---- per-slice deterministic aggregation (same-wave LDS, no barrier) ----
  {
    int n0 = dsts[sbase], nL = dsts[sbase+15];
    const int s = lane>>4, cq2 = lane&15;
    for (int n = n0 + s; n <= nL; n += 4){
      int lo = indptr[n], hi = indptr[n+1];
      int lo_c = lo - sbase; if (lo_c < 0) lo_c = 0;
      int hi_c = hi - sbase; if (hi_c > 16) hi_c = 16;
      float4 a = {0,0,0,0};
      for (int p = lo_c; p < hi_c; ++p){
        float4 v = xs4[(16*wv+p)*17 + cq2];
        a.x += v.x; a.y += v.y; a.z += v.z; a.w += v.w;
      }
      if (lo < sbase)            ((float4*)(headp + (size_t)sid*64))[cq2] = a;
      else if (hi > sbase + 16)  ((float4*)(tailp + (size_t)sid*64))[cq2] = a;
      else                       ((float4*)(aggp + (size_t)n*64))[cq2] = a;
    }
    if (s == 0 && !(indptr[n0] < sbase)){
      float4 z = {0,0,0,0};
      ((float4*)(headp + (size_t)sid*64))[cq2] = z;
    }
    if (s == 1){
      int lo = indptr[nL], hi = indptr[nL+1];
      if (!(lo >= sbase && hi > sbase + 16)){
        float4 z = {0,0,0,0};
        ((float4*)(tailp + (size_t)sid*64))[cq2] = z;
      }
    }
  }
}

// ---------------- node MLP: barrier-free, per-wave 16-node slices ----------------
// 256 threads (4 waves), 64 nodes/block. Slice id = bid*4 + wv (2048 slices).
template<int PREP>
__global__ __launch_bounds__(256) void node_mlp_mfma(
    const float* __restrict__ hn, const float* __restrict__ agg,
    const float* __restrict__ un,
    const int* __restrict__ indptr,
    const float* __restrict__ headp, const float* __restrict__ tailp,
    const short* __restrict__ w1h, const short* __restrict__ w1l,
    const short* __restrict__ w2h, const short* __restrict__ w2l,
    const short* __restrict__ wah, const short* __restrict__ wal,
    const short* __restrict__ wbh, const short* __restrict__ wbl,
    const float* __restrict__ b1, const float* __restrict__ b2,
    const float* __restrict__ lng, const float* __restrict__ lnb,
    float* __restrict__ outp, float* __restrict__ pn, float* __restrict__ pe,
    float* __restrict__ pa, float* __restrict__ pb)
{
  __shared__ float4 xs4[64*33];   // 64 rows x 128 f (+pad); hn|agg; h1/LN-out in quads 0..15

  const int t = threadIdx.x;
  const int bid = ((blockIdx.x & 7) << 6) | (blockIdx.x >> 3);   // XCD swizzle, 512 = 8*64
  const int rowbase = bid*64;
  const int g = rowbase >> 9;
  const int wv = t>>6, lane = t&63, cl = lane&15, kgrp = lane>>4;
  const int sid   = bid*4 + wv;
  const int lrow  = 16*wv + cl;
  const int grow0 = rowbase + 16*wv + 4*kgrp;

  float b1c[4], b2c[4], lngc[4], lnbc[4], unc[4];
#pragma unroll
  for (int nt=0;nt<4;nt++){
    int cn = nt*16 + cl;
    b1c[nt] = b1[cn]; b2c[nt] = b2[cn];
    lngc[nt] = lng[cn]; lnbc[nt] = lnb[cn];
    unc[nt] = un[(g<<6)+cn];
  }

  // stage hn (own rows, quads 0..15)
  {
    const float4* hn4 = (const float4*)(hn + (size_t)rowbase*64);
#pragma unroll
    for (int it=0;it<4;it++){
      int r = 16*wv + (lane>>4) + it*4;
      xs4[r*33 + cl] = hn4[r*16 + cl];
    }
  }
  // stage agg with fused slice fixup (own rows, quads 16..31) + accumulate pe partial
  float4 easum = {0,0,0,0};
  {
#pragma unroll
    for (int it=0;it<4;it++){
      int r = 16*wv + (lane>>4) + it*4;
      int n = rowbase + r;
      int lo = indptr[n], hi = indptr[n+1];
      float4 a = {0,0,0,0};
      if (lo < hi){
        int s0 = lo >> 4, s1 = (hi-1) >> 4;
        if (s0 == s1){
          a = ((const float4*)(agg + (size_t)n*64))[cl];
        } else {
          a = ((const float4*)(tailp + (size_t)s0*64))[cl];
          for (int s = s0+1; s <= s1; ++s){
            float4 h = ((const float4*)(headp + (size_t)s*64))[cl];
            a.x+=h.x; a.y+=h.y; a.z+=h.z; a.w+=h.w;
          }
        }
      }
      xs4[r*33 + 16 + cl] = a;
      easum.x += a.x; easum.y += a.y; easum.z += a.z; easum.w += a.w;
    }
    easum.x += __shfl_xor(easum.x,16); easum.x += __shfl_xor(easum.x,32);
    easum.y += __shfl_xor(easum.y,16); easum.y += __shfl_xor(easum.y,32);
    easum.z += __shfl_xor(easum.z,16); easum.z += __shfl_xor(easum.z,32);
    easum.w += __shfl_xor(easum.w,16); easum.w += __shfl_xor(easum.w,32);
    if (kgrp == 0) ((float4*)(pe + (size_t)sid*64))[cl] = easum;
  }

  const short8b* W1h = (const short8b*)w1h;
  const short8b* W1l = (const short8b*)w1l;
  const short8b* W2h = (const short8b*)w2h;
  const short8b* W2l = (const short8b*)w2l;

  // ---- GEMM1 (K=128) ----
  f32x4 acc0 = {0,0,0,0}, acc1 = {0,0,0,0}, acc2_ = {0,0,0,0}, acc3 = {0,0,0,0};
#pragma unroll
  for (int kc=0;kc<4;kc++){
    float4 a0 = xs4[lrow*33 + kc*8 + kgrp*2];
    float4 a1 = xs4[lrow*33 + kc*8 + kgrp*2 + 1];
    short8b ahi, alo; mk_frag(a0, a1, ahi, alo);
#pragma unroll
    for (int nt=0;nt<4;nt++){
      short8b bh = W1h[(kc*4+nt)*64 + lane];
      short8b bl = W1l[(kc*4+nt)*64 + lane];
      f32x4 c = (nt==0)?acc0:(nt==1)?acc1:(nt==2)?acc2_:acc3;
      c = __builtin_amdgcn_mfma_f32_16x16x32_bf16(ahi, bh, c, 0,0,0);
      c = __builtin_amdgcn_mfma_f32_16x16x32_bf16(alo, bh, c, 0,0,0);
      c = __builtin_amdgcn_mfma_f32_16x16x32_bf16(ahi, bl, c, 0,0,0);
      if (nt==0) acc0=c; else if (nt==1) acc1=c; else if (nt==2) acc2_=c; else acc3=c;
    }
  }

  // ---- epilogue1: h1 -> LDS (own rows, quads 0..15) ----
  float* xsw = (float*)xs4;
#pragma unroll
  for (int nt=0;nt<4;nt++){
    int cn = nt*16 + cl;
    float bc = b1c[nt] + unc[nt];
    f32x4 c = (nt==0)?acc0:(nt==1)?acc1:(nt==2)?acc2_:acc3;
#pragma unroll
    for (int reg=0;reg<4;reg++){
      float h = fmaxf(c[reg] + bc, 0.f);
      xsw[(16*wv + 4*kgrp + reg)*132 + cn] = h;
    }
  }

  // ---- GEMM2 (K=64) ----
  f32x4 d0 = {0,0,0,0}, d1 = {0,0,0,0}, d2 = {0,0,0,0}, d3 = {0,0,0,0};
#pragma unroll
  for (int kc=0;kc<2;kc++){
    float4 a0 = xs4[lrow*33 + kc*8 + kgrp*2];
    float4 a1 = xs4[lrow*33 + kc*8 + kgrp*2 + 1];
    short8b ahi, alo; mk_frag(a0, a1, ahi, alo);
#pragma unroll
    for (int nt=0;nt<4;nt++){
      short8b bh = W2h[(kc*4+nt)*64 + lane];
      short8b bl = W2l[(kc*4+nt)*64 + lane];
      f32x4 c = (nt==0)?d0:(nt==1)?d1:(nt==2)?d2:d3;
      c = __builtin_amdgcn_mfma_f32_16x16x32_bf16(ahi, bh, c, 0,0,0);
      c = __builtin_amdgcn_mfma_f32_16x16x32_bf16(alo, bh, c, 0,0,0);
      c = __builtin_amdgcn_mfma_f32_16x16x32_bf16(ahi, bl, c, 0,0,0);
      if (nt==0) d0=c; else if (nt==1) d1=c; else if (nt==2) d2=c; else d3=c;
    }
  }

  // ---- LayerNorm -> LDS (own rows) + pn partial ----
  float ms0 = 0.f, ms1 = 0.f, ms2 = 0.f, ms3 = 0.f;
#pragma unroll
  for (int reg=0;reg<4;reg++){
    float v0 = d0[reg] + b2c[0];
    float v1 = d1[reg] + b2c[1];
    float v2 = d2[reg] + b2c[2];
    float v3 = d3[reg] + b2c[3];
    float sA = v0+v1+v2+v3;
    float sB = v0*v0+v1*v1+v2*v2+v3*v3;
#pragma unroll
    for (int m=1;m<16;m<<=1){ sA += __shfl_xor(sA,m); sB += __shfl_xor(sB,m); }
    float mean = sA * 0.015625f;
    float var  = sB * 0.015625f - mean*mean;
    float inv  = 1.0f / sqrtf(var + 1e-5f);
    float o0v = (v0-mean)*inv*lngc[0] + lnbc[0];
    float o1v = (v1-mean)*inv*lngc[1] + lnbc[1];
    float o2v = (v2-mean)*inv*lngc[2] + lnbc[2];
    float o3v = (v3-mean)*inv*lngc[3] + lnbc[3];
    float* lr = xsw + (16*wv + 4*kgrp + reg)*132;
    lr[cl] = o0v; lr[16+cl] = o1v; lr[32+cl] = o2v; lr[48+cl] = o3v;
    ms0 += o0v; ms1 += o1v; ms2 += o2v; ms3 += o3v;
  }
  ms0 += __shfl_xor(ms0,16); ms0 += __shfl_xor(ms0,32);
  ms1 += __shfl_xor(ms1,16); ms1 += __shfl_xor(ms1,32);
  ms2 += __shfl_xor(ms2,16); ms2 += __shfl_xor(ms2,32);
  ms3 += __shfl_xor(ms3,16); ms3 += __shfl_xor(ms3,32);
  if (kgrp == 0){
    pn[(size_t)sid*64 + cl]      = ms0;
    pn[(size_t)sid*64 + 16 + cl] = ms1;
    pn[(size_t)sid*64 + 32 + cl] = ms2;
    pn[(size_t)sid*64 + 48 + cl] = ms3;
  }

  // ---- hn store (own rows, coalesced float4 from LDS) ----
  {
    float4* hn4o = (float4*)outp;
#pragma unroll
    for (int it=0;it<4;it++){
      int r = 16*wv + (lane>>4) + it*4;
      hn4o[(size_t)rowbase*16 + r*16 + cl] = xs4[r*33 + cl];
    }
  }

  // ---- PREP: pa/pb for next layer from LN-out rows (own rows) ----
  if constexpr (PREP){
#pragma unroll
    for (int m2=0;m2<2;m2++){
      const short8b* Wh = (const short8b*)(m2==0 ? wah : wbh);
      const short8b* Wl = (const short8b*)(m2==0 ? wal : wbl);
      f32x4 e0 = {0,0,0,0}, e1 = {0,0,0,0}, e2 = {0,0,0,0}, e3 = {0,0,0,0};
#pragma unroll
      for (int kc=0;kc<2;kc++){
        float4 a0 = xs4[lrow*33 + kc*8 + kgrp*2];
        float4 a1 = xs4[lrow*33 + kc*8 + kgrp*2 + 1];
        short8b ahi, alo; mk_frag(a0, a1, ahi, alo);
#pragma unroll
        for (int nt=0;nt<4;nt++){
          short8b bh = Wh[(kc*4+nt)*64 + lane];
          short8b bl = Wl[(kc*4+nt)*64 + lane];
          f32x4 c = (nt==0)?e0:(nt==1)?e1:(nt==2)?e2:e3;
          c = __builtin_amdgcn_mfma_f32_16x16x32_bf16(ahi, bh, c, 0,0,0);
          c = __builtin_amdgcn_mfma_f32_16x16x32_bf16(alo, bh, c, 0,0,0);
          c = __builtin_amdgcn_mfma_f32_16x16x32_bf16(ahi, bl, c, 0,0,0);
          if (nt==0) e0=c; else if (nt==1) e1=c; else if (nt==2) e2=c; else e3=c;
        }
      }
      float* dstp = (m2==0) ? pa : pb;
#pragma unroll
      for (int nt=0;nt<4;nt++){
        int cn = nt*16 + cl;
        f32x4 c = (nt==0)?e0:(nt==1)?e1:(nt==2)?e2:e3;
#pragma unroll
        for (int reg=0;reg<4;reg++)
          dstp[(size_t)(grow0+reg)*64 + cn] = c[reg];
      }
    }
  }
}

// ---------------- graphk: means reduce (32 chunks) + graph MLP + LN + next ue/un ----------------
__global__ __launch_bounds__(64) void graphk(
    const float* __restrict__ pn, const float* __restrict__ pe,
    float* __restrict__ u,
    const float* __restrict__ w1, const float* __restrict__ b1,
    const float* __restrict__ w2, const float* __restrict__ b2,
    const float* __restrict__ lng, const float* __restrict__ lnb,
    const float* __restrict__ wue, const float* __restrict__ wun,
    float* __restrict__ ue, float* __restrict__ un)
{
  const int g = blockIdx.x, t = threadIdx.x;
  __shared__ float xin[192];
  __shared__ float h1[64];
  __shared__ float us[64];
  float uo = u[(g<<6)+t];
  float ns = 0.f, es = 0.f;
#pragma unroll
  for (int c=0;c<32;c++){
    ns += pn[(size_t)(g*32+c)*64 + t];
    es += pe[(size_t)(g*32+c)*64 + t];
  }
  xin[t] = uo; xin[64+t] = ns*(1.f/512.f); xin[128+t] = es*(1.f/4096.f);
  __syncthreads();
  float acc = b1[t];
  for (int k=0;k<192;k++) acc = fmaf(xin[k], w1[k*64+t], acc);
  h1[t] = fmaxf(acc, 0.f);
  __syncthreads();
  float v = b2[t];
  for (int k=0;k<64;k++) v = fmaf(h1[k], w2[k*64+t], v);
  float sA = v, sB = v*v;
#pragma unroll
  for (int m=1;m<64;m<<=1){ sA += __shfl_xor(sA,m); sB += __shfl_xor(sB,m); }
  float mean = sA * 0.015625f;
  float var  = sB * 0.015625f - mean*mean;
  float inv  = 1.0f / sqrtf(var + 1e-5f);
  float unew = (v-mean)*inv*lng[t] + lnb[t];
  u[(g<<6)+t] = unew;
  if (wue){
    us[t] = unew;
    __syncthreads();
    float a1 = 0.f, a2 = 0.f;
    for (int k=0;k<64;k++){
      float xv = us[k];
      a1 = fmaf(xv, wue[k*64+t], a1);
      a2 = fmaf(xv, wun[k*64+t], a2);
    }
    ue[(g<<6)+t] = a1;
    un[(g<<6)+t] = a2;
  }
}

// ---------------- heads ----------------
__global__ __launch_bounds__(512) void heads_kernel(
    const float* __restrict__ hn, const float* __restrict__ uvec,
    const float* __restrict__ aw, const float* __restrict__ ab,
    const float* __restrict__ cw, const float* __restrict__ cb,
    float* __restrict__ out)
{
  const int g = blockIdx.x, t = threadIdx.x;
  const int n = (g<<9) + t;
  const float4* hp = (const float4*)(hn + (size_t)n*64);
  const float4* ap = (const float4*)aw;
  float d = 0.f;
#pragma unroll
  for (int i=0;i<16;i++){
    float4 h = hp[i], a = ap[i];
    d += h.x*a.x + h.y*a.y + h.z*a.z + h.w*a.w;
  }
  d += ab[0];
  float z = 1.0f/(1.0f + expf(-d));

  unsigned o0,o1;
  threefry(0u, 42u, 0u, (unsigned)n, o0, o1);
  unsigned bits = o0 ^ o1;
  float f = __uint_as_float((bits>>9) | 0x3f800000u) - 1.0f;
  float gum = -logf(-logf(fmaxf(1.17549435e-38f, f)));

  const int lane = t & 63, wid = t >> 6;
  __shared__ float smax[8], ssum[8], sent[8], skey[8];
  __shared__ int   sidx[8];
  __shared__ float sM, sS;
  __shared__ int   sA;

  float m = z;
#pragma unroll
  for (int sh=1; sh<64; sh<<=1) m = fmaxf(m, __shfl_xor(m, sh));
  if (lane==0) smax[wid] = m;
  __syncthreads();
  if (t==0){ float mm=smax[0]; for(int i=1;i<8;i++) mm=fmaxf(mm,smax[i]); sM=mm; }
  __syncthreads();
  float M = sM;
  float ex = expf(z - M);
  float ssl = ex;
#pragma unroll
  for (int sh=1; sh<64; sh<<=1) ssl += __shfl_xor(ssl, sh);
  if (lane==0) ssum[wid] = ssl;
  __syncthreads();
  if (t==0){ float ss=0.f; for(int i=0;i<8;i++) ss+=ssum[i]; sS=ss; }
  __syncthreads();
  float logp = z - M - logf(sS);
  float p = expf(logp);
  float entl = p * logp;
#pragma unroll
  for (int sh=1; sh<64; sh<<=1) entl += __shfl_xor(entl, sh);
  if (lane==0) sent[wid] = entl;

  float kv = z + gum; int ki = t;
#pragma unroll
  for (int sh=1; sh<64; sh<<=1){
    float ov = __shfl_xor(kv, sh);
    int   oi = __shfl_xor(ki, sh);
    if (ov > kv || (ov == kv && oi < ki)){ kv = ov; ki = oi; }
  }
  if (lane==0){ skey[wid] = kv; sidx[wid] = ki; }
  __syncthreads();
  if (t==0){
    float bv = skey[0]; int bi = sidx[0];
    for (int i=1;i<8;i++) if (skey[i] > bv || (skey[i]==bv && sidx[i] < bi)){ bv=skey[i]; bi=sidx[i]; }
    sA = bi;
    float ent = 0.f; for (int i=0;i<8;i++) ent += sent[i];
    out[g]      = (float)bi;
    out[128+g]  = -ent;
  }
  __syncthreads();
  if (t == sA) out[64+g] = logp;

  if (t < 64){
    float pv = uvec[(g<<6)+t] * cw[t];
#pragma unroll
    for (int sh=1; sh<64; sh<<=1) pv += __shfl_xor(pv, sh);
    if (t==0) out[192+g] = pv + cb[0];
  }
}

// ---------------- launch ----------------
extern "C" void kernel_launch(void* const* d_in, const int* in_sizes, int n_in,
                              void* d_out, int out_size, void* d_ws, size_t ws_size,
                              hipStream_t stream)
{
  (void)in_sizes; (void)n_in; (void)out_size; (void)ws_size;
  const float* x      = (const float*)d_in[0];
  const float* eattr  = (const float*)d_in[1];
  const int*   eidx   = (const int*)d_in[2];
  const float* node_w = (const float*)d_in[5];
  const float* node_b = (const float*)d_in[6];
  const float* edge_w = (const float*)d_in[7];
  const float* edge_b = (const float*)d_in[8];
  const float* init_u = (const float*)d_in[9];
  const float* ew1 = (const float*)d_in[10]; const float* eb1 = (const float*)d_in[11];
  const float* ew2 = (const float*)d_in[12]; const float* eb2 = (const float*)d_in[13];
  const float* elg = (const float*)d_in[14]; const float* elb = (const float*)d_in[15];
  const float* nw1 = (const float*)d_in[16]; const float* nb1 = (const float*)d_in[17];
  const float* nw2 = (const float*)d_in[18]; const float* nb2 = (const float*)d_in[19];
  const float* nlg = (const float*)d_in[20]; const float* nlb = (const float*)d_in[21];
  const float* gw1 = (const float*)d_in[22]; const float* gb1 = (const float*)d_in[23];
  const float* gw2 = (const float*)d_in[24]; const float* gb2 = (const float*)d_in[25];
  const float* glg = (const float*)d_in[26]; const float* glb = (const float*)d_in[27];
  const float* aw  = (const float*)d_in[28]; const float* ab  = (const float*)d_in[29];
  const float* cw  = (const float*)d_in[30]; const float* cb  = (const float*)d_in[31];
  const int* src = eidx;
  const int* dst = eidx + EE;

  float* ws    = (float*)d_ws;
  float* hn    = ws;                         // N*64
  float* he    = hn + (size_t)NN*64;         // E*64  (dst-sorted order)
  float* agg   = he + (size_t)EE*64;         // N*64
  float* u     = agg + (size_t)NN*64;        // G*64
  int* cnt     = (int*)(u + GG*64);          // N
  int* indptr  = cnt + NN;                   // N+1
  int* fillc   = indptr + NN + 1;            // N
  int* eord    = fillc + NN;                 // E
  int* srcs    = eord + EE;                  // E
  int* dsts    = srcs + EE;                  // E
  float* pb    = (float*)(dsts + EE);        // N*64
  float* pa    = pb + (size_t)NN*64;         // N*64
  float* ue    = pa + (size_t)NN*64;         // G*64
  float* un    = ue + GG*64;                 // G*64
  float* pn    = un + GG*64;                 // 2048*64
  float* pe    = pn + 2048*64;               // 2048*64
  float* headp = pe + 2048*64;               // 16384*64
  float* tailp = headp + (size_t)16384*64;   // 16384*64
  short* wfh   = (short*)(tailp + (size_t)16384*64);  // 88064 shorts
  short* wfl   = wfh + 88064;                // 88064 shorts

  float* out = (float*)d_out;

  hipMemsetAsync(cnt,   0, NN*sizeof(int), stream);
  hipMemsetAsync(fillc, 0, NN*sizeof(int), stream);

  count_kernel<<<EE/256, 256, 0, stream>>>(dst, cnt);
  scan_kernel<<<1, 1024, 0, stream>>>(cnt, indptr);
  fill_kernel<<<EE/256, 256, 0, stream>>>(dst, indptr, fillc, eord);
  sort_kernel<<<NN/256, 256, 0, stream>>>(indptr, eord);
  perm_kernel<<<EE/256, 256, 0, stream>>>(src, dst, eord, srcs, dsts);

  encode_kernel<32><<<NN/4, 256, 0, stream>>>(x, node_w, node_b, hn, NN);
  initu_kernel<<<16, 256, 0, stream>>>(init_u, u);
  wprep_kernel<<<43, 256, 0, stream>>>(edge_w, ew1, ew2, nw1, nw2, wfh, wfl);

  // layer-0 pa/pb, ue/un
  pre_kernel<<<NN/32, 256, 0, stream>>>(hn, ew1, ew1 + 64*64, pa, pb, NN);
  pre_kernel<<<2, 256, 0, stream>>>(u, ew1 + 192*64, nw1 + 128*64, ue, un, GG);

  // frag offsets (shorts): enc=0; per layer l: e1=2048+l*20480, e2=+4096, n1=+8192, n2=+16384
  // prep frags: pa(l)=63488+l*8192, pb(l)=+4096
  for (int l=0; l<NL; ++l){
    size_t e1o = 2048 + (size_t)l*20480;
    size_t e2o = e1o + 4096, n1o = e1o + 8192, n2o = e1o + 16384;
    size_t pao = 63488 + (size_t)(l+1)*8192, pbo = pao + 4096;  // next layer

    if (l == 0)
      edge_mlp_mfma<1,1><<<EE/32, 128, 0, stream>>>(he, eattr, eord, pa, pb, ue, srcs, dsts, indptr,
          wfh, wfl, wfh + e1o, wfl + e1o, wfh + e2o, wfl + e2o,
          edge_b, eb1 + l*64, eb2 + l*64, elg + l*64, elb + l*64, he, agg, headp, tailp);
    else if (l == 1)
      edge_mlp_mfma<0,1><<<EE/32, 128, 0, stream>>>(he, eattr, eord, pa, pb, ue, srcs, dsts, indptr,
          wfh, wfl, wfh + e1o, wfl + e1o, wfh + e2o, wfl + e2o,
          edge_b, eb1 + l*64, eb2 + l*64, elg + l*64, elb + l*64, he, agg, headp, tailp);
    else
      edge_mlp_mfma<0,0><<<EE/32, 128, 0, stream>>>(he, eattr, eord, pa, pb, ue, srcs, dsts, indptr,
          wfh, wfl, wfh + e1o, wfl + e1o, wfh + e2o, wfl + e2o,
          edge_b, eb1 + l*64, eb2 + l*64, elg + l*64, elb + l*64, he, agg, headp, tailp);

    if (l < NL-1)
      node_mlp_mfma<1><<<NN/64, 256, 0, stream>>>(hn, agg, un, indptr, headp, tailp,
          wfh + n1o, wfl + n1o, wfh + n2o, wfl + n2o,
          wfh + pao, wfl + pao, wfh + pbo, wfl + pbo,
          nb1 + l*64, nb2 + l*64, nlg + l*64, nlb + l*64, hn, pn, pe, pa, pb);
    else
      node_mlp_mfma<0><<<NN/64, 256, 0, stream>>>(hn, agg, un, indptr, headp, tailp,
          wfh + n1o, wfl + n1o, wfh + n2o, wfl + n2o,
          nullptr, nullptr, nullptr, nullptr,
          nb1 + l*64, nb2 + l*64, nlg + l*64, nlb + l*64, hn, pn, pe, pa, pb);

    const float* wue = (l < NL-1) ? (ew1 + (size_t)(l+1)*16384 + 192*64) : nullptr;
    const float* wun = (l < NL-1) ? (nw1 + (size_t)(l+1)*12288 + 128*64) : nullptr;
    graphk<<<GG, 64, 0, stream>>>(pn, pe, u,
        gw1 + (size_t)l*192*64, gb1 + l*64, gw2 + (size_t)l*64*64, gb2 + l*64,
        glg + l*64, glb + l*64, wue, wun, ue, un);
  }

  heads_kernel<<<GG, 512, 0, stream>>>(hn, u, aw, ab, cw, cb, out);
}